// Round 6
// baseline (593.600 us; speedup 1.0000x reference)
//
#include <hip/hip_runtime.h>
#include <hip/hip_bf16.h>
#include <math.h>

#define NN 100000     // nodes
#define NE 800000     // edges per relation
#define FD 128        // feature dim

typedef unsigned short ushort_t;

// ---------- bf16 pack helpers (round-to-nearest-even) ----------
__device__ inline unsigned f2bf(float f){
    unsigned u = __float_as_uint(f);
    return (u + 0x7fffu + ((u >> 16) & 1u)) >> 16;
}
__device__ inline unsigned pk(float a, float b){
    return f2bf(a) | (f2bf(b) << 16);
}

// ---------- CSR build ----------
__global__ void k_hist(const int* __restrict__ dst, int* __restrict__ counts){
    int i = blockIdx.x * blockDim.x + threadIdx.x;
    if (i < NE) atomicAdd(&counts[dst[i]], 1);
}

#define SCAN_TILE 1024
__global__ void k_scan_partial(const int* __restrict__ counts, int n, int* __restrict__ partials){
    __shared__ int sm[256];
    int base = blockIdx.x * SCAN_TILE;
    int t = threadIdx.x;
    int s = 0;
    #pragma unroll
    for (int j = 0; j < 4; j++){
        int idx = base + t*4 + j;
        if (idx < n) s += counts[idx];
    }
    sm[t] = s; __syncthreads();
    for (int off = 128; off > 0; off >>= 1){
        if (t < off) sm[t] += sm[t+off];
        __syncthreads();
    }
    if (t == 0) partials[blockIdx.x] = sm[0];
}

__global__ void k_scan_partials_excl(int* partials, int nb){
    __shared__ int sm[256];
    int t = threadIdx.x;
    int v = (t < nb) ? partials[t] : 0;
    sm[t] = v; __syncthreads();
    for (int off = 1; off < 256; off <<= 1){
        int add = (t >= off) ? sm[t-off] : 0;
        __syncthreads();
        sm[t] += add;
        __syncthreads();
    }
    if (t < nb) partials[t] = sm[t] - v;   // exclusive
}

__global__ void k_scan_final(const int* __restrict__ counts, int n,
                             const int* __restrict__ partials, int* __restrict__ rowptr){
    __shared__ int sm[256];
    int base = blockIdx.x * SCAN_TILE;
    int t = threadIdx.x;
    int v[4]; int s = 0;
    #pragma unroll
    for (int j = 0; j < 4; j++){
        int idx = base + t*4 + j;
        v[j] = (idx < n) ? counts[idx] : 0;
        s += v[j];
    }
    sm[t] = s; __syncthreads();
    for (int off = 1; off < 256; off <<= 1){
        int add = (t >= off) ? sm[t-off] : 0;
        __syncthreads();
        sm[t] += add;
        __syncthreads();
    }
    int excl = sm[t] - s + partials[blockIdx.x];
    #pragma unroll
    for (int j = 0; j < 4; j++){
        int idx = base + t*4 + j;
        if (idx < n) rowptr[idx] = excl;
        excl += v[j];
    }
    if (blockIdx.x == 0 && t == 0) rowptr[n] = NE;
}

__global__ void k_scatter(const int* __restrict__ dst, const int* __restrict__ src,
                          int* __restrict__ cursor, int* __restrict__ colsrc){
    int i = blockIdx.x * blockDim.x + threadIdx.x;
    if (i < NE){
        int p = atomicAdd(&cursor[dst[i]], 1);
        colsrc[p] = src[i];
    }
}

// ---------- helpers ----------
__device__ inline float dot4(float4 a, float4 b){
    return fmaf(a.x, b.x, fmaf(a.y, b.y, fmaf(a.z, b.z, a.w * b.w)));
}
__device__ inline float red16(float v){
    v += __shfl_xor(v, 1);
    v += __shfl_xor(v, 2);
    v += __shfl_xor(v, 4);
    v += __shfl_xor(v, 8);
    return v;
}

// ---------- GEMM + fused el/er epilogue, K-chunked, bf16 feat output ----------
template<int H, bool RELU>
__global__ __launch_bounds__(256) void k_gemm(const float* __restrict__ A,
                                              const float* __restrict__ W,
                                              const float* __restrict__ al,
                                              const float* __restrict__ ar,
                                              ushort_t* __restrict__ featb,
                                              float* __restrict__ el,
                                              float* __restrict__ er){
    __shared__ float Ws[32*128];   // 16 KB: K-chunk of W, layout [k][n]
    __shared__ float As[64*36];    // 9 KB: A chunk, stride 36 (16B-aligned rows)
    int t = threadIdx.x;
    long row0 = (long)blockIdx.x * 64;
    int g = t >> 4, c = t & 15;
    int r0 = g * 4;
    int lr = t >> 3, lc = (t & 7) * 4;
    float4 acc[4][2];
    #pragma unroll
    for (int i = 0; i < 4; i++){
        acc[i][0] = make_float4(0.f,0.f,0.f,0.f);
        acc[i][1] = make_float4(0.f,0.f,0.f,0.f);
    }
    for (int k0 = 0; k0 < 128; k0 += 32){
        __syncthreads();
        #pragma unroll
        for (int i = 0; i < 4; i++){
            int idx = t*4 + i*1024;
            *(float4*)&Ws[idx] = *(const float4*)&W[k0*FD + idx];
        }
        #pragma unroll
        for (int i = 0; i < 2; i++){
            int r = lr + i*32;
            float4 a = make_float4(0.f, 0.f, 0.f, 0.f);
            if (row0 + r < NN){
                a = *(const float4*)&A[(row0 + r)*FD + k0 + lc];
                if (RELU){
                    a.x = fmaxf(a.x, 0.f); a.y = fmaxf(a.y, 0.f);
                    a.z = fmaxf(a.z, 0.f); a.w = fmaxf(a.w, 0.f);
                }
            }
            *(float4*)&As[r*36 + lc] = a;
        }
        __syncthreads();
        #pragma unroll 4
        for (int k = 0; k < 32; k++){
            float4 w0 = *(const float4*)&Ws[k*FD + c*4];
            float4 w1 = *(const float4*)&Ws[k*FD + 64 + c*4];
            #pragma unroll
            for (int i = 0; i < 4; i++){
                float a = As[(r0+i)*36 + k];
                acc[i][0].x = fmaf(a, w0.x, acc[i][0].x);
                acc[i][0].y = fmaf(a, w0.y, acc[i][0].y);
                acc[i][0].z = fmaf(a, w0.z, acc[i][0].z);
                acc[i][0].w = fmaf(a, w0.w, acc[i][0].w);
                acc[i][1].x = fmaf(a, w1.x, acc[i][1].x);
                acc[i][1].y = fmaf(a, w1.y, acc[i][1].y);
                acc[i][1].z = fmaf(a, w1.z, acc[i][1].z);
                acc[i][1].w = fmaf(a, w1.w, acc[i][1].w);
            }
        }
    }
    // epilogue: bf16 feat stores + fused el/er (fp32)
    float4 alv0 = *(const float4*)&al[c*4];
    float4 alv1 = *(const float4*)&al[64 + c*4];
    float4 arv0 = *(const float4*)&ar[c*4];
    float4 arv1 = *(const float4*)&ar[64 + c*4];
    #pragma unroll
    for (int i = 0; i < 4; i++){
        long row = row0 + r0 + i;
        if (row < NN){
            uint2 p0 = make_uint2(pk(acc[i][0].x, acc[i][0].y), pk(acc[i][0].z, acc[i][0].w));
            uint2 p1 = make_uint2(pk(acc[i][1].x, acc[i][1].y), pk(acc[i][1].z, acc[i][1].w));
            *(uint2*)&featb[row*FD + c*4]      = p0;
            *(uint2*)&featb[row*FD + 64 + c*4] = p1;
        }
        if (H == 2){
            float pl0 = red16(dot4(acc[i][0], alv0));
            float pl1 = red16(dot4(acc[i][1], alv1));
            float pr0 = red16(dot4(acc[i][0], arv0));
            float pr1 = red16(dot4(acc[i][1], arv1));
            if (c == 0 && row < NN){
                el[row*2]   = pl0; el[row*2+1] = pl1;
                er[row*2]   = pr0; er[row*2+1] = pr1;
            }
        } else {
            float pl = red16(dot4(acc[i][0], alv0) + dot4(acc[i][1], alv1));
            float pr = red16(dot4(acc[i][0], arv0) + dot4(acc[i][1], arv1));
            if (c == 0 && row < NN){
                el[row] = pl; er[row] = pr;
            }
        }
    }
}

// ---------- per-relation aggregation core: 16 lanes x 16B per gathered row ----------
// Wave = 4 groups of 16 lanes; each iteration gathers 8 edges' rows (2 per lane in
// flight). lane sub = lane&15 covers feature cols [8*sub, 8*sub+8).
// H=2: sub<8 -> head0 (cols 0..63), sub>=8 -> head1 (cols 64..127).
template<int H>
__device__ inline void agg_one(const int* __restrict__ rowptr, const int* __restrict__ colsrc,
                               const float* __restrict__ el, const float* __restrict__ er,
                               const ushort_t* __restrict__ featb, int node, int lane,
                               float acc[8], float& inv){
    int beg = rowptr[node], end = rowptr[node+1];
    float er0 = er[node*H];
    float er1 = (H == 2) ? er[node*H + 1] : 0.f;
    int sub = lane & 15;
    int g   = lane >> 4;
    float s0 = 0.f, s1 = 0.f;
    for (int base = beg; base < end; base += 64){
        int nrem = end - base;
        bool active = lane < nrem;
        int sv = active ? colsrc[base + lane] : 0;
        float a0 = 0.f, a1 = 0.f;
        if (active){
            if (H == 2){
                float2 e2 = *(const float2*)&el[sv*2];
                float e0 = e2.x + er0, e1 = e2.y + er1;
                e0 = (e0 > 0.f) ? e0 : 0.2f*e0;
                e1 = (e1 > 0.f) ? e1 : 0.2f*e1;
                a0 = __expf(e0); a1 = __expf(e1);
            } else {
                float e0 = el[sv] + er0;
                e0 = (e0 > 0.f) ? e0 : 0.2f*e0;
                a0 = __expf(e0);
            }
        }
        s0 += a0;
        if (H == 2) s1 += a1;
        int nn = min(64, nrem);
        // 8 edges per iteration: group g handles slots j4+g and j4+g+4
        // (tail slots have weight 0; their dummy row-0 loads are cache hits)
        for (int j4 = 0; j4 < nn; j4 += 8){
            int slotA = j4 + g;
            int slotB = j4 + g + 4;
            int sjA = __shfl(sv, slotA);
            int sjB = __shfl(sv, slotB);
            float wA, wB;
            if (H == 2){
                float wA0 = __shfl(a0, slotA);
                float wA1 = __shfl(a1, slotA);
                float wB0 = __shfl(a0, slotB);
                float wB1 = __shfl(a1, slotB);
                wA = (sub < 8) ? wA0 : wA1;
                wB = (sub < 8) ? wB0 : wB1;
            } else {
                wA = __shfl(a0, slotA);
                wB = __shfl(a0, slotB);
            }
            uint4 pA = *(const uint4*)&featb[(size_t)sjA*FD + sub*8];
            uint4 pB = *(const uint4*)&featb[(size_t)sjB*FD + sub*8];
            acc[0] = fmaf(wA, __uint_as_float(pA.x << 16),         acc[0]);
            acc[1] = fmaf(wA, __uint_as_float(pA.x & 0xffff0000u), acc[1]);
            acc[2] = fmaf(wA, __uint_as_float(pA.y << 16),         acc[2]);
            acc[3] = fmaf(wA, __uint_as_float(pA.y & 0xffff0000u), acc[3]);
            acc[4] = fmaf(wA, __uint_as_float(pA.z << 16),         acc[4]);
            acc[5] = fmaf(wA, __uint_as_float(pA.z & 0xffff0000u), acc[5]);
            acc[6] = fmaf(wA, __uint_as_float(pA.w << 16),         acc[6]);
            acc[7] = fmaf(wA, __uint_as_float(pA.w & 0xffff0000u), acc[7]);
            acc[0] = fmaf(wB, __uint_as_float(pB.x << 16),         acc[0]);
            acc[1] = fmaf(wB, __uint_as_float(pB.x & 0xffff0000u), acc[1]);
            acc[2] = fmaf(wB, __uint_as_float(pB.y << 16),         acc[2]);
            acc[3] = fmaf(wB, __uint_as_float(pB.y & 0xffff0000u), acc[3]);
            acc[4] = fmaf(wB, __uint_as_float(pB.z << 16),         acc[4]);
            acc[5] = fmaf(wB, __uint_as_float(pB.z & 0xffff0000u), acc[5]);
            acc[6] = fmaf(wB, __uint_as_float(pB.w << 16),         acc[6]);
            acc[7] = fmaf(wB, __uint_as_float(pB.w & 0xffff0000u), acc[7]);
        }
    }
    #pragma unroll
    for (int off = 32; off > 0; off >>= 1){
        s0 += __shfl_xor(s0, off);
        if (H == 2) s1 += __shfl_xor(s1, off);
    }
    float i0 = (end > beg) ? 1.f/s0 : 0.f;
    if (H == 2){
        float i1 = (end > beg) ? 1.f/s1 : 0.f;
        inv = (sub < 8) ? i0 : i1;
    } else {
        inv = i0;
    }
}

// ---------- fused aggregation: 2 waves per node (one per relation) ----------
// block = 256 = 4 waves = 2 nodes x 2 relations. rel-1 wave stages its normalized
// result in LDS; rel-0 wave merges, adds biases, scales by 0.5, writes out once.
template<int H>
__global__ __launch_bounds__(256) void k_agg2(
                       const int* __restrict__ rowptr0, const int* __restrict__ colsrc0,
                       const int* __restrict__ rowptr1, const int* __restrict__ colsrc1,
                       const float* __restrict__ el0, const float* __restrict__ er0,
                       const float* __restrict__ el1, const float* __restrict__ er1,
                       const ushort_t* __restrict__ featb0, const ushort_t* __restrict__ featb1,
                       const float* __restrict__ bias0, const float* __restrict__ bias1,
                       float* __restrict__ out){
    __shared__ float red[2][128];
    int wid  = threadIdx.x >> 6;
    int lane = threadIdx.x & 63;
    int slot = wid >> 1;
    int rel  = wid & 1;
    int node = blockIdx.x * 2 + slot;
    const int*      rp = rel ? rowptr1 : rowptr0;
    const int*      cs = rel ? colsrc1 : colsrc0;
    const float*    elp = rel ? el1 : el0;
    const float*    erp = rel ? er1 : er0;
    const ushort_t* fb = rel ? featb1 : featb0;
    float acc[8] = {0.f,0.f,0.f,0.f,0.f,0.f,0.f,0.f};
    float inv = 0.f;
    if (node < NN){
        agg_one<H>(rp, cs, elp, erp, fb, node, lane, acc, inv);
    }
    // reduce across the 4 groups (lane bits 4 and 5); then normalize
    #pragma unroll
    for (int i = 0; i < 8; i++){
        acc[i] += __shfl_xor(acc[i], 16);
        acc[i] += __shfl_xor(acc[i], 32);
        acc[i] *= inv;
    }
    if (rel == 1 && lane < 16 && node < NN){
        #pragma unroll
        for (int i = 0; i < 8; i++) red[slot][lane*8 + i] = acc[i];
    }
    __syncthreads();
    if (rel == 0 && lane < 16 && node < NN){
        int sub = lane;
        float4 ba0 = *(const float4*)&bias0[sub*8];
        float4 bb0 = *(const float4*)&bias0[sub*8 + 4];
        float4 ba1 = *(const float4*)&bias1[sub*8];
        float4 bb1 = *(const float4*)&bias1[sub*8 + 4];
        const float* r1 = &red[slot][sub*8];
        float4 o0, o1;
        o0.x = 0.5f*(acc[0] + r1[0] + ba0.x + ba1.x);
        o0.y = 0.5f*(acc[1] + r1[1] + ba0.y + ba1.y);
        o0.z = 0.5f*(acc[2] + r1[2] + ba0.z + ba1.z);
        o0.w = 0.5f*(acc[3] + r1[3] + ba0.w + ba1.w);
        o1.x = 0.5f*(acc[4] + r1[4] + bb0.x + bb1.x);
        o1.y = 0.5f*(acc[5] + r1[5] + bb0.y + bb1.y);
        o1.z = 0.5f*(acc[6] + r1[6] + bb0.z + bb1.z);
        o1.w = 0.5f*(acc[7] + r1[7] + bb0.w + bb1.w);
        float* o = &out[(size_t)node*FD + sub*8];
        *(float4*)&o[0] = o0;
        *(float4*)&o[4] = o1;
    }
}

// ---------- launch ----------
extern "C" void kernel_launch(void* const* d_in, const int* in_sizes, int n_in,
                              void* d_out, int out_size, void* d_ws, size_t ws_size,
                              hipStream_t stream){
    const float* x   = (const float*)d_in[0];
    const float* W1  = (const float*)d_in[1];
    const float* al1 = (const float*)d_in[2];
    const float* ar1 = (const float*)d_in[3];
    const float* b1  = (const float*)d_in[4];
    const float* W2  = (const float*)d_in[5];
    const float* al2 = (const float*)d_in[6];
    const float* ar2 = (const float*)d_in[7];
    const float* b2  = (const float*)d_in[8];
    const int*   src = (const int*)d_in[9];
    const int*   dst = (const int*)d_in[10];
    float* out = (float*)d_out;

    size_t off = 0;
    auto carve = [&](size_t bytes) -> char* {
        char* p = (char*)d_ws + off;
        off += (bytes + 255) & ~(size_t)255;
        return p;
    };
    ushort_t* featb0 = (ushort_t*)carve((size_t)NN * FD * 2);
    ushort_t* featb1 = (ushort_t*)carve((size_t)NN * FD * 2);
    float* h1       = (float*)carve((size_t)NN * FD * 4);
    float* el0      = (float*)carve((size_t)NN * 2 * 4);
    float* er0      = (float*)carve((size_t)NN * 2 * 4);
    float* el1      = (float*)carve((size_t)NN * 2 * 4);
    float* er1      = (float*)carve((size_t)NN * 2 * 4);
    int*   rowptr0  = (int*)  carve((size_t)(NN + 1) * 4);
    int*   rowptr1  = (int*)  carve((size_t)(NN + 1) * 4);
    int*   colsrc0  = (int*)  carve((size_t)NE * 4);
    int*   colsrc1  = (int*)  carve((size_t)NE * 4);
    int*   counts   = (int*)  carve((size_t)NN * 4);
    int*   cursor   = (int*)  carve((size_t)NN * 4);
    int*   partials = (int*)  carve(1024);
    if (off > ws_size) return;

    const int EB = (NE + 255) / 256;
    const int NB = (NN + SCAN_TILE - 1) / SCAN_TILE;
    const int GB = (NN + 63) / 64;
    const int AB = (NN + 1) / 2;   // 2 nodes per block (2 waves each)

    int* rowptrs[2] = {rowptr0, rowptr1};
    int* colsrcs[2] = {colsrc0, colsrc1};

    // build CSR per relation (shared by both layers); adjacency stores src ids
    for (int r = 0; r < 2; r++){
        const int* dstr = dst + (size_t)r * NE;
        const int* srcr = src + (size_t)r * NE;
        hipMemsetAsync(counts, 0, (size_t)NN * 4, stream);
        k_hist<<<EB, 256, 0, stream>>>(dstr, counts);
        k_scan_partial<<<NB, 256, 0, stream>>>(counts, NN, partials);
        k_scan_partials_excl<<<1, 256, 0, stream>>>(partials, NB);
        k_scan_final<<<NB, 256, 0, stream>>>(counts, NN, partials, rowptrs[r]);
        hipMemcpyAsync(cursor, rowptrs[r], (size_t)NN * 4, hipMemcpyDeviceToDevice, stream);
        k_scatter<<<EB, 256, 0, stream>>>(dstr, srcr, cursor, colsrcs[r]);
    }

    // layer 1: H=2, D=64
    k_gemm<2, false><<<GB, 256, 0, stream>>>(x, W1,                    al1,      ar1,      featb0, el0, er0);
    k_gemm<2, false><<<GB, 256, 0, stream>>>(x, W1 + (size_t)FD * FD,  al1 + FD, ar1 + FD, featb1, el1, er1);
    k_agg2<2><<<AB, 256, 0, stream>>>(rowptr0, colsrc0, rowptr1, colsrc1,
                                      el0, er0, el1, er1, featb0, featb1,
                                      b1, b1 + FD, h1);

    // layer 2: H=1, D=128 (relu folded into GEMM A-load)
    k_gemm<1, true><<<GB, 256, 0, stream>>>(h1, W2,                    al2,      ar2,      featb0, el0, er0);
    k_gemm<1, true><<<GB, 256, 0, stream>>>(h1, W2 + (size_t)FD * FD,  al2 + FD, ar2 + FD, featb1, el1, er1);
    k_agg2<1><<<AB, 256, 0, stream>>>(rowptr0, colsrc0, rowptr1, colsrc1,
                                      el0, er0, el1, er1, featb0, featb1,
                                      b2, b2 + FD, out);
}

// Round 7
// 470.847 us; speedup vs baseline: 1.2607x; 1.2607x over previous
//
#include <hip/hip_runtime.h>
#include <hip/hip_bf16.h>
#include <math.h>

#define NN 100000     // nodes
#define NE 800000     // edges per relation
#define FD 128        // feature dim

typedef unsigned short ushort_t;
typedef __attribute__((ext_vector_type(8))) short bf16x8;
typedef __attribute__((ext_vector_type(4))) float f32x4;

// ---------- bf16 pack helpers ----------
__device__ inline unsigned f2bf(float f){              // software RNE (prep kernels)
    unsigned u = __float_as_uint(f);
    return (u + 0x7fffu + ((u >> 16) & 1u)) >> 16;
}
__device__ inline unsigned pk(float a, float b){
    return f2bf(a) | (f2bf(b) << 16);
}
__device__ inline unsigned cvtpk(float lo, float hi){  // HW packed cvt (1 inst)
    unsigned r;
    asm("v_cvt_pk_bf16_f32 %0, %1, %2" : "=v"(r) : "v"(lo), "v"(hi));
    return r;
}

// ---------- CSR build ----------
__global__ void k_hist(const int* __restrict__ dst, int* __restrict__ counts){
    int i = blockIdx.x * blockDim.x + threadIdx.x;
    if (i < NE) atomicAdd(&counts[dst[i]], 1);
}

#define SCAN_TILE 1024
__global__ void k_scan_partial(const int* __restrict__ counts, int n, int* __restrict__ partials){
    __shared__ int sm[256];
    int base = blockIdx.x * SCAN_TILE;
    int t = threadIdx.x;
    int s = 0;
    #pragma unroll
    for (int j = 0; j < 4; j++){
        int idx = base + t*4 + j;
        if (idx < n) s += counts[idx];
    }
    sm[t] = s; __syncthreads();
    for (int off = 128; off > 0; off >>= 1){
        if (t < off) sm[t] += sm[t+off];
        __syncthreads();
    }
    if (t == 0) partials[blockIdx.x] = sm[0];
}

__global__ void k_scan_partials_excl(int* partials, int nb){
    __shared__ int sm[256];
    int t = threadIdx.x;
    int v = (t < nb) ? partials[t] : 0;
    sm[t] = v; __syncthreads();
    for (int off = 1; off < 256; off <<= 1){
        int add = (t >= off) ? sm[t-off] : 0;
        __syncthreads();
        sm[t] += add;
        __syncthreads();
    }
    if (t < nb) partials[t] = sm[t] - v;   // exclusive
}

__global__ void k_scan_final(const int* __restrict__ counts, int n,
                             const int* __restrict__ partials, int* __restrict__ rowptr){
    __shared__ int sm[256];
    int base = blockIdx.x * SCAN_TILE;
    int t = threadIdx.x;
    int v[4]; int s = 0;
    #pragma unroll
    for (int j = 0; j < 4; j++){
        int idx = base + t*4 + j;
        v[j] = (idx < n) ? counts[idx] : 0;
        s += v[j];
    }
    sm[t] = s; __syncthreads();
    for (int off = 1; off < 256; off <<= 1){
        int add = (t >= off) ? sm[t-off] : 0;
        __syncthreads();
        sm[t] += add;
        __syncthreads();
    }
    int excl = sm[t] - s + partials[blockIdx.x];
    #pragma unroll
    for (int j = 0; j < 4; j++){
        int idx = base + t*4 + j;
        if (idx < n) rowptr[idx] = excl;
        excl += v[j];
    }
    if (blockIdx.x == 0 && t == 0) rowptr[n] = NE;
}

__global__ void k_scatter(const int* __restrict__ dst, const int* __restrict__ src,
                          int* __restrict__ cursor, int* __restrict__ colsrc){
    int i = blockIdx.x * blockDim.x + threadIdx.x;
    if (i < NE){
        int p = atomicAdd(&cursor[dst[i]], 1);
        colsrc[p] = src[i];
    }
}

// ---------- prep: x -> bf16 ----------
__global__ void k_cast(const float* __restrict__ in, ushort_t* __restrict__ out, int n8){
    int i = blockIdx.x * blockDim.x + threadIdx.x;
    if (i < n8){
        float4 u = ((const float4*)in)[i*2];
        float4 v = ((const float4*)in)[i*2 + 1];
        uint4 o;
        o.x = pk(u.x, u.y); o.y = pk(u.z, u.w);
        o.z = pk(v.x, v.y); o.w = pk(v.z, v.w);
        ((uint4*)out)[i] = o;
    }
}

// ---------- prep: W (2 rel x 128x128 fp32) -> B-fragment-linear bf16 ----------
// Wt[((f*4+ks)*64 + l)*8 + j] = W[rel=f>>3][ k ][ (f&7)*16 + (l&15) ],
// k = ks*32 + (l>>4)*8 + j  (PERM: k -> (k&7)*16 + (k>>3), absorbing h1b's layout)
__global__ void k_prepw(const float* __restrict__ W, ushort_t* __restrict__ Wt, int perm){
    int idx = blockIdx.x * blockDim.x + threadIdx.x;   // 32768 total
    if (idx >= 32768) return;
    int j  = idx & 7;
    int l  = (idx >> 3) & 63;
    int ks = (idx >> 9) & 3;
    int f  = idx >> 11;
    int k  = ks*32 + (l >> 4)*8 + j;
    if (perm) k = (k & 7)*16 + (k >> 3);
    int col = (f & 7)*16 + (l & 15);
    int rel = f >> 3;
    Wt[idx] = (ushort_t)f2bf(W[rel*16384 + k*FD + col]);
}

// ---------- helpers ----------
__device__ inline float red16(float v){
    v += __shfl_xor(v, 1);
    v += __shfl_xor(v, 2);
    v += __shfl_xor(v, 4);
    v += __shfl_xor(v, 8);
    return v;
}

// ---------- MFMA dual-relation GEMM + fused el/er ----------
// feat(256 cols = rel0|rel1) = Ab(N,128 bf16) @ Wt; 4 waves x 16 rows, 64 MFMA/wave.
// featb stored frag-permuted: stored[row][c*8+j] = logical col j*16+c  (agg reads
// the same uint4 addresses as before; head split becomes register-index split).
template<int H>
__global__ __launch_bounds__(256) void k_gemm_mfma(
        const ushort_t* __restrict__ Ab, const ushort_t* __restrict__ Wt,
        const float* __restrict__ al0, const float* __restrict__ ar0,
        const float* __restrict__ al1, const float* __restrict__ ar1,
        ushort_t* __restrict__ featb0, ushort_t* __restrict__ featb1,
        float* __restrict__ el0, float* __restrict__ er0,
        float* __restrict__ el1, float* __restrict__ er1){
    int t = threadIdx.x;
    int w = t >> 6, l = t & 63;
    int c = l & 15, kgrp = l >> 4;
    const bf16x8* AbV = (const bf16x8*)Ab;
    const bf16x8* WtV = (const bf16x8*)Wt;
    long arow = (long)blockIdx.x*64 + w*16 + c;     // A row this lane supplies
    bf16x8 zero8 = {0,0,0,0,0,0,0,0};
    bf16x8 af[4];
    bool rok = arow < NN;
    #pragma unroll
    for (int ks = 0; ks < 4; ks++)
        af[ks] = rok ? AbV[arow*16 + ks*4 + kgrp] : zero8;
    f32x4 acc[16];
    #pragma unroll
    for (int f = 0; f < 16; f++) acc[f] = (f32x4){0.f,0.f,0.f,0.f};
    #pragma unroll
    for (int f = 0; f < 16; f++){
        #pragma unroll
        for (int ks = 0; ks < 4; ks++){
            acc[f] = __builtin_amdgcn_mfma_f32_16x16x32_bf16(
                         af[ks], WtV[(f*4 + ks)*64 + l], acc[f], 0, 0, 0);
        }
    }
    // epilogue: per lane, attention-vector slices at logical cols f*16+c
    float alv0[8], arv0[8], alv1[8], arv1[8];
    #pragma unroll
    for (int f = 0; f < 8; f++){
        alv0[f] = al0[f*16 + c]; arv0[f] = ar0[f*16 + c];
        alv1[f] = al1[f*16 + c]; arv1[f] = ar1[f*16 + c];
    }
    #pragma unroll
    for (int reg = 0; reg < 4; reg++){
        long orow = (long)blockIdx.x*64 + w*16 + kgrp*4 + reg;  // D row
        bool ok = orow < NN;
        if (ok){
            uint4 p0, p1;
            p0.x = cvtpk(acc[0][reg],  acc[1][reg]);
            p0.y = cvtpk(acc[2][reg],  acc[3][reg]);
            p0.z = cvtpk(acc[4][reg],  acc[5][reg]);
            p0.w = cvtpk(acc[6][reg],  acc[7][reg]);
            p1.x = cvtpk(acc[8][reg],  acc[9][reg]);
            p1.y = cvtpk(acc[10][reg], acc[11][reg]);
            p1.z = cvtpk(acc[12][reg], acc[13][reg]);
            p1.w = cvtpk(acc[14][reg], acc[15][reg]);
            *(uint4*)&featb0[orow*FD + c*8] = p0;
            *(uint4*)&featb1[orow*FD + c*8] = p1;
        }
        if (H == 2){
            float pl00=0, pr00=0, pl01=0, pr01=0;
            float pl10=0, pr10=0, pl11=0, pr11=0;
            #pragma unroll
            for (int f = 0; f < 4; f++){
                pl00 = fmaf(acc[f][reg],    alv0[f],   pl00);
                pr00 = fmaf(acc[f][reg],    arv0[f],   pr00);
                pl01 = fmaf(acc[4+f][reg],  alv0[4+f], pl01);
                pr01 = fmaf(acc[4+f][reg],  arv0[4+f], pr01);
                pl10 = fmaf(acc[8+f][reg],  alv1[f],   pl10);
                pr10 = fmaf(acc[8+f][reg],  arv1[f],   pr10);
                pl11 = fmaf(acc[12+f][reg], alv1[4+f], pl11);
                pr11 = fmaf(acc[12+f][reg], arv1[4+f], pr11);
            }
            pl00 = red16(pl00); pr00 = red16(pr00);
            pl01 = red16(pl01); pr01 = red16(pr01);
            pl10 = red16(pl10); pr10 = red16(pr10);
            pl11 = red16(pl11); pr11 = red16(pr11);
            if (c == 0 && ok){
                el0[orow*2] = pl00; el0[orow*2+1] = pl01;
                er0[orow*2] = pr00; er0[orow*2+1] = pr01;
                el1[orow*2] = pl10; el1[orow*2+1] = pl11;
                er1[orow*2] = pr10; er1[orow*2+1] = pr11;
            }
        } else {
            float pl0=0, pr0=0, pl1=0, pr1=0;
            #pragma unroll
            for (int f = 0; f < 8; f++){
                pl0 = fmaf(acc[f][reg],   alv0[f], pl0);
                pr0 = fmaf(acc[f][reg],   arv0[f], pr0);
                pl1 = fmaf(acc[8+f][reg], alv1[f], pl1);
                pr1 = fmaf(acc[8+f][reg], arv1[f], pr1);
            }
            pl0 = red16(pl0); pr0 = red16(pr0);
            pl1 = red16(pl1); pr1 = red16(pr1);
            if (c == 0 && ok){
                el0[orow] = pl0; er0[orow] = pr0;
                el1[orow] = pl1; er1[orow] = pr1;
            }
        }
    }
}

// ---------- per-relation aggregation core (R5 structure, 4 rows in flight) ----------
// acc[j] covers logical col j*16+sub; H=2: j<4 head0, j>=4 head1 (no lane select).
template<int H>
__device__ inline void agg_one(const int* __restrict__ rowptr, const int* __restrict__ colsrc,
                               const float* __restrict__ el, const float* __restrict__ er,
                               const ushort_t* __restrict__ featb, int node, int lane,
                               float acc[8]){
    int beg = rowptr[node], end = rowptr[node+1];
    float er0 = er[node*H];
    float er1 = (H == 2) ? er[node*H + 1] : 0.f;
    int sub = lane & 15;
    int g   = lane >> 4;
    float s0 = 0.f, s1 = 0.f;
    for (int base = beg; base < end; base += 64){
        int nrem = end - base;
        bool active = lane < nrem;
        int sv = active ? colsrc[base + lane] : 0;
        float a0 = 0.f, a1 = 0.f;
        if (active){
            if (H == 2){
                float2 e2 = *(const float2*)&el[sv*2];
                float e0 = e2.x + er0, e1 = e2.y + er1;
                e0 = (e0 > 0.f) ? e0 : 0.2f*e0;
                e1 = (e1 > 0.f) ? e1 : 0.2f*e1;
                a0 = __expf(e0); a1 = __expf(e1);
            } else {
                float e0 = el[sv] + er0;
                e0 = (e0 > 0.f) ? e0 : 0.2f*e0;
                a0 = __expf(e0);
            }
        }
        s0 += a0;
        if (H == 2) s1 += a1;
        int nn = min(64, nrem);
        for (int j4 = 0; j4 < nn; j4 += 4){
            int slot = j4 + g;
            int sj = __shfl(sv, slot);
            float w0 = __shfl(a0, slot);
            float w1 = (H == 2) ? __shfl(a1, slot) : w0;
            uint4 p = *(const uint4*)&featb[(size_t)sj*FD + sub*8];
            acc[0] = fmaf(w0, __uint_as_float(p.x << 16),         acc[0]);
            acc[1] = fmaf(w0, __uint_as_float(p.x & 0xffff0000u), acc[1]);
            acc[2] = fmaf(w0, __uint_as_float(p.y << 16),         acc[2]);
            acc[3] = fmaf(w0, __uint_as_float(p.y & 0xffff0000u), acc[3]);
            acc[4] = fmaf(w1, __uint_as_float(p.z << 16),         acc[4]);
            acc[5] = fmaf(w1, __uint_as_float(p.z & 0xffff0000u), acc[5]);
            acc[6] = fmaf(w1, __uint_as_float(p.w << 16),         acc[6]);
            acc[7] = fmaf(w1, __uint_as_float(p.w & 0xffff0000u), acc[7]);
        }
    }
    #pragma unroll
    for (int off = 32; off > 0; off >>= 1){
        s0 += __shfl_xor(s0, off);
        if (H == 2) s1 += __shfl_xor(s1, off);
    }
    float i0 = (end > beg) ? 1.f/s0 : 0.f;
    float i1 = (H == 2) ? ((end > beg) ? 1.f/s1 : 0.f) : i0;
    #pragma unroll
    for (int j = 0; j < 4; j++) acc[j] *= i0;
    #pragma unroll
    for (int j = 4; j < 8; j++) acc[j] *= i1;
}

// ---------- fused both-relations aggregation: one wave per dst node ----------
// H=2 writes bf16 relu(h1) in the permuted layout (next GEMM's A); H=1 writes fp32 out.
template<int H>
__global__ __launch_bounds__(256) void k_agg2(
                       const int* __restrict__ rowptr0, const int* __restrict__ colsrc0,
                       const int* __restrict__ rowptr1, const int* __restrict__ colsrc1,
                       const float* __restrict__ el0, const float* __restrict__ er0,
                       const float* __restrict__ el1, const float* __restrict__ er1,
                       const ushort_t* __restrict__ featb0, const ushort_t* __restrict__ featb1,
                       const float* __restrict__ bias0, const float* __restrict__ bias1,
                       ushort_t* __restrict__ outb, float* __restrict__ outf){
    int node = (blockIdx.x * blockDim.x + threadIdx.x) >> 6;
    int lane = threadIdx.x & 63;
    if (node >= NN) return;
    float a0[8] = {0.f,0.f,0.f,0.f,0.f,0.f,0.f,0.f};
    float a1[8] = {0.f,0.f,0.f,0.f,0.f,0.f,0.f,0.f};
    agg_one<H>(rowptr0, colsrc0, el0, er0, featb0, node, lane, a0);
    agg_one<H>(rowptr1, colsrc1, el1, er1, featb1, node, lane, a1);
    #pragma unroll
    for (int i = 0; i < 8; i++){
        a0[i] += __shfl_xor(a0[i], 16);
        a0[i] += __shfl_xor(a0[i], 32);
        a1[i] += __shfl_xor(a1[i], 16);
        a1[i] += __shfl_xor(a1[i], 32);
    }
    if (lane < 16){
        int sub = lane;
        float v[8];
        #pragma unroll
        for (int j = 0; j < 8; j++)
            v[j] = 0.5f*(a0[j] + a1[j] + bias0[j*16 + sub] + bias1[j*16 + sub]);
        if (H == 2){
            #pragma unroll
            for (int j = 0; j < 8; j++) v[j] = fmaxf(v[j], 0.f);
            uint4 o;
            o.x = cvtpk(v[0], v[1]); o.y = cvtpk(v[2], v[3]);
            o.z = cvtpk(v[4], v[5]); o.w = cvtpk(v[6], v[7]);
            *(uint4*)&outb[(size_t)node*FD + sub*8] = o;
        } else {
            #pragma unroll
            for (int j = 0; j < 8; j++)
                outf[(size_t)node*FD + j*16 + sub] = v[j];
        }
    }
}

// ---------- launch ----------
extern "C" void kernel_launch(void* const* d_in, const int* in_sizes, int n_in,
                              void* d_out, int out_size, void* d_ws, size_t ws_size,
                              hipStream_t stream){
    const float* x   = (const float*)d_in[0];
    const float* W1  = (const float*)d_in[1];
    const float* al1 = (const float*)d_in[2];
    const float* ar1 = (const float*)d_in[3];
    const float* b1  = (const float*)d_in[4];
    const float* W2  = (const float*)d_in[5];
    const float* al2 = (const float*)d_in[6];
    const float* ar2 = (const float*)d_in[7];
    const float* b2  = (const float*)d_in[8];
    const int*   src = (const int*)d_in[9];
    const int*   dst = (const int*)d_in[10];
    float* out = (float*)d_out;

    size_t off = 0;
    auto carve = [&](size_t bytes) -> char* {
        char* p = (char*)d_ws + off;
        off += (bytes + 255) & ~(size_t)255;
        return p;
    };
    ushort_t* xb     = (ushort_t*)carve((size_t)NN * FD * 2);
    ushort_t* h1b    = (ushort_t*)carve((size_t)NN * FD * 2);
    ushort_t* featb0 = (ushort_t*)carve((size_t)NN * FD * 2);
    ushort_t* featb1 = (ushort_t*)carve((size_t)NN * FD * 2);
    ushort_t* Wt1    = (ushort_t*)carve(32768 * 2);
    ushort_t* Wt2    = (ushort_t*)carve(32768 * 2);
    float* el0      = (float*)carve((size_t)NN * 2 * 4);
    float* er0      = (float*)carve((size_t)NN * 2 * 4);
    float* el1      = (float*)carve((size_t)NN * 2 * 4);
    float* er1      = (float*)carve((size_t)NN * 2 * 4);
    int*   rowptr0  = (int*)  carve((size_t)(NN + 1) * 4);
    int*   rowptr1  = (int*)  carve((size_t)(NN + 1) * 4);
    int*   colsrc0  = (int*)  carve((size_t)NE * 4);
    int*   colsrc1  = (int*)  carve((size_t)NE * 4);
    int*   counts   = (int*)  carve((size_t)NN * 4);
    int*   cursor   = (int*)  carve((size_t)NN * 4);
    int*   partials = (int*)  carve(1024);
    if (off > ws_size) return;

    const int EB = (NE + 255) / 256;
    const int NB = (NN + SCAN_TILE - 1) / SCAN_TILE;
    const int GB = (NN + 63) / 64;      // 1563 MFMA-GEMM blocks
    const int WB = NN / 4;              // agg: 4 waves/block, 1 wave per node
    const int CB = (NN * FD / 8 + 255) / 256;

    int* rowptrs[2] = {rowptr0, rowptr1};
    int* colsrcs[2] = {colsrc0, colsrc1};

    // prep: casts + W repack (independent of CSR)
    k_cast<<<CB, 256, 0, stream>>>(x, xb, NN * FD / 8);
    k_prepw<<<128, 256, 0, stream>>>(W1, Wt1, 0);
    k_prepw<<<128, 256, 0, stream>>>(W2, Wt2, 1);

    // build CSR per relation (shared by both layers); adjacency stores src ids
    for (int r = 0; r < 2; r++){
        const int* dstr = dst + (size_t)r * NE;
        const int* srcr = src + (size_t)r * NE;
        hipMemsetAsync(counts, 0, (size_t)NN * 4, stream);
        k_hist<<<EB, 256, 0, stream>>>(dstr, counts);
        k_scan_partial<<<NB, 256, 0, stream>>>(counts, NN, partials);
        k_scan_partials_excl<<<1, 256, 0, stream>>>(partials, NB);
        k_scan_final<<<NB, 256, 0, stream>>>(counts, NN, partials, rowptrs[r]);
        hipMemcpyAsync(cursor, rowptrs[r], (size_t)NN * 4, hipMemcpyDeviceToDevice, stream);
        k_scatter<<<EB, 256, 0, stream>>>(dstr, srcr, cursor, colsrcs[r]);
    }

    // layer 1: H=2 (both relations in one GEMM; agg writes bf16 relu(h1))
    k_gemm_mfma<2><<<GB, 256, 0, stream>>>(xb, Wt1, al1, ar1, al1 + FD, ar1 + FD,
                                           featb0, featb1, el0, er0, el1, er1);
    k_agg2<2><<<WB, 256, 0, stream>>>(rowptr0, colsrc0, rowptr1, colsrc1,
                                      el0, er0, el1, er1, featb0, featb1,
                                      b1, b1 + FD, h1b, nullptr);

    // layer 2: H=1 (W2 rows pre-permuted to absorb h1b's layout)
    k_gemm_mfma<1><<<GB, 256, 0, stream>>>(h1b, Wt2, al2, ar2, al2 + FD, ar2 + FD,
                                           featb0, featb1, el0, er0, el1, er1);
    k_agg2<1><<<WB, 256, 0, stream>>>(rowptr0, colsrc0, rowptr1, colsrc1,
                                      el0, er0, el1, er1, featb0, featb1,
                                      b2, b2 + FD, nullptr, out);
}

// Round 8
// 460.396 us; speedup vs baseline: 1.2893x; 1.0227x over previous
//
#include <hip/hip_runtime.h>
#include <hip/hip_bf16.h>
#include <math.h>

#define NN 100000     // nodes
#define NE 800000     // edges per relation
#define FD 128        // feature dim

typedef unsigned short ushort_t;
typedef __attribute__((ext_vector_type(8))) short bf16x8;
typedef __attribute__((ext_vector_type(4))) float f32x4;

// ---------- bf16 pack helpers ----------
__device__ inline unsigned f2bf(float f){              // software RNE (prep kernels)
    unsigned u = __float_as_uint(f);
    return (u + 0x7fffu + ((u >> 16) & 1u)) >> 16;
}
__device__ inline unsigned pk(float a, float b){
    return f2bf(a) | (f2bf(b) << 16);
}
__device__ inline unsigned cvtpk(float lo, float hi){  // HW packed cvt (1 inst)
    unsigned r;
    asm("v_cvt_pk_bf16_f32 %0, %1, %2" : "=v"(r) : "v"(lo), "v"(hi));
    return r;
}
__device__ inline float blo(unsigned p){ return __uint_as_float(p << 16); }
__device__ inline float bhi(unsigned p){ return __uint_as_float(p & 0xffff0000u); }

// ---------- CSR build (both relations in one pass; unified index space) ----------
// counts/rowptr index: rel*NN + node; colsrc is 2*NE with rel1 offsets automatic.
__global__ void k_hist2(const int* __restrict__ dst, int* __restrict__ counts){
    int i = blockIdx.x * blockDim.x + threadIdx.x;
    if (i < 2*NE){
        int idx = dst[i] + ((i >= NE) ? NN : 0);
        atomicAdd(&counts[idx], 1);
    }
}

#define SCAN_TILE 1024
__global__ void k_scan_partial(const int* __restrict__ counts, int n, int* __restrict__ partials){
    __shared__ int sm[256];
    int base = blockIdx.x * SCAN_TILE;
    int t = threadIdx.x;
    int s = 0;
    #pragma unroll
    for (int j = 0; j < 4; j++){
        int idx = base + t*4 + j;
        if (idx < n) s += counts[idx];
    }
    sm[t] = s; __syncthreads();
    for (int off = 128; off > 0; off >>= 1){
        if (t < off) sm[t] += sm[t+off];
        __syncthreads();
    }
    if (t == 0) partials[blockIdx.x] = sm[0];
}

__global__ void k_scan_partials_excl(int* partials, int nb){
    __shared__ int sm[256];
    int t = threadIdx.x;
    int v = (t < nb) ? partials[t] : 0;
    sm[t] = v; __syncthreads();
    for (int off = 1; off < 256; off <<= 1){
        int add = (t >= off) ? sm[t-off] : 0;
        __syncthreads();
        sm[t] += add;
        __syncthreads();
    }
    if (t < nb) partials[t] = sm[t] - v;   // exclusive
}

__global__ void k_scan_final(const int* __restrict__ counts, int n, int tot,
                             const int* __restrict__ partials, int* __restrict__ rowptr){
    __shared__ int sm[256];
    int base = blockIdx.x * SCAN_TILE;
    int t = threadIdx.x;
    int v[4]; int s = 0;
    #pragma unroll
    for (int j = 0; j < 4; j++){
        int idx = base + t*4 + j;
        v[j] = (idx < n) ? counts[idx] : 0;
        s += v[j];
    }
    sm[t] = s; __syncthreads();
    for (int off = 1; off < 256; off <<= 1){
        int add = (t >= off) ? sm[t-off] : 0;
        __syncthreads();
        sm[t] += add;
        __syncthreads();
    }
    int excl = sm[t] - s + partials[blockIdx.x];
    #pragma unroll
    for (int j = 0; j < 4; j++){
        int idx = base + t*4 + j;
        if (idx < n) rowptr[idx] = excl;
        excl += v[j];
    }
    if (blockIdx.x == 0 && t == 0) rowptr[n] = tot;
}

__global__ void k_scatter2(const int* __restrict__ dst, const int* __restrict__ src,
                           int* __restrict__ cursor, int* __restrict__ colsrc){
    int i = blockIdx.x * blockDim.x + threadIdx.x;
    if (i < 2*NE){
        int idx = dst[i] + ((i >= NE) ? NN : 0);
        int p = atomicAdd(&cursor[idx], 1);
        colsrc[p] = src[i];
    }
}

// ---------- prep: x -> bf16 ----------
__global__ void k_cast(const float* __restrict__ in, ushort_t* __restrict__ out, int n8){
    int i = blockIdx.x * blockDim.x + threadIdx.x;
    if (i < n8){
        float4 u = ((const float4*)in)[i*2];
        float4 v = ((const float4*)in)[i*2 + 1];
        uint4 o;
        o.x = pk(u.x, u.y); o.y = pk(u.z, u.w);
        o.z = pk(v.x, v.y); o.w = pk(v.z, v.w);
        ((uint4*)out)[i] = o;
    }
}

// ---------- prep: W (2 rel x 128x128 fp32) -> B-fragment-linear bf16 ----------
__global__ void k_prepw(const float* __restrict__ W, ushort_t* __restrict__ Wt, int perm){
    int idx = blockIdx.x * blockDim.x + threadIdx.x;   // 32768 total
    if (idx >= 32768) return;
    int j  = idx & 7;
    int l  = (idx >> 3) & 63;
    int ks = (idx >> 9) & 3;
    int f  = idx >> 11;
    int k  = ks*32 + (l >> 4)*8 + j;
    if (perm) k = (k & 7)*16 + (k >> 3);
    int col = (f & 7)*16 + (l & 15);
    int rel = f >> 3;
    Wt[idx] = (ushort_t)f2bf(W[rel*16384 + k*FD + col]);
}

// ---------- helpers ----------
__device__ inline float red16(float v){
    v += __shfl_xor(v, 1);
    v += __shfl_xor(v, 2);
    v += __shfl_xor(v, 4);
    v += __shfl_xor(v, 8);
    return v;
}

// ---------- MFMA dual-relation GEMM + fused el/er (unchanged from R7) ----------
template<int H>
__global__ __launch_bounds__(256) void k_gemm_mfma(
        const ushort_t* __restrict__ Ab, const ushort_t* __restrict__ Wt,
        const float* __restrict__ al0, const float* __restrict__ ar0,
        const float* __restrict__ al1, const float* __restrict__ ar1,
        ushort_t* __restrict__ featb0, ushort_t* __restrict__ featb1,
        float* __restrict__ el0, float* __restrict__ er0,
        float* __restrict__ el1, float* __restrict__ er1){
    int t = threadIdx.x;
    int w = t >> 6, l = t & 63;
    int c = l & 15, kgrp = l >> 4;
    const bf16x8* AbV = (const bf16x8*)Ab;
    const bf16x8* WtV = (const bf16x8*)Wt;
    long arow = (long)blockIdx.x*64 + w*16 + c;
    bf16x8 zero8 = {0,0,0,0,0,0,0,0};
    bf16x8 af[4];
    bool rok = arow < NN;
    #pragma unroll
    for (int ks = 0; ks < 4; ks++)
        af[ks] = rok ? AbV[arow*16 + ks*4 + kgrp] : zero8;
    f32x4 acc[16];
    #pragma unroll
    for (int f = 0; f < 16; f++) acc[f] = (f32x4){0.f,0.f,0.f,0.f};
    #pragma unroll
    for (int f = 0; f < 16; f++){
        #pragma unroll
        for (int ks = 0; ks < 4; ks++){
            acc[f] = __builtin_amdgcn_mfma_f32_16x16x32_bf16(
                         af[ks], WtV[(f*4 + ks)*64 + l], acc[f], 0, 0, 0);
        }
    }
    float alv0[8], arv0[8], alv1[8], arv1[8];
    #pragma unroll
    for (int f = 0; f < 8; f++){
        alv0[f] = al0[f*16 + c]; arv0[f] = ar0[f*16 + c];
        alv1[f] = al1[f*16 + c]; arv1[f] = ar1[f*16 + c];
    }
    #pragma unroll
    for (int reg = 0; reg < 4; reg++){
        long orow = (long)blockIdx.x*64 + w*16 + kgrp*4 + reg;
        bool ok = orow < NN;
        if (ok){
            uint4 p0, p1;
            p0.x = cvtpk(acc[0][reg],  acc[1][reg]);
            p0.y = cvtpk(acc[2][reg],  acc[3][reg]);
            p0.z = cvtpk(acc[4][reg],  acc[5][reg]);
            p0.w = cvtpk(acc[6][reg],  acc[7][reg]);
            p1.x = cvtpk(acc[8][reg],  acc[9][reg]);
            p1.y = cvtpk(acc[10][reg], acc[11][reg]);
            p1.z = cvtpk(acc[12][reg], acc[13][reg]);
            p1.w = cvtpk(acc[14][reg], acc[15][reg]);
            *(uint4*)&featb0[orow*FD + c*8] = p0;
            *(uint4*)&featb1[orow*FD + c*8] = p1;
        }
        if (H == 2){
            float pl00=0, pr00=0, pl01=0, pr01=0;
            float pl10=0, pr10=0, pl11=0, pr11=0;
            #pragma unroll
            for (int f = 0; f < 4; f++){
                pl00 = fmaf(acc[f][reg],    alv0[f],   pl00);
                pr00 = fmaf(acc[f][reg],    arv0[f],   pr00);
                pl01 = fmaf(acc[4+f][reg],  alv0[4+f], pl01);
                pr01 = fmaf(acc[4+f][reg],  arv0[4+f], pr01);
                pl10 = fmaf(acc[8+f][reg],  alv1[f],   pl10);
                pr10 = fmaf(acc[8+f][reg],  arv1[f],   pr10);
                pl11 = fmaf(acc[12+f][reg], alv1[4+f], pl11);
                pr11 = fmaf(acc[12+f][reg], arv1[4+f], pr11);
            }
            pl00 = red16(pl00); pr00 = red16(pr00);
            pl01 = red16(pl01); pr01 = red16(pr01);
            pl10 = red16(pl10); pr10 = red16(pr10);
            pl11 = red16(pl11); pr11 = red16(pr11);
            if (c == 0 && ok){
                el0[orow*2] = pl00; el0[orow*2+1] = pl01;
                er0[orow*2] = pr00; er0[orow*2+1] = pr01;
                el1[orow*2] = pl10; el1[orow*2+1] = pl11;
                er1[orow*2] = pr10; er1[orow*2+1] = pr11;
            }
        } else {
            float pl0=0, pr0=0, pl1=0, pr1=0;
            #pragma unroll
            for (int f = 0; f < 8; f++){
                pl0 = fmaf(acc[f][reg],   alv0[f], pl0);
                pr0 = fmaf(acc[f][reg],   arv0[f], pr0);
                pl1 = fmaf(acc[8+f][reg], alv1[f], pl1);
                pr1 = fmaf(acc[8+f][reg], arv1[f], pr1);
            }
            pl0 = red16(pl0); pr0 = red16(pr0);
            pl1 = red16(pl1); pr1 = red16(pr1);
            if (c == 0 && ok){
                el0[orow] = pl0; er0[orow] = pr0;
                el1[orow] = pl1; er1[orow] = pr1;
            }
        }
    }
}

// ---------- fused aggregation: one wave per node, BOTH relation walks interleaved ----
// Per j4 iteration: 2 independent gathers (one per relation) in flight; both
// prologue chains (colsrc load -> el gather -> exp) overlap. acc layout as R7:
// acc[j] = logical col j*16+sub; H=2: j<4 head0, j>=4 head1.
template<int H>
__global__ __launch_bounds__(256) void k_agg2(
                       const int* __restrict__ rowptr,   // 2*NN+1, rel1 at +NN
                       const int* __restrict__ colsrc,   // 2*NE unified
                       const float* __restrict__ el0, const float* __restrict__ er0,
                       const float* __restrict__ el1, const float* __restrict__ er1,
                       const ushort_t* __restrict__ featb0, const ushort_t* __restrict__ featb1,
                       const float* __restrict__ bias0, const float* __restrict__ bias1,
                       ushort_t* __restrict__ outb, float* __restrict__ outf){
    int node = (blockIdx.x * blockDim.x + threadIdx.x) >> 6;
    int lane = threadIdx.x & 63;
    if (node >= NN) return;
    int sub = lane & 15, g = lane >> 4;
    int base0 = rowptr[node],        end0 = rowptr[node+1];
    int base1 = rowptr[NN + node],   end1 = rowptr[NN + node + 1];
    bool has0 = end0 > base0, has1 = end1 > base1;
    float er00 = er0[node*H];
    float er01 = (H == 2) ? er0[node*H + 1] : 0.f;
    float er10 = er1[node*H];
    float er11 = (H == 2) ? er1[node*H + 1] : 0.f;
    float acc0[8] = {0.f,0.f,0.f,0.f,0.f,0.f,0.f,0.f};
    float acc1[8] = {0.f,0.f,0.f,0.f,0.f,0.f,0.f,0.f};
    float s00=0.f, s01=0.f, s10=0.f, s11=0.f;
    while (base0 < end0 || base1 < end1){
        int nrem0 = end0 - base0, nrem1 = end1 - base1;
        bool act0 = lane < nrem0, act1 = lane < nrem1;
        int sv0 = act0 ? colsrc[base0 + lane] : 0;
        int sv1 = act1 ? colsrc[base1 + lane] : 0;
        float a00=0.f, a01=0.f, a10=0.f, a11=0.f;
        if (act0){
            if (H == 2){
                float2 e2 = *(const float2*)&el0[sv0*2];
                float e0 = e2.x + er00, e1 = e2.y + er01;
                e0 = (e0 > 0.f) ? e0 : 0.2f*e0;
                e1 = (e1 > 0.f) ? e1 : 0.2f*e1;
                a00 = __expf(e0); a01 = __expf(e1);
            } else {
                float e0 = el0[sv0] + er00;
                e0 = (e0 > 0.f) ? e0 : 0.2f*e0;
                a00 = __expf(e0);
            }
        }
        if (act1){
            if (H == 2){
                float2 e2 = *(const float2*)&el1[sv1*2];
                float e0 = e2.x + er10, e1 = e2.y + er11;
                e0 = (e0 > 0.f) ? e0 : 0.2f*e0;
                e1 = (e1 > 0.f) ? e1 : 0.2f*e1;
                a10 = __expf(e0); a11 = __expf(e1);
            } else {
                float e0 = el1[sv1] + er10;
                e0 = (e0 > 0.f) ? e0 : 0.2f*e0;
                a10 = __expf(e0);
            }
        }
        s00 += a00; s01 += a01; s10 += a10; s11 += a11;
        int nn0 = (nrem0 > 0) ? min(64, nrem0) : 0;
        int nn1 = (nrem1 > 0) ? min(64, nrem1) : 0;
        int nnm = (nn0 > nn1) ? nn0 : nn1;
        for (int j4 = 0; j4 < nnm; j4 += 4){
            int slot = j4 + g;
            int sj0 = __shfl(sv0, slot);
            int sj1 = __shfl(sv1, slot);
            float w00 = __shfl(a00, slot);
            float w01 = (H == 2) ? __shfl(a01, slot) : w00;
            float w10 = __shfl(a10, slot);
            float w11 = (H == 2) ? __shfl(a11, slot) : w10;
            uint4 p0 = *(const uint4*)&featb0[(unsigned)sj0*FD + sub*8];
            uint4 p1 = *(const uint4*)&featb1[(unsigned)sj1*FD + sub*8];
            acc0[0] = fmaf(w00, blo(p0.x), acc0[0]);
            acc0[1] = fmaf(w00, bhi(p0.x), acc0[1]);
            acc0[2] = fmaf(w00, blo(p0.y), acc0[2]);
            acc0[3] = fmaf(w00, bhi(p0.y), acc0[3]);
            acc0[4] = fmaf(w01, blo(p0.z), acc0[4]);
            acc0[5] = fmaf(w01, bhi(p0.z), acc0[5]);
            acc0[6] = fmaf(w01, blo(p0.w), acc0[6]);
            acc0[7] = fmaf(w01, bhi(p0.w), acc0[7]);
            acc1[0] = fmaf(w10, blo(p1.x), acc1[0]);
            acc1[1] = fmaf(w10, bhi(p1.x), acc1[1]);
            acc1[2] = fmaf(w10, blo(p1.y), acc1[2]);
            acc1[3] = fmaf(w10, bhi(p1.y), acc1[3]);
            acc1[4] = fmaf(w11, blo(p1.z), acc1[4]);
            acc1[5] = fmaf(w11, bhi(p1.z), acc1[5]);
            acc1[6] = fmaf(w11, blo(p1.w), acc1[6]);
            acc1[7] = fmaf(w11, bhi(p1.w), acc1[7]);
        }
        base0 += 64; base1 += 64;
    }
    #pragma unroll
    for (int off = 32; off > 0; off >>= 1){
        s00 += __shfl_xor(s00, off);
        s10 += __shfl_xor(s10, off);
        if (H == 2){ s01 += __shfl_xor(s01, off); s11 += __shfl_xor(s11, off); }
    }
    float i00 = has0 ? 1.f/s00 : 0.f;
    float i01 = (H == 2) ? (has0 ? 1.f/s01 : 0.f) : i00;
    float i10 = has1 ? 1.f/s10 : 0.f;
    float i11 = (H == 2) ? (has1 ? 1.f/s11 : 0.f) : i10;
    #pragma unroll
    for (int j = 0; j < 4; j++){
        acc0[j]   *= i00; acc0[j+4] *= i01;
        acc1[j]   *= i10; acc1[j+4] *= i11;
    }
    #pragma unroll
    for (int i = 0; i < 8; i++){
        acc0[i] += __shfl_xor(acc0[i], 16);
        acc0[i] += __shfl_xor(acc0[i], 32);
        acc1[i] += __shfl_xor(acc1[i], 16);
        acc1[i] += __shfl_xor(acc1[i], 32);
    }
    if (lane < 16){
        float v[8];
        #pragma unroll
        for (int j = 0; j < 8; j++)
            v[j] = 0.5f*(acc0[j] + acc1[j] + bias0[j*16 + sub] + bias1[j*16 + sub]);
        if (H == 2){
            #pragma unroll
            for (int j = 0; j < 8; j++) v[j] = fmaxf(v[j], 0.f);
            uint4 o;
            o.x = cvtpk(v[0], v[1]); o.y = cvtpk(v[2], v[3]);
            o.z = cvtpk(v[4], v[5]); o.w = cvtpk(v[6], v[7]);
            *(uint4*)&outb[(size_t)node*FD + sub*8] = o;
        } else {
            #pragma unroll
            for (int j = 0; j < 8; j++)
                outf[(size_t)node*FD + j*16 + sub] = v[j];
        }
    }
}

// ---------- launch ----------
extern "C" void kernel_launch(void* const* d_in, const int* in_sizes, int n_in,
                              void* d_out, int out_size, void* d_ws, size_t ws_size,
                              hipStream_t stream){
    const float* x   = (const float*)d_in[0];
    const float* W1  = (const float*)d_in[1];
    const float* al1 = (const float*)d_in[2];
    const float* ar1 = (const float*)d_in[3];
    const float* b1  = (const float*)d_in[4];
    const float* W2  = (const float*)d_in[5];
    const float* al2 = (const float*)d_in[6];
    const float* ar2 = (const float*)d_in[7];
    const float* b2  = (const float*)d_in[8];
    const int*   src = (const int*)d_in[9];
    const int*   dst = (const int*)d_in[10];
    float* out = (float*)d_out;

    size_t off = 0;
    auto carve = [&](size_t bytes) -> char* {
        char* p = (char*)d_ws + off;
        off += (bytes + 255) & ~(size_t)255;
        return p;
    };
    ushort_t* xb     = (ushort_t*)carve((size_t)NN * FD * 2);
    ushort_t* h1b    = (ushort_t*)carve((size_t)NN * FD * 2);
    ushort_t* featb0 = (ushort_t*)carve((size_t)NN * FD * 2);
    ushort_t* featb1 = (ushort_t*)carve((size_t)NN * FD * 2);
    ushort_t* Wt1    = (ushort_t*)carve(32768 * 2);
    ushort_t* Wt2    = (ushort_t*)carve(32768 * 2);
    float* el0      = (float*)carve((size_t)NN * 2 * 4);
    float* er0      = (float*)carve((size_t)NN * 2 * 4);
    float* el1      = (float*)carve((size_t)NN * 2 * 4);
    float* er1      = (float*)carve((size_t)NN * 2 * 4);
    int*   rowptrA  = (int*)  carve((size_t)(2*NN + 1) * 4);
    int*   colsrcA  = (int*)  carve((size_t)2*NE * 4);
    int*   counts   = (int*)  carve((size_t)2*NN * 4);
    int*   cursor   = (int*)  carve((size_t)2*NN * 4);
    int*   partials = (int*)  carve(1024);
    if (off > ws_size) return;

    const int EB2 = (2*NE + 255) / 256;                    // 6250
    const int NB2 = (2*NN + SCAN_TILE - 1) / SCAN_TILE;    // 196
    const int GB  = (NN + 63) / 64;                        // 1563
    const int WB  = NN / 4;                                // agg: 4 waves/block
    const int CB  = (NN * FD / 8 + 255) / 256;

    // prep: casts + W repack (independent of CSR)
    k_cast<<<CB, 256, 0, stream>>>(x, xb, NN * FD / 8);
    k_prepw<<<128, 256, 0, stream>>>(W1, Wt1, 0);
    k_prepw<<<128, 256, 0, stream>>>(W2, Wt2, 1);

    // build CSR for both relations in one pass (shared by both layers)
    hipMemsetAsync(counts, 0, (size_t)2*NN * 4, stream);
    k_hist2<<<EB2, 256, 0, stream>>>(dst, counts);
    k_scan_partial<<<NB2, 256, 0, stream>>>(counts, 2*NN, partials);
    k_scan_partials_excl<<<1, 256, 0, stream>>>(partials, NB2);
    k_scan_final<<<NB2, 256, 0, stream>>>(counts, 2*NN, 2*NE, partials, rowptrA);
    hipMemcpyAsync(cursor, rowptrA, (size_t)2*NN * 4, hipMemcpyDeviceToDevice, stream);
    k_scatter2<<<EB2, 256, 0, stream>>>(dst, src, cursor, colsrcA);

    // layer 1: H=2 (both relations in one GEMM; agg writes bf16 relu(h1))
    k_gemm_mfma<2><<<GB, 256, 0, stream>>>(xb, Wt1, al1, ar1, al1 + FD, ar1 + FD,
                                           featb0, featb1, el0, er0, el1, er1);
    k_agg2<2><<<WB, 256, 0, stream>>>(rowptrA, colsrcA,
                                      el0, er0, el1, er1, featb0, featb1,
                                      b1, b1 + FD, h1b, nullptr);

    // layer 2: H=1 (W2 rows pre-permuted to absorb h1b's layout)
    k_gemm_mfma<1><<<GB, 256, 0, stream>>>(h1b, Wt2, al2, ar2, al2 + FD, ar2 + FD,
                                           featb0, featb1, el0, er0, el1, er1);
    k_agg2<1><<<WB, 256, 0, stream>>>(rowptrA, colsrcA,
                                      el0, er0, el1, er1, featb0, featb1,
                                      b2, b2 + FD, nullptr, out);
}

// Round 9
// 410.086 us; speedup vs baseline: 1.4475x; 1.1227x over previous
//
#include <hip/hip_runtime.h>
#include <hip/hip_bf16.h>
#include <math.h>

#define NN 100000     // nodes
#define NE 800000     // edges per relation
#define FD 128        // feature dim

#define BKW 512       // bucket width in (unified) dst-node space
#define NBK 391       // ceil(2*NN / BKW)
#define CHUNK 8192    // edges per partition block

typedef unsigned short ushort_t;
typedef __attribute__((ext_vector_type(8))) short bf16x8;
typedef __attribute__((ext_vector_type(4))) float f32x4;

// ---------- bf16 pack helpers ----------
__device__ inline unsigned f2bf(float f){              // software RNE (prep kernels)
    unsigned u = __float_as_uint(f);
    return (u + 0x7fffu + ((u >> 16) & 1u)) >> 16;
}
__device__ inline unsigned pk(float a, float b){
    return f2bf(a) | (f2bf(b) << 16);
}
__device__ inline unsigned cvtpk(float lo, float hi){  // HW packed cvt (1 inst)
    unsigned r;
    asm("v_cvt_pk_bf16_f32 %0, %1, %2" : "=v"(r) : "v"(lo), "v"(hi));
    return r;
}
__device__ inline float blo(unsigned p){ return __uint_as_float(p << 16); }
__device__ inline float bhi(unsigned p){ return __uint_as_float(p & 0xffff0000u); }

// ---------- CSR build: histogram over unified dst space ----------
__global__ void k_hist2(const int* __restrict__ dst, int* __restrict__ counts){
    int i = blockIdx.x * blockDim.x + threadIdx.x;
    if (i < 2*NE){
        int idx = dst[i] + ((i >= NE) ? NN : 0);
        atomicAdd(&counts[idx], 1);
    }
}

#define SCAN_TILE 1024
__global__ void k_scan_partial(const int* __restrict__ counts, int n, int* __restrict__ partials){
    __shared__ int sm[256];
    int base = blockIdx.x * SCAN_TILE;
    int t = threadIdx.x;
    int s = 0;
    #pragma unroll
    for (int j = 0; j < 4; j++){
        int idx = base + t*4 + j;
        if (idx < n) s += counts[idx];
    }
    sm[t] = s; __syncthreads();
    for (int off = 128; off > 0; off >>= 1){
        if (t < off) sm[t] += sm[t+off];
        __syncthreads();
    }
    if (t == 0) partials[blockIdx.x] = sm[0];
}

__global__ void k_scan_partials_excl(int* partials, int nb){
    __shared__ int sm[256];
    int t = threadIdx.x;
    int v = (t < nb) ? partials[t] : 0;
    sm[t] = v; __syncthreads();
    for (int off = 1; off < 256; off <<= 1){
        int add = (t >= off) ? sm[t-off] : 0;
        __syncthreads();
        sm[t] += add;
        __syncthreads();
    }
    if (t < nb) partials[t] = sm[t] - v;   // exclusive
}

__global__ void k_scan_final(const int* __restrict__ counts, int n, int tot,
                             const int* __restrict__ partials, int* __restrict__ rowptr){
    __shared__ int sm[256];
    int base = blockIdx.x * SCAN_TILE;
    int t = threadIdx.x;
    int v[4]; int s = 0;
    #pragma unroll
    for (int j = 0; j < 4; j++){
        int idx = base + t*4 + j;
        v[j] = (idx < n) ? counts[idx] : 0;
        s += v[j];
    }
    sm[t] = s; __syncthreads();
    for (int off = 1; off < 256; off <<= 1){
        int add = (t >= off) ? sm[t-off] : 0;
        __syncthreads();
        sm[t] += add;
        __syncthreads();
    }
    int excl = sm[t] - s + partials[blockIdx.x];
    #pragma unroll
    for (int j = 0; j < 4; j++){
        int idx = base + t*4 + j;
        if (idx < n) rowptr[idx] = excl;
        excl += v[j];
    }
    if (blockIdx.x == 0 && t == 0) rowptr[n] = tot;
}

// bucket bases/cursors from rowptr (buckets are contiguous node ranges)
__global__ void k_bcur(const int* __restrict__ rowptr, int* __restrict__ bbase,
                       int* __restrict__ bcur){
    int t = blockIdx.x * blockDim.x + threadIdx.x;
    if (t <= NBK){
        int node = t * BKW; if (node > 2*NN) node = 2*NN;
        int v = rowptr[node];
        bbase[t] = v;
        if (t < NBK) bcur[t] = v;
    }
}

// ---------- pass B: stable partition into NBK buckets, coalesced pair writes ----
__global__ __launch_bounds__(256) void k_part(const int* __restrict__ dst,
                                              const int* __restrict__ src,
                                              int* __restrict__ bcur,
                                              uint2* __restrict__ ebuf){
    __shared__ int lcount[NBK];
    __shared__ int lbase[NBK];
    int t = threadIdx.x;
    long base = (long)blockIdx.x * CHUNK;
    for (int j = t; j < NBK; j += 256) lcount[j] = 0;
    __syncthreads();
    #pragma unroll 4
    for (int k = 0; k < CHUNK/256; k++){
        long i = base + k*256 + t;
        if (i < 2*NE){
            int b = (dst[i] + ((i >= NE) ? NN : 0)) >> 9;
            atomicAdd(&lcount[b], 1);
        }
    }
    __syncthreads();
    for (int j = t; j < NBK; j += 256){
        int c = lcount[j];
        lbase[j] = c ? atomicAdd(&bcur[j], c) : 0;
    }
    __syncthreads();
    for (int j = t; j < NBK; j += 256) lcount[j] = 0;
    __syncthreads();
    #pragma unroll 4
    for (int k = 0; k < CHUNK/256; k++){
        long i = base + k*256 + t;
        if (i < 2*NE){
            int dstU = dst[i] + ((i >= NE) ? NN : 0);
            int b = dstU >> 9;
            int r = atomicAdd(&lcount[b], 1);
            ebuf[lbase[b] + r] = make_uint2((unsigned)src[i], (unsigned)dstU);
        }
    }
}

// ---------- pass C: per-bucket scatter; one block owns one colsrc window ----------
__global__ __launch_bounds__(256) void k_bscatter(const uint2* __restrict__ ebuf,
                                                  const int* __restrict__ bbase,
                                                  int* __restrict__ cursor,
                                                  int* __restrict__ colsrc){
    int b = blockIdx.x;
    int lo = bbase[b], hi = bbase[b+1];
    for (int i = lo + threadIdx.x; i < hi; i += 256){
        uint2 e = ebuf[i];
        int p = atomicAdd(&cursor[e.y], 1);
        colsrc[p] = (int)e.x;
    }
}

// ---------- prep: x -> bf16 ----------
__global__ void k_cast(const float* __restrict__ in, ushort_t* __restrict__ out, int n8){
    int i = blockIdx.x * blockDim.x + threadIdx.x;
    if (i < n8){
        float4 u = ((const float4*)in)[i*2];
        float4 v = ((const float4*)in)[i*2 + 1];
        uint4 o;
        o.x = pk(u.x, u.y); o.y = pk(u.z, u.w);
        o.z = pk(v.x, v.y); o.w = pk(v.z, v.w);
        ((uint4*)out)[i] = o;
    }
}

// ---------- prep: W (2 rel x 128x128 fp32) -> B-fragment-linear bf16 ----------
__global__ void k_prepw(const float* __restrict__ W, ushort_t* __restrict__ Wt, int perm){
    int idx = blockIdx.x * blockDim.x + threadIdx.x;   // 32768 total
    if (idx >= 32768) return;
    int j  = idx & 7;
    int l  = (idx >> 3) & 63;
    int ks = (idx >> 9) & 3;
    int f  = idx >> 11;
    int k  = ks*32 + (l >> 4)*8 + j;
    if (perm) k = (k & 7)*16 + (k >> 3);
    int col = (f & 7)*16 + (l & 15);
    int rel = f >> 3;
    Wt[idx] = (ushort_t)f2bf(W[rel*16384 + k*FD + col]);
}

// ---------- helpers ----------
__device__ inline float red16(float v){
    v += __shfl_xor(v, 1);
    v += __shfl_xor(v, 2);
    v += __shfl_xor(v, 4);
    v += __shfl_xor(v, 8);
    return v;
}

// ---------- MFMA dual-relation GEMM + fused el/er ----------
template<int H>
__global__ __launch_bounds__(256) void k_gemm_mfma(
        const ushort_t* __restrict__ Ab, const ushort_t* __restrict__ Wt,
        const float* __restrict__ al0, const float* __restrict__ ar0,
        const float* __restrict__ al1, const float* __restrict__ ar1,
        ushort_t* __restrict__ featb0, ushort_t* __restrict__ featb1,
        float* __restrict__ el0, float* __restrict__ er0,
        float* __restrict__ el1, float* __restrict__ er1){
    int t = threadIdx.x;
    int w = t >> 6, l = t & 63;
    int c = l & 15, kgrp = l >> 4;
    const bf16x8* AbV = (const bf16x8*)Ab;
    const bf16x8* WtV = (const bf16x8*)Wt;
    long arow = (long)blockIdx.x*64 + w*16 + c;
    bf16x8 zero8 = {0,0,0,0,0,0,0,0};
    bf16x8 af[4];
    bool rok = arow < NN;
    #pragma unroll
    for (int ks = 0; ks < 4; ks++)
        af[ks] = rok ? AbV[arow*16 + ks*4 + kgrp] : zero8;
    f32x4 acc[16];
    #pragma unroll
    for (int f = 0; f < 16; f++) acc[f] = (f32x4){0.f,0.f,0.f,0.f};
    #pragma unroll
    for (int f = 0; f < 16; f++){
        #pragma unroll
        for (int ks = 0; ks < 4; ks++){
            acc[f] = __builtin_amdgcn_mfma_f32_16x16x32_bf16(
                         af[ks], WtV[(f*4 + ks)*64 + l], acc[f], 0, 0, 0);
        }
    }
    float alv0[8], arv0[8], alv1[8], arv1[8];
    #pragma unroll
    for (int f = 0; f < 8; f++){
        alv0[f] = al0[f*16 + c]; arv0[f] = ar0[f*16 + c];
        alv1[f] = al1[f*16 + c]; arv1[f] = ar1[f*16 + c];
    }
    #pragma unroll
    for (int reg = 0; reg < 4; reg++){
        long orow = (long)blockIdx.x*64 + w*16 + kgrp*4 + reg;
        bool ok = orow < NN;
        if (ok){
            uint4 p0, p1;
            p0.x = cvtpk(acc[0][reg],  acc[1][reg]);
            p0.y = cvtpk(acc[2][reg],  acc[3][reg]);
            p0.z = cvtpk(acc[4][reg],  acc[5][reg]);
            p0.w = cvtpk(acc[6][reg],  acc[7][reg]);
            p1.x = cvtpk(acc[8][reg],  acc[9][reg]);
            p1.y = cvtpk(acc[10][reg], acc[11][reg]);
            p1.z = cvtpk(acc[12][reg], acc[13][reg]);
            p1.w = cvtpk(acc[14][reg], acc[15][reg]);
            *(uint4*)&featb0[orow*FD + c*8] = p0;
            *(uint4*)&featb1[orow*FD + c*8] = p1;
        }
        if (H == 2){
            float pl00=0, pr00=0, pl01=0, pr01=0;
            float pl10=0, pr10=0, pl11=0, pr11=0;
            #pragma unroll
            for (int f = 0; f < 4; f++){
                pl00 = fmaf(acc[f][reg],    alv0[f],   pl00);
                pr00 = fmaf(acc[f][reg],    arv0[f],   pr00);
                pl01 = fmaf(acc[4+f][reg],  alv0[4+f], pl01);
                pr01 = fmaf(acc[4+f][reg],  arv0[4+f], pr01);
                pl10 = fmaf(acc[8+f][reg],  alv1[f],   pl10);
                pr10 = fmaf(acc[8+f][reg],  arv1[f],   pr10);
                pl11 = fmaf(acc[12+f][reg], alv1[4+f], pl11);
                pr11 = fmaf(acc[12+f][reg], arv1[4+f], pr11);
            }
            pl00 = red16(pl00); pr00 = red16(pr00);
            pl01 = red16(pl01); pr01 = red16(pr01);
            pl10 = red16(pl10); pr10 = red16(pr10);
            pl11 = red16(pl11); pr11 = red16(pr11);
            if (c == 0 && ok){
                el0[orow*2] = pl00; el0[orow*2+1] = pl01;
                er0[orow*2] = pr00; er0[orow*2+1] = pr01;
                el1[orow*2] = pl10; el1[orow*2+1] = pl11;
                er1[orow*2] = pr10; er1[orow*2+1] = pr11;
            }
        } else {
            float pl0=0, pr0=0, pl1=0, pr1=0;
            #pragma unroll
            for (int f = 0; f < 8; f++){
                pl0 = fmaf(acc[f][reg],   alv0[f], pl0);
                pr0 = fmaf(acc[f][reg],   arv0[f], pr0);
                pl1 = fmaf(acc[8+f][reg], alv1[f], pl1);
                pr1 = fmaf(acc[8+f][reg], arv1[f], pr1);
            }
            pl0 = red16(pl0); pr0 = red16(pr0);
            pl1 = red16(pl1); pr1 = red16(pr1);
            if (c == 0 && ok){
                el0[orow] = pl0; er0[orow] = pr0;
                el1[orow] = pl1; er1[orow] = pr1;
            }
        }
    }
}

// ---------- fused aggregation: one wave per node, BOTH relation walks interleaved ----
template<int H>
__global__ __launch_bounds__(256) void k_agg2(
                       const int* __restrict__ rowptr,   // 2*NN+1, rel1 at +NN
                       const int* __restrict__ colsrc,   // 2*NE unified
                       const float* __restrict__ el0, const float* __restrict__ er0,
                       const float* __restrict__ el1, const float* __restrict__ er1,
                       const ushort_t* __restrict__ featb0, const ushort_t* __restrict__ featb1,
                       const float* __restrict__ bias0, const float* __restrict__ bias1,
                       ushort_t* __restrict__ outb, float* __restrict__ outf){
    int node = (blockIdx.x * blockDim.x + threadIdx.x) >> 6;
    int lane = threadIdx.x & 63;
    if (node >= NN) return;
    int sub = lane & 15, g = lane >> 4;
    int base0 = rowptr[node],        end0 = rowptr[node+1];
    int base1 = rowptr[NN + node],   end1 = rowptr[NN + node + 1];
    bool has0 = end0 > base0, has1 = end1 > base1;
    float er00 = er0[node*H];
    float er01 = (H == 2) ? er0[node*H + 1] : 0.f;
    float er10 = er1[node*H];
    float er11 = (H == 2) ? er1[node*H + 1] : 0.f;
    float acc0[8] = {0.f,0.f,0.f,0.f,0.f,0.f,0.f,0.f};
    float acc1[8] = {0.f,0.f,0.f,0.f,0.f,0.f,0.f,0.f};
    float s00=0.f, s01=0.f, s10=0.f, s11=0.f;
    while (base0 < end0 || base1 < end1){
        int nrem0 = end0 - base0, nrem1 = end1 - base1;
        bool act0 = lane < nrem0, act1 = lane < nrem1;
        int sv0 = act0 ? colsrc[base0 + lane] : 0;
        int sv1 = act1 ? colsrc[base1 + lane] : 0;
        float a00=0.f, a01=0.f, a10=0.f, a11=0.f;
        if (act0){
            if (H == 2){
                float2 e2 = *(const float2*)&el0[sv0*2];
                float e0 = e2.x + er00, e1 = e2.y + er01;
                e0 = (e0 > 0.f) ? e0 : 0.2f*e0;
                e1 = (e1 > 0.f) ? e1 : 0.2f*e1;
                a00 = __expf(e0); a01 = __expf(e1);
            } else {
                float e0 = el0[sv0] + er00;
                e0 = (e0 > 0.f) ? e0 : 0.2f*e0;
                a00 = __expf(e0);
            }
        }
        if (act1){
            if (H == 2){
                float2 e2 = *(const float2*)&el1[sv1*2];
                float e0 = e2.x + er10, e1 = e2.y + er11;
                e0 = (e0 > 0.f) ? e0 : 0.2f*e0;
                e1 = (e1 > 0.f) ? e1 : 0.2f*e1;
                a10 = __expf(e0); a11 = __expf(e1);
            } else {
                float e0 = el1[sv1] + er10;
                e0 = (e0 > 0.f) ? e0 : 0.2f*e0;
                a10 = __expf(e0);
            }
        }
        s00 += a00; s01 += a01; s10 += a10; s11 += a11;
        int nn0 = (nrem0 > 0) ? min(64, nrem0) : 0;
        int nn1 = (nrem1 > 0) ? min(64, nrem1) : 0;
        int nnm = (nn0 > nn1) ? nn0 : nn1;
        for (int j4 = 0; j4 < nnm; j4 += 4){
            int slot = j4 + g;
            int sj0 = __shfl(sv0, slot);
            int sj1 = __shfl(sv1, slot);
            float w00 = __shfl(a00, slot);
            float w01 = (H == 2) ? __shfl(a01, slot) : w00;
            float w10 = __shfl(a10, slot);
            float w11 = (H == 2) ? __shfl(a11, slot) : w10;
            uint4 p0 = *(const uint4*)&featb0[(unsigned)sj0*FD + sub*8];
            uint4 p1 = *(const uint4*)&featb1[(unsigned)sj1*FD + sub*8];
            acc0[0] = fmaf(w00, blo(p0.x), acc0[0]);
            acc0[1] = fmaf(w00, bhi(p0.x), acc0[1]);
            acc0[2] = fmaf(w00, blo(p0.y), acc0[2]);
            acc0[3] = fmaf(w00, bhi(p0.y), acc0[3]);
            acc0[4] = fmaf(w01, blo(p0.z), acc0[4]);
            acc0[5] = fmaf(w01, bhi(p0.z), acc0[5]);
            acc0[6] = fmaf(w01, blo(p0.w), acc0[6]);
            acc0[7] = fmaf(w01, bhi(p0.w), acc0[7]);
            acc1[0] = fmaf(w10, blo(p1.x), acc1[0]);
            acc1[1] = fmaf(w10, bhi(p1.x), acc1[1]);
            acc1[2] = fmaf(w10, blo(p1.y), acc1[2]);
            acc1[3] = fmaf(w10, bhi(p1.y), acc1[3]);
            acc1[4] = fmaf(w11, blo(p1.z), acc1[4]);
            acc1[5] = fmaf(w11, bhi(p1.z), acc1[5]);
            acc1[6] = fmaf(w11, blo(p1.w), acc1[6]);
            acc1[7] = fmaf(w11, bhi(p1.w), acc1[7]);
        }
        base0 += 64; base1 += 64;
    }
    #pragma unroll
    for (int off = 32; off > 0; off >>= 1){
        s00 += __shfl_xor(s00, off);
        s10 += __shfl_xor(s10, off);
        if (H == 2){ s01 += __shfl_xor(s01, off); s11 += __shfl_xor(s11, off); }
    }
    float i00 = has0 ? 1.f/s00 : 0.f;
    float i01 = (H == 2) ? (has0 ? 1.f/s01 : 0.f) : i00;
    float i10 = has1 ? 1.f/s10 : 0.f;
    float i11 = (H == 2) ? (has1 ? 1.f/s11 : 0.f) : i10;
    #pragma unroll
    for (int j = 0; j < 4; j++){
        acc0[j]   *= i00; acc0[j+4] *= i01;
        acc1[j]   *= i10; acc1[j+4] *= i11;
    }
    #pragma unroll
    for (int i = 0; i < 8; i++){
        acc0[i] += __shfl_xor(acc0[i], 16);
        acc0[i] += __shfl_xor(acc0[i], 32);
        acc1[i] += __shfl_xor(acc1[i], 16);
        acc1[i] += __shfl_xor(acc1[i], 32);
    }
    if (lane < 16){
        float v[8];
        #pragma unroll
        for (int j = 0; j < 8; j++)
            v[j] = 0.5f*(acc0[j] + acc1[j] + bias0[j*16 + sub] + bias1[j*16 + sub]);
        if (H == 2){
            #pragma unroll
            for (int j = 0; j < 8; j++) v[j] = fmaxf(v[j], 0.f);
            uint4 o;
            o.x = cvtpk(v[0], v[1]); o.y = cvtpk(v[2], v[3]);
            o.z = cvtpk(v[4], v[5]); o.w = cvtpk(v[6], v[7]);
            *(uint4*)&outb[(size_t)node*FD + sub*8] = o;
        } else {
            #pragma unroll
            for (int j = 0; j < 8; j++)
                outf[(size_t)node*FD + j*16 + sub] = v[j];
        }
    }
}

// ---------- launch ----------
extern "C" void kernel_launch(void* const* d_in, const int* in_sizes, int n_in,
                              void* d_out, int out_size, void* d_ws, size_t ws_size,
                              hipStream_t stream){
    const float* x   = (const float*)d_in[0];
    const float* W1  = (const float*)d_in[1];
    const float* al1 = (const float*)d_in[2];
    const float* ar1 = (const float*)d_in[3];
    const float* b1  = (const float*)d_in[4];
    const float* W2  = (const float*)d_in[5];
    const float* al2 = (const float*)d_in[6];
    const float* ar2 = (const float*)d_in[7];
    const float* b2  = (const float*)d_in[8];
    const int*   src = (const int*)d_in[9];
    const int*   dst = (const int*)d_in[10];
    float* out = (float*)d_out;

    size_t off = 0;
    auto carve = [&](size_t bytes) -> char* {
        char* p = (char*)d_ws + off;
        off += (bytes + 255) & ~(size_t)255;
        return p;
    };
    ushort_t* xb     = (ushort_t*)carve((size_t)NN * FD * 2);
    ushort_t* h1b    = (ushort_t*)carve((size_t)NN * FD * 2);
    ushort_t* featb0 = (ushort_t*)carve((size_t)NN * FD * 2);
    ushort_t* featb1 = (ushort_t*)carve((size_t)NN * FD * 2);
    ushort_t* Wt1    = (ushort_t*)carve(32768 * 2);
    ushort_t* Wt2    = (ushort_t*)carve(32768 * 2);
    float* el0      = (float*)carve((size_t)NN * 2 * 4);
    float* er0      = (float*)carve((size_t)NN * 2 * 4);
    float* el1      = (float*)carve((size_t)NN * 2 * 4);
    float* er1      = (float*)carve((size_t)NN * 2 * 4);
    int*   rowptrA  = (int*)  carve((size_t)(2*NN + 1) * 4);
    int*   colsrcA  = (int*)  carve((size_t)2*NE * 4);
    int*   counts   = (int*)  carve((size_t)2*NN * 4);
    int*   cursor   = (int*)  carve((size_t)2*NN * 4);
    int*   partials = (int*)  carve(1024);
    int*   bbase    = (int*)  carve((size_t)(NBK + 1) * 4);
    int*   bcur     = (int*)  carve((size_t)NBK * 4);
    if (off > ws_size) return;
    // ebuf (12.8 MB) aliases featb0+featb1 (51.2 MB): consumed before the GEMM fills them
    uint2* ebuf = (uint2*)featb0;

    const int EB2 = (2*NE + 255) / 256;                    // 6250
    const int NB2 = (2*NN + SCAN_TILE - 1) / SCAN_TILE;    // 196
    const int PB  = (2*NE + CHUNK - 1) / CHUNK;            // 196 partition blocks
    const int GB  = (NN + 63) / 64;                        // 1563
    const int WB  = NN / 4;                                // agg: 4 waves/block
    const int CB  = (NN * FD / 8 + 255) / 256;

    // prep: casts + W repack (independent of CSR)
    k_cast<<<CB, 256, 0, stream>>>(x, xb, NN * FD / 8);
    k_prepw<<<128, 256, 0, stream>>>(W1, Wt1, 0);
    k_prepw<<<128, 256, 0, stream>>>(W2, Wt2, 1);

    // CSR build: hist -> scan -> bucket partition -> per-bucket scatter
    hipMemsetAsync(counts, 0, (size_t)2*NN * 4, stream);
    k_hist2<<<EB2, 256, 0, stream>>>(dst, counts);
    k_scan_partial<<<NB2, 256, 0, stream>>>(counts, 2*NN, partials);
    k_scan_partials_excl<<<1, 256, 0, stream>>>(partials, NB2);
    k_scan_final<<<NB2, 256, 0, stream>>>(counts, 2*NN, 2*NE, partials, rowptrA);
    k_bcur<<<2, 256, 0, stream>>>(rowptrA, bbase, bcur);
    hipMemcpyAsync(cursor, rowptrA, (size_t)2*NN * 4, hipMemcpyDeviceToDevice, stream);
    k_part<<<PB, 256, 0, stream>>>(dst, src, bcur, ebuf);
    k_bscatter<<<NBK, 256, 0, stream>>>(ebuf, bbase, cursor, colsrcA);

    // layer 1: H=2 (both relations in one GEMM; agg writes bf16 relu(h1))
    k_gemm_mfma<2><<<GB, 256, 0, stream>>>(xb, Wt1, al1, ar1, al1 + FD, ar1 + FD,
                                           featb0, featb1, el0, er0, el1, er1);
    k_agg2<2><<<WB, 256, 0, stream>>>(rowptrA, colsrcA,
                                      el0, er0, el1, er1, featb0, featb1,
                                      b1, b1 + FD, h1b, nullptr);

    // layer 2: H=1 (W2 rows pre-permuted to absorb h1b's layout)
    k_gemm_mfma<1><<<GB, 256, 0, stream>>>(h1b, Wt2, al2, ar2, al2 + FD, ar2 + FD,
                                           featb0, featb1, el0, er0, el1, er1);
    k_agg2<1><<<WB, 256, 0, stream>>>(rowptrA, colsrcA,
                                      el0, er0, el1, er1, featb0, featb1,
                                      b2, b2 + FD, nullptr, out);
}

// Round 10
// 388.519 us; speedup vs baseline: 1.5279x; 1.0555x over previous
//
#include <hip/hip_runtime.h>
#include <hip/hip_bf16.h>
#include <math.h>

#define NN 100000     // nodes
#define NE 800000     // edges per relation
#define FD 128        // feature dim

#define BKW 512       // bucket width in (unified) dst-node space
#define NBK 391       // ceil(2*NN / BKW)
#define CHUNK 8192    // edges per partition block

typedef unsigned short ushort_t;
typedef __attribute__((ext_vector_type(8))) short bf16x8;
typedef __attribute__((ext_vector_type(4))) float f32x4;

// ---------- bf16 pack helpers ----------
__device__ inline unsigned f2bf(float f){              // software RNE (prep kernels)
    unsigned u = __float_as_uint(f);
    return (u + 0x7fffu + ((u >> 16) & 1u)) >> 16;
}
__device__ inline unsigned pk(float a, float b){
    return f2bf(a) | (f2bf(b) << 16);
}
__device__ inline unsigned cvtpk(float lo, float hi){  // HW packed cvt (1 inst)
    unsigned r;
    asm("v_cvt_pk_bf16_f32 %0, %1, %2" : "=v"(r) : "v"(lo), "v"(hi));
    return r;
}
__device__ inline float blo(unsigned p){ return __uint_as_float(p << 16); }
__device__ inline float bhi(unsigned p){ return __uint_as_float(p & 0xffff0000u); }
__device__ inline float2 up2(unsigned p){ float2 f; f.x = blo(p); f.y = bhi(p); return f; }
// packed dual-FMA: d.x += a.x*b.x; d.y += a.y*b.y  (one VALU inst)
__device__ inline void pkfma(float2& d, float2 a, float2 b){
    asm("v_pk_fma_f32 %0, %1, %2, %0" : "+v"(d) : "v"(a), "v"(b));
}

// ---------- CSR build: histogram over unified dst space ----------
__global__ void k_hist2(const int* __restrict__ dst, int* __restrict__ counts){
    int i = blockIdx.x * blockDim.x + threadIdx.x;
    if (i < 2*NE){
        int idx = dst[i] + ((i >= NE) ? NN : 0);
        atomicAdd(&counts[idx], 1);
    }
}

#define SCAN_TILE 1024
__global__ void k_scan_partial(const int* __restrict__ counts, int n, int* __restrict__ partials){
    __shared__ int sm[256];
    int base = blockIdx.x * SCAN_TILE;
    int t = threadIdx.x;
    int s = 0;
    #pragma unroll
    for (int j = 0; j < 4; j++){
        int idx = base + t*4 + j;
        if (idx < n) s += counts[idx];
    }
    sm[t] = s; __syncthreads();
    for (int off = 128; off > 0; off >>= 1){
        if (t < off) sm[t] += sm[t+off];
        __syncthreads();
    }
    if (t == 0) partials[blockIdx.x] = sm[0];
}

__global__ void k_scan_partials_excl(int* partials, int nb){
    __shared__ int sm[256];
    int t = threadIdx.x;
    int v = (t < nb) ? partials[t] : 0;
    sm[t] = v; __syncthreads();
    for (int off = 1; off < 256; off <<= 1){
        int add = (t >= off) ? sm[t-off] : 0;
        __syncthreads();
        sm[t] += add;
        __syncthreads();
    }
    if (t < nb) partials[t] = sm[t] - v;   // exclusive
}

__global__ void k_scan_final(const int* __restrict__ counts, int n, int tot,
                             const int* __restrict__ partials, int* __restrict__ rowptr){
    __shared__ int sm[256];
    int base = blockIdx.x * SCAN_TILE;
    int t = threadIdx.x;
    int v[4]; int s = 0;
    #pragma unroll
    for (int j = 0; j < 4; j++){
        int idx = base + t*4 + j;
        v[j] = (idx < n) ? counts[idx] : 0;
        s += v[j];
    }
    sm[t] = s; __syncthreads();
    for (int off = 1; off < 256; off <<= 1){
        int add = (t >= off) ? sm[t-off] : 0;
        __syncthreads();
        sm[t] += add;
        __syncthreads();
    }
    int excl = sm[t] - s + partials[blockIdx.x];
    #pragma unroll
    for (int j = 0; j < 4; j++){
        int idx = base + t*4 + j;
        if (idx < n) rowptr[idx] = excl;
        excl += v[j];
    }
    if (blockIdx.x == 0 && t == 0) rowptr[n] = tot;
}

// bucket bases/cursors from rowptr (buckets are contiguous node ranges)
__global__ void k_bcur(const int* __restrict__ rowptr, int* __restrict__ bbase,
                       int* __restrict__ bcur){
    int t = blockIdx.x * blockDim.x + threadIdx.x;
    if (t <= NBK){
        int node = t * BKW; if (node > 2*NN) node = 2*NN;
        int v = rowptr[node];
        bbase[t] = v;
        if (t < NBK) bcur[t] = v;
    }
}

// ---------- pass B: stable partition into NBK buckets, coalesced pair writes ----
__global__ __launch_bounds__(256) void k_part(const int* __restrict__ dst,
                                              const int* __restrict__ src,
                                              int* __restrict__ bcur,
                                              uint2* __restrict__ ebuf){
    __shared__ int lcount[NBK];
    __shared__ int lbase[NBK];
    int t = threadIdx.x;
    long base = (long)blockIdx.x * CHUNK;
    for (int j = t; j < NBK; j += 256) lcount[j] = 0;
    __syncthreads();
    #pragma unroll 4
    for (int k = 0; k < CHUNK/256; k++){
        long i = base + k*256 + t;
        if (i < 2*NE){
            int b = (dst[i] + ((i >= NE) ? NN : 0)) >> 9;
            atomicAdd(&lcount[b], 1);
        }
    }
    __syncthreads();
    for (int j = t; j < NBK; j += 256){
        int c = lcount[j];
        lbase[j] = c ? atomicAdd(&bcur[j], c) : 0;
    }
    __syncthreads();
    for (int j = t; j < NBK; j += 256) lcount[j] = 0;
    __syncthreads();
    #pragma unroll 4
    for (int k = 0; k < CHUNK/256; k++){
        long i = base + k*256 + t;
        if (i < 2*NE){
            int dstU = dst[i] + ((i >= NE) ? NN : 0);
            int b = dstU >> 9;
            int r = atomicAdd(&lcount[b], 1);
            ebuf[lbase[b] + r] = make_uint2((unsigned)src[i], (unsigned)dstU);
        }
    }
}

// ---------- pass C: per-bucket scatter; one block owns one colsrc window ----------
__global__ __launch_bounds__(256) void k_bscatter(const uint2* __restrict__ ebuf,
                                                  const int* __restrict__ bbase,
                                                  int* __restrict__ cursor,
                                                  int* __restrict__ colsrc){
    int b = blockIdx.x;
    int lo = bbase[b], hi = bbase[b+1];
    for (int i = lo + threadIdx.x; i < hi; i += 256){
        uint2 e = ebuf[i];
        int p = atomicAdd(&cursor[e.y], 1);
        colsrc[p] = (int)e.x;
    }
}

// ---------- prep: x -> bf16 ----------
__global__ void k_cast(const float* __restrict__ in, ushort_t* __restrict__ out, int n8){
    int i = blockIdx.x * blockDim.x + threadIdx.x;
    if (i < n8){
        float4 u = ((const float4*)in)[i*2];
        float4 v = ((const float4*)in)[i*2 + 1];
        uint4 o;
        o.x = pk(u.x, u.y); o.y = pk(u.z, u.w);
        o.z = pk(v.x, v.y); o.w = pk(v.z, v.w);
        ((uint4*)out)[i] = o;
    }
}

// ---------- prep: W (2 rel x 128x128 fp32) -> B-fragment-linear bf16 ----------
// perm=1 (layer 2): A rows come from h1b's interleaved-stored layout:
// linear A pos q holds logical col (((q&7)>>1) + 4*(q&1))*16 + (q>>3).
__global__ void k_prepw(const float* __restrict__ W, ushort_t* __restrict__ Wt, int perm){
    int idx = blockIdx.x * blockDim.x + threadIdx.x;   // 32768 total
    if (idx >= 32768) return;
    int j  = idx & 7;
    int l  = (idx >> 3) & 63;
    int ks = (idx >> 9) & 3;
    int f  = idx >> 11;
    int k  = ks*32 + (l >> 4)*8 + j;
    if (perm) k = (((k & 7) >> 1) + 4*(k & 1))*16 + (k >> 3);
    int col = (f & 7)*16 + (l & 15);
    int rel = f >> 3;
    Wt[idx] = (ushort_t)f2bf(W[rel*16384 + k*FD + col]);
}

// ---------- helpers ----------
__device__ inline float red16(float v){
    v += __shfl_xor(v, 1);
    v += __shfl_xor(v, 2);
    v += __shfl_xor(v, 4);
    v += __shfl_xor(v, 8);
    return v;
}

// ---------- MFMA dual-relation GEMM + fused el/er ----------
// featb stored head-interleaved: stored[c*8 + 2t]   = logical col  t   *16+c
//                                stored[c*8 + 2t+1] = logical col (t+4)*16+c
// -> each bf16 pair = (head0 elem, head1 elem) for the agg's packed FMA.
template<int H>
__global__ __launch_bounds__(256) void k_gemm_mfma(
        const ushort_t* __restrict__ Ab, const ushort_t* __restrict__ Wt,
        const float* __restrict__ al0, const float* __restrict__ ar0,
        const float* __restrict__ al1, const float* __restrict__ ar1,
        ushort_t* __restrict__ featb0, ushort_t* __restrict__ featb1,
        float* __restrict__ el0, float* __restrict__ er0,
        float* __restrict__ el1, float* __restrict__ er1){
    int t = threadIdx.x;
    int w = t >> 6, l = t & 63;
    int c = l & 15, kgrp = l >> 4;
    const bf16x8* AbV = (const bf16x8*)Ab;
    const bf16x8* WtV = (const bf16x8*)Wt;
    long arow = (long)blockIdx.x*64 + w*16 + c;
    bf16x8 zero8 = {0,0,0,0,0,0,0,0};
    bf16x8 af[4];
    bool rok = arow < NN;
    #pragma unroll
    for (int ks = 0; ks < 4; ks++)
        af[ks] = rok ? AbV[arow*16 + ks*4 + kgrp] : zero8;
    f32x4 acc[16];
    #pragma unroll
    for (int f = 0; f < 16; f++) acc[f] = (f32x4){0.f,0.f,0.f,0.f};
    #pragma unroll
    for (int f = 0; f < 16; f++){
        #pragma unroll
        for (int ks = 0; ks < 4; ks++){
            acc[f] = __builtin_amdgcn_mfma_f32_16x16x32_bf16(
                         af[ks], WtV[(f*4 + ks)*64 + l], acc[f], 0, 0, 0);
        }
    }
    float alv0[8], arv0[8], alv1[8], arv1[8];
    #pragma unroll
    for (int f = 0; f < 8; f++){
        alv0[f] = al0[f*16 + c]; arv0[f] = ar0[f*16 + c];
        alv1[f] = al1[f*16 + c]; arv1[f] = ar1[f*16 + c];
    }
    #pragma unroll
    for (int reg = 0; reg < 4; reg++){
        long orow = (long)blockIdx.x*64 + w*16 + kgrp*4 + reg;
        bool ok = orow < NN;
        if (ok){
            uint4 p0, p1;
            p0.x = cvtpk(acc[0][reg],  acc[4][reg]);
            p0.y = cvtpk(acc[1][reg],  acc[5][reg]);
            p0.z = cvtpk(acc[2][reg],  acc[6][reg]);
            p0.w = cvtpk(acc[3][reg],  acc[7][reg]);
            p1.x = cvtpk(acc[8][reg],  acc[12][reg]);
            p1.y = cvtpk(acc[9][reg],  acc[13][reg]);
            p1.z = cvtpk(acc[10][reg], acc[14][reg]);
            p1.w = cvtpk(acc[11][reg], acc[15][reg]);
            *(uint4*)&featb0[orow*FD + c*8] = p0;
            *(uint4*)&featb1[orow*FD + c*8] = p1;
        }
        if (H == 2){
            float pl00=0, pr00=0, pl01=0, pr01=0;
            float pl10=0, pr10=0, pl11=0, pr11=0;
            #pragma unroll
            for (int f = 0; f < 4; f++){
                pl00 = fmaf(acc[f][reg],    alv0[f],   pl00);
                pr00 = fmaf(acc[f][reg],    arv0[f],   pr00);
                pl01 = fmaf(acc[4+f][reg],  alv0[4+f], pl01);
                pr01 = fmaf(acc[4+f][reg],  arv0[4+f], pr01);
                pl10 = fmaf(acc[8+f][reg],  alv1[f],   pl10);
                pr10 = fmaf(acc[8+f][reg],  arv1[f],   pr10);
                pl11 = fmaf(acc[12+f][reg], alv1[4+f], pl11);
                pr11 = fmaf(acc[12+f][reg], arv1[4+f], pr11);
            }
            pl00 = red16(pl00); pr00 = red16(pr00);
            pl01 = red16(pl01); pr01 = red16(pr01);
            pl10 = red16(pl10); pr10 = red16(pr10);
            pl11 = red16(pl11); pr11 = red16(pr11);
            if (c == 0 && ok){
                el0[orow*2] = pl00; el0[orow*2+1] = pl01;
                er0[orow*2] = pr00; er0[orow*2+1] = pr01;
                el1[orow*2] = pl10; el1[orow*2+1] = pl11;
                er1[orow*2] = pr10; er1[orow*2+1] = pr11;
            }
        } else {
            float pl0=0, pr0=0, pl1=0, pr1=0;
            #pragma unroll
            for (int f = 0; f < 8; f++){
                pl0 = fmaf(acc[f][reg],   alv0[f], pl0);
                pr0 = fmaf(acc[f][reg],   arv0[f], pr0);
                pl1 = fmaf(acc[8+f][reg], alv1[f], pl1);
                pr1 = fmaf(acc[8+f][reg], arv1[f], pr1);
            }
            pl0 = red16(pl0); pr0 = red16(pr0);
            pl1 = red16(pl1); pr1 = red16(pr1);
            if (c == 0 && ok){
                el0[orow] = pl0; er0[orow] = pr0;
                el1[orow] = pl1; er1[orow] = pr1;
            }
        }
    }
}

// ---------- fused aggregation: 2 nodes per wave (32 lanes each), packed FMA ----------
// Half = 32 lanes = one node; 2 groups of 16 per half gather rows (slot = j2+g).
// acc pairs: ap[t] = {col t*16+sub, col (t+4)*16+sub} -> pk_fma with w2={w_h0,w_h1}.
template<int H>
__global__ __launch_bounds__(256) void k_agg2(
                       const int* __restrict__ rowptr,   // 2*NN+1, rel1 at +NN
                       const int* __restrict__ colsrc,   // 2*NE unified
                       const float* __restrict__ el0, const float* __restrict__ er0,
                       const float* __restrict__ el1, const float* __restrict__ er1,
                       const ushort_t* __restrict__ featb0, const ushort_t* __restrict__ featb1,
                       const float* __restrict__ bias0, const float* __restrict__ bias1,
                       ushort_t* __restrict__ outb, float* __restrict__ outf){
    int lane = threadIdx.x & 63;
    int half = lane >> 5;
    int hl   = lane & 31;
    int sub  = lane & 15;
    int g    = (lane >> 4) & 1;
    int node = ((blockIdx.x * blockDim.x + threadIdx.x) >> 6) * 2 + half;
    if (node >= NN) return;
    int base0 = rowptr[node],       end0 = rowptr[node+1];
    int base1 = rowptr[NN + node],  end1 = rowptr[NN + node + 1];
    bool has0 = end0 > base0, has1 = end1 > base1;
    float er00 = er0[node*H];
    float er01 = (H == 2) ? er0[node*H + 1] : 0.f;
    float er10 = er1[node*H];
    float er11 = (H == 2) ? er1[node*H + 1] : 0.f;
    float2 ap0[4], ap1[4];
    #pragma unroll
    for (int i = 0; i < 4; i++){ ap0[i] = make_float2(0.f,0.f); ap1[i] = make_float2(0.f,0.f); }
    float s00=0.f, s01=0.f, s10=0.f, s11=0.f;
    while (base0 < end0 || base1 < end1){
        int nrem0 = end0 - base0, nrem1 = end1 - base1;
        bool act0 = hl < nrem0, act1 = hl < nrem1;
        int sv0 = act0 ? colsrc[base0 + hl] : 0;
        int sv1 = act1 ? colsrc[base1 + hl] : 0;
        float a00=0.f, a01=0.f, a10=0.f, a11=0.f;
        if (act0){
            if (H == 2){
                float2 e2 = *(const float2*)&el0[sv0*2];
                float e0 = e2.x + er00, e1 = e2.y + er01;
                e0 = (e0 > 0.f) ? e0 : 0.2f*e0;
                e1 = (e1 > 0.f) ? e1 : 0.2f*e1;
                a00 = __expf(e0); a01 = __expf(e1);
            } else {
                float e0 = el0[sv0] + er00;
                e0 = (e0 > 0.f) ? e0 : 0.2f*e0;
                a00 = __expf(e0);
            }
        }
        if (act1){
            if (H == 2){
                float2 e2 = *(const float2*)&el1[sv1*2];
                float e0 = e2.x + er10, e1 = e2.y + er11;
                e0 = (e0 > 0.f) ? e0 : 0.2f*e0;
                e1 = (e1 > 0.f) ? e1 : 0.2f*e1;
                a10 = __expf(e0); a11 = __expf(e1);
            } else {
                float e0 = el1[sv1] + er10;
                e0 = (e0 > 0.f) ? e0 : 0.2f*e0;
                a10 = __expf(e0);
            }
        }
        s00 += a00; s01 += a01; s10 += a10; s11 += a11;
        int nn0 = (nrem0 > 0) ? min(32, nrem0) : 0;
        int nn1 = (nrem1 > 0) ? min(32, nrem1) : 0;
        int nnm = (nn0 > nn1) ? nn0 : nn1;
        for (int j2 = 0; j2 < nnm; j2 += 2){
            int sl = (half << 5) + j2 + g;    // source lane within own half
            int sj0 = __shfl(sv0, sl);
            int sj1 = __shfl(sv1, sl);
            float2 w0p, w1p;
            w0p.x = __shfl(a00, sl);
            w0p.y = (H == 2) ? __shfl(a01, sl) : w0p.x;
            w1p.x = __shfl(a10, sl);
            w1p.y = (H == 2) ? __shfl(a11, sl) : w1p.x;
            uint4 p0 = *(const uint4*)&featb0[(unsigned)sj0*FD + sub*8];
            uint4 p1 = *(const uint4*)&featb1[(unsigned)sj1*FD + sub*8];
            pkfma(ap0[0], w0p, up2(p0.x));
            pkfma(ap0[1], w0p, up2(p0.y));
            pkfma(ap0[2], w0p, up2(p0.z));
            pkfma(ap0[3], w0p, up2(p0.w));
            pkfma(ap1[0], w1p, up2(p1.x));
            pkfma(ap1[1], w1p, up2(p1.y));
            pkfma(ap1[2], w1p, up2(p1.z));
            pkfma(ap1[3], w1p, up2(p1.w));
        }
        base0 += 32; base1 += 32;
    }
    // s-reduce within the 32-lane half (5 levels)
    #pragma unroll
    for (int off = 16; off > 0; off >>= 1){
        s00 += __shfl_xor(s00, off);
        s10 += __shfl_xor(s10, off);
        if (H == 2){ s01 += __shfl_xor(s01, off); s11 += __shfl_xor(s11, off); }
    }
    // group-reduce across the 2 groups of this half (1 level)
    #pragma unroll
    for (int i = 0; i < 4; i++){
        float2 t0, t1;
        t0.x = __shfl_xor(ap0[i].x, 16); t0.y = __shfl_xor(ap0[i].y, 16);
        t1.x = __shfl_xor(ap1[i].x, 16); t1.y = __shfl_xor(ap1[i].y, 16);
        ap0[i].x += t0.x; ap0[i].y += t0.y;
        ap1[i].x += t1.x; ap1[i].y += t1.y;
    }
    if (hl < 16){
        float i00 = has0 ? 1.f/s00 : 0.f;
        float i01 = (H == 2) ? (has0 ? 1.f/s01 : 0.f) : i00;
        float i10 = has1 ? 1.f/s10 : 0.f;
        float i11 = (H == 2) ? (has1 ? 1.f/s11 : 0.f) : i10;
        float2 vp[4];
        #pragma unroll
        for (int t = 0; t < 4; t++){
            float bx = bias0[t*16 + sub]       + bias1[t*16 + sub];
            float by = bias0[(t+4)*16 + sub]   + bias1[(t+4)*16 + sub];
            vp[t].x = 0.5f*(ap0[t].x*i00 + ap1[t].x*i10 + bx);
            vp[t].y = 0.5f*(ap0[t].y*i01 + ap1[t].y*i11 + by);
        }
        if (H == 2){
            #pragma unroll
            for (int t = 0; t < 4; t++){
                vp[t].x = fmaxf(vp[t].x, 0.f);
                vp[t].y = fmaxf(vp[t].y, 0.f);
            }
            uint4 o;
            o.x = cvtpk(vp[0].x, vp[0].y); o.y = cvtpk(vp[1].x, vp[1].y);
            o.z = cvtpk(vp[2].x, vp[2].y); o.w = cvtpk(vp[3].x, vp[3].y);
            *(uint4*)&outb[(size_t)node*FD + sub*8] = o;
        } else {
            #pragma unroll
            for (int t = 0; t < 4; t++){
                outf[(size_t)node*FD + t*16 + sub]     = vp[t].x;
                outf[(size_t)node*FD + (t+4)*16 + sub] = vp[t].y;
            }
        }
    }
}

// ---------- launch ----------
extern "C" void kernel_launch(void* const* d_in, const int* in_sizes, int n_in,
                              void* d_out, int out_size, void* d_ws, size_t ws_size,
                              hipStream_t stream){
    const float* x   = (const float*)d_in[0];
    const float* W1  = (const float*)d_in[1];
    const float* al1 = (const float*)d_in[2];
    const float* ar1 = (const float*)d_in[3];
    const float* b1  = (const float*)d_in[4];
    const float* W2  = (const float*)d_in[5];
    const float* al2 = (const float*)d_in[6];
    const float* ar2 = (const float*)d_in[7];
    const float* b2  = (const float*)d_in[8];
    const int*   src = (const int*)d_in[9];
    const int*   dst = (const int*)d_in[10];
    float* out = (float*)d_out;

    size_t off = 0;
    auto carve = [&](size_t bytes) -> char* {
        char* p = (char*)d_ws + off;
        off += (bytes + 255) & ~(size_t)255;
        return p;
    };
    ushort_t* xb     = (ushort_t*)carve((size_t)NN * FD * 2);
    ushort_t* h1b    = (ushort_t*)carve((size_t)NN * FD * 2);
    ushort_t* featb0 = (ushort_t*)carve((size_t)NN * FD * 2);
    ushort_t* featb1 = (ushort_t*)carve((size_t)NN * FD * 2);
    ushort_t* Wt1    = (ushort_t*)carve(32768 * 2);
    ushort_t* Wt2    = (ushort_t*)carve(32768 * 2);
    float* el0      = (float*)carve((size_t)NN * 2 * 4);
    float* er0      = (float*)carve((size_t)NN * 2 * 4);
    float* el1      = (float*)carve((size_t)NN * 2 * 4);
    float* er1      = (float*)carve((size_t)NN * 2 * 4);
    int*   rowptrA  = (int*)  carve((size_t)(2*NN + 1) * 4);
    int*   colsrcA  = (int*)  carve((size_t)2*NE * 4);
    int*   counts   = (int*)  carve((size_t)2*NN * 4);
    int*   cursor   = (int*)  carve((size_t)2*NN * 4);
    int*   partials = (int*)  carve(1024);
    int*   bbase    = (int*)  carve((size_t)(NBK + 1) * 4);
    int*   bcur     = (int*)  carve((size_t)NBK * 4);
    if (off > ws_size) return;
    // ebuf (12.8 MB) aliases featb0+featb1 (51.2 MB): consumed before the GEMM fills them
    uint2* ebuf = (uint2*)featb0;

    const int EB2 = (2*NE + 255) / 256;                    // 6250
    const int NB2 = (2*NN + SCAN_TILE - 1) / SCAN_TILE;    // 196
    const int PB  = (2*NE + CHUNK - 1) / CHUNK;            // 196 partition blocks
    const int GB  = (NN + 63) / 64;                        // 1563
    const int WB  = (NN + 7) / 8;                          // agg: 8 nodes/block
    const int CB  = (NN * FD / 8 + 255) / 256;

    // prep: casts + W repack (independent of CSR)
    k_cast<<<CB, 256, 0, stream>>>(x, xb, NN * FD / 8);
    k_prepw<<<128, 256, 0, stream>>>(W1, Wt1, 0);
    k_prepw<<<128, 256, 0, stream>>>(W2, Wt2, 1);

    // CSR build: hist -> scan -> bucket partition -> per-bucket scatter
    hipMemsetAsync(counts, 0, (size_t)2*NN * 4, stream);
    k_hist2<<<EB2, 256, 0, stream>>>(dst, counts);
    k_scan_partial<<<NB2, 256, 0, stream>>>(counts, 2*NN, partials);
    k_scan_partials_excl<<<1, 256, 0, stream>>>(partials, NB2);
    k_scan_final<<<NB2, 256, 0, stream>>>(counts, 2*NN, 2*NE, partials, rowptrA);
    k_bcur<<<2, 256, 0, stream>>>(rowptrA, bbase, bcur);
    hipMemcpyAsync(cursor, rowptrA, (size_t)2*NN * 4, hipMemcpyDeviceToDevice, stream);
    k_part<<<PB, 256, 0, stream>>>(dst, src, bcur, ebuf);
    k_bscatter<<<NBK, 256, 0, stream>>>(ebuf, bbase, cursor, colsrcA);

    // layer 1: H=2 (both relations in one GEMM; agg writes bf16 relu(h1))
    k_gemm_mfma<2><<<GB, 256, 0, stream>>>(xb, Wt1, al1, ar1, al1 + FD, ar1 + FD,
                                           featb0, featb1, el0, er0, el1, er1);
    k_agg2<2><<<WB, 256, 0, stream>>>(rowptrA, colsrcA,
                                      el0, er0, el1, er1, featb0, featb1,
                                      b1, b1 + FD, h1b, nullptr);

    // layer 2: H=1 (W2 rows pre-permuted to absorb h1b's layout)
    k_gemm_mfma<1><<<GB, 256, 0, stream>>>(h1b, Wt2, al2, ar2, al2 + FD, ar2 + FD,
                                           featb0, featb1, el0, er0, el1, er1);
    k_agg2<1><<<WB, 256, 0, stream>>>(rowptrA, colsrcA,
                                      el0, er0, el1, er1, featb0, featb1,
                                      b2, b2 + FD, nullptr, out);
}

// Round 12
// 356.333 us; speedup vs baseline: 1.6659x; 1.0903x over previous
//
#include <hip/hip_runtime.h>
#include <hip/hip_bf16.h>
#include <math.h>

#define NN 100000     // nodes
#define NE 800000     // edges per relation
#define FD 128        // feature dim

#define BKW 512       // bucket width in (unified) dst-node space
#define NBK 391       // ceil(2*NN / BKW)
#define CHUNK 8192    // edges per partition block

typedef unsigned short ushort_t;
typedef __attribute__((ext_vector_type(8))) short bf16x8;
typedef __attribute__((ext_vector_type(4))) float f32x4;

union U8 { uint4 u; bf16x8 b; };

// ---------- bf16 pack helpers ----------
__device__ inline unsigned f2bf(float f){              // software RNE (prep kernels)
    unsigned u = __float_as_uint(f);
    return (u + 0x7fffu + ((u >> 16) & 1u)) >> 16;
}
__device__ inline unsigned cvtpk(float lo, float hi){  // HW packed cvt (1 inst, RNE)
    unsigned r;
    asm("v_cvt_pk_bf16_f32 %0, %1, %2" : "=v"(r) : "v"(lo), "v"(hi));
    return r;
}
__device__ inline float blo(unsigned p){ return __uint_as_float(p << 16); }
__device__ inline float bhi(unsigned p){ return __uint_as_float(p & 0xffff0000u); }
__device__ inline float2 up2(unsigned p){ float2 f; f.x = blo(p); f.y = bhi(p); return f; }
// packed dual-FMA: d.x += a.x*b.x; d.y += a.y*b.y  (one VALU inst)
__device__ inline void pkfma(float2& d, float2 a, float2 b){
    asm("v_pk_fma_f32 %0, %1, %2, %0" : "+v"(d) : "v"(a), "v"(b));
}

// ---------- CSR build: histogram over unified dst space ----------
__global__ void k_hist2(const int* __restrict__ dst, int* __restrict__ counts){
    int i = blockIdx.x * blockDim.x + threadIdx.x;
    if (i < 2*NE){
        int idx = dst[i] + ((i >= NE) ? NN : 0);
        atomicAdd(&counts[idx], 1);
    }
}

#define SCAN_TILE 1024
__global__ void k_scan_partial(const int* __restrict__ counts, int n, int* __restrict__ partials){
    __shared__ int sm[256];
    int base = blockIdx.x * SCAN_TILE;
    int t = threadIdx.x;
    int s = 0;
    #pragma unroll
    for (int j = 0; j < 4; j++){
        int idx = base + t*4 + j;
        if (idx < n) s += counts[idx];
    }
    sm[t] = s; __syncthreads();
    for (int off = 128; off > 0; off >>= 1){
        if (t < off) sm[t] += sm[t+off];
        __syncthreads();
    }
    if (t == 0) partials[blockIdx.x] = sm[0];
}

__global__ void k_scan_partials_excl(int* partials, int nb){
    __shared__ int sm[256];
    int t = threadIdx.x;
    int v = (t < nb) ? partials[t] : 0;
    sm[t] = v; __syncthreads();
    for (int off = 1; off < 256; off <<= 1){
        int add = (t >= off) ? sm[t-off] : 0;
        __syncthreads();
        sm[t] += add;
        __syncthreads();
    }
    if (t < nb) partials[t] = sm[t] - v;   // exclusive
}

__global__ void k_scan_final(const int* __restrict__ counts, int n, int tot,
                             const int* __restrict__ partials, int* __restrict__ rowptr){
    __shared__ int sm[256];
    int base = blockIdx.x * SCAN_TILE;
    int t = threadIdx.x;
    int v[4]; int s = 0;
    #pragma unroll
    for (int j = 0; j < 4; j++){
        int idx = base + t*4 + j;
        v[j] = (idx < n) ? counts[idx] : 0;
        s += v[j];
    }
    sm[t] = s; __syncthreads();
    for (int off = 1; off < 256; off <<= 1){
        int add = (t >= off) ? sm[t-off] : 0;
        __syncthreads();
        sm[t] += add;
        __syncthreads();
    }
    int excl = sm[t] - s + partials[blockIdx.x];
    #pragma unroll
    for (int j = 0; j < 4; j++){
        int idx = base + t*4 + j;
        if (idx < n) rowptr[idx] = excl;
        excl += v[j];
    }
    if (blockIdx.x == 0 && t == 0) rowptr[n] = tot;
}

// ebuf allocation cursors (one per bucket) from rowptr
__global__ void k_bcur(const int* __restrict__ rowptr, int* __restrict__ bcur){
    int t = blockIdx.x * blockDim.x + threadIdx.x;
    if (t < NBK) bcur[t] = rowptr[t * BKW];
}

// ---------- pass B: stable partition into NBK buckets, coalesced pair writes ----
__global__ __launch_bounds__(256) void k_part(const int* __restrict__ dst,
                                              const int* __restrict__ src,
                                              int* __restrict__ bcur,
                                              uint2* __restrict__ ebuf){
    __shared__ int lcount[NBK];
    __shared__ int lbase[NBK];
    int t = threadIdx.x;
    long base = (long)blockIdx.x * CHUNK;
    for (int j = t; j < NBK; j += 256) lcount[j] = 0;
    __syncthreads();
    #pragma unroll 4
    for (int k = 0; k < CHUNK/256; k++){
        long i = base + k*256 + t;
        if (i < 2*NE){
            int b = (dst[i] + ((i >= NE) ? NN : 0)) >> 9;
            atomicAdd(&lcount[b], 1);
        }
    }
    __syncthreads();
    for (int j = t; j < NBK; j += 256){
        int c = lcount[j];
        lbase[j] = c ? atomicAdd(&bcur[j], c) : 0;
    }
    __syncthreads();
    for (int j = t; j < NBK; j += 256) lcount[j] = 0;
    __syncthreads();
    #pragma unroll 4
    for (int k = 0; k < CHUNK/256; k++){
        long i = base + k*256 + t;
        if (i < 2*NE){
            int dstU = dst[i] + ((i >= NE) ? NN : 0);
            int b = dstU >> 9;
            int r = atomicAdd(&lcount[b], 1);
            ebuf[lbase[b] + r] = make_uint2((unsigned)src[i], (unsigned)dstU);
        }
    }
}

// ---------- pass C: per-bucket scatter with LDS cursors ----------
// One block owns bucket b = nodes [b*BKW, b*BKW+BKW): cursors live in LDS,
// colsrc writes land in the bucket's private window (single-XCD L2 locality).
__global__ __launch_bounds__(256) void k_bscatter(const uint2* __restrict__ ebuf,
                                                  const int* __restrict__ rowptr,
                                                  int* __restrict__ colsrc){
    __shared__ int lcur[BKW];
    int b = blockIdx.x;
    int n0 = b * BKW;
    int nend = min(2*NN, n0 + BKW);
    for (int j = threadIdx.x; j < nend - n0; j += 256)
        lcur[j] = rowptr[n0 + j];
    __syncthreads();
    int lo = rowptr[n0], hi = rowptr[nend];
    for (int i = lo + threadIdx.x; i < hi; i += 256){
        uint2 e = ebuf[i];
        int p = atomicAdd(&lcur[e.y - n0], 1);
        colsrc[p] = (int)e.x;
    }
}

// ---------- prep: both W matrices -> B-fragment-linear bf16 (one launch) ----------
// m=1 (layer 2): A rows come from h1b's interleaved-stored layout:
// linear A pos q holds logical col (((q&7)>>1) + 4*(q&1))*16 + (q>>3).
__global__ void k_prepw2(const float* __restrict__ W1, const float* __restrict__ W2,
                         ushort_t* __restrict__ Wt1, ushort_t* __restrict__ Wt2){
    int idx = blockIdx.x * blockDim.x + threadIdx.x;   // 65536 total
    if (idx >= 65536) return;
    int m = idx >> 15;
    int i = idx & 32767;
    const float* W = m ? W2 : W1;
    ushort_t* Wt   = m ? Wt2 : Wt1;
    int j  = i & 7;
    int l  = (i >> 3) & 63;
    int ks = (i >> 9) & 3;
    int f  = i >> 11;
    int k  = ks*32 + (l >> 4)*8 + j;
    if (m) k = (((k & 7) >> 1) + 4*(k & 1))*16 + (k >> 3);
    int col = (f & 7)*16 + (l & 15);
    int rel = f >> 3;
    Wt[i] = (ushort_t)f2bf(W[rel*16384 + k*FD + col]);   // FIX: index is i, not i+m*32768
}

// ---------- helpers ----------
__device__ inline float red16(float v){
    v += __shfl_xor(v, 1);
    v += __shfl_xor(v, 2);
    v += __shfl_xor(v, 4);
    v += __shfl_xor(v, 8);
    return v;
}

// ---------- MFMA dual-relation GEMM + fused el/er ----------
// AF32: read fp32 A directly, convert fragments in-register (kills k_cast).
// featb stored head-interleaved: stored[c*8 + 2t]   = logical col  t   *16+c
//                                stored[c*8 + 2t+1] = logical col (t+4)*16+c
template<int H, bool AF32>
__global__ __launch_bounds__(256) void k_gemm_mfma(
        const ushort_t* __restrict__ Ab, const float* __restrict__ Af,
        const ushort_t* __restrict__ Wt,
        const float* __restrict__ al0, const float* __restrict__ ar0,
        const float* __restrict__ al1, const float* __restrict__ ar1,
        ushort_t* __restrict__ featb0, ushort_t* __restrict__ featb1,
        float* __restrict__ el0, float* __restrict__ er0,
        float* __restrict__ el1, float* __restrict__ er1){
    int t = threadIdx.x;
    int w = t >> 6, l = t & 63;
    int c = l & 15, kgrp = l >> 4;
    const bf16x8* WtV = (const bf16x8*)Wt;
    long arow = (long)blockIdx.x*64 + w*16 + c;
    bf16x8 zero8 = {0,0,0,0,0,0,0,0};
    bf16x8 af[4];
    bool rok = arow < NN;
    if (AF32){
        const float4* xv = (const float4*)Af;
        #pragma unroll
        for (int ks = 0; ks < 4; ks++){
            if (rok){
                float4 u = xv[arow*32 + (ks*4 + kgrp)*2];
                float4 v = xv[arow*32 + (ks*4 + kgrp)*2 + 1];
                U8 q;
                q.u = make_uint4(cvtpk(u.x,u.y), cvtpk(u.z,u.w),
                                 cvtpk(v.x,v.y), cvtpk(v.z,v.w));
                af[ks] = q.b;
            } else af[ks] = zero8;
        }
    } else {
        const bf16x8* AbV = (const bf16x8*)Ab;
        #pragma unroll
        for (int ks = 0; ks < 4; ks++)
            af[ks] = rok ? AbV[arow*16 + ks*4 + kgrp] : zero8;
    }
    f32x4 acc[16];
    #pragma unroll
    for (int f = 0; f < 16; f++) acc[f] = (f32x4){0.f,0.f,0.f,0.f};
    #pragma unroll
    for (int f = 0; f < 16; f++){
        #pragma unroll
        for (int ks = 0; ks < 4; ks++){
            acc[f] = __builtin_amdgcn_mfma_f32_16x16x32_bf16(
                         af[ks], WtV[(f*4 + ks)*64 + l], acc[f], 0, 0, 0);
        }
    }
    float alv0[8], arv0[8], alv1[8], arv1[8];
    #pragma unroll
    for (int f = 0; f < 8; f++){
        alv0[f] = al0[f*16 + c]; arv0[f] = ar0[f*16 + c];
        alv1[f] = al1[f*16 + c]; arv1[f] = ar1[f*16 + c];
    }
    #pragma unroll
    for (int reg = 0; reg < 4; reg++){
        long orow = (long)blockIdx.x*64 + w*16 + kgrp*4 + reg;
        bool ok = orow < NN;
        if (ok){
            uint4 p0, p1;
            p0.x = cvtpk(acc[0][reg],  acc[4][reg]);
            p0.y = cvtpk(acc[1][reg],  acc[5][reg]);
            p0.z = cvtpk(acc[2][reg],  acc[6][reg]);
            p0.w = cvtpk(acc[3][reg],  acc[7][reg]);
            p1.x = cvtpk(acc[8][reg],  acc[12][reg]);
            p1.y = cvtpk(acc[9][reg],  acc[13][reg]);
            p1.z = cvtpk(acc[10][reg], acc[14][reg]);
            p1.w = cvtpk(acc[11][reg], acc[15][reg]);
            *(uint4*)&featb0[orow*FD + c*8] = p0;
            *(uint4*)&featb1[orow*FD + c*8] = p1;
        }
        if (H == 2){
            float pl00=0, pr00=0, pl01=0, pr01=0;
            float pl10=0, pr10=0, pl11=0, pr11=0;
            #pragma unroll
            for (int f = 0; f < 4; f++){
                pl00 = fmaf(acc[f][reg],    alv0[f],   pl00);
                pr00 = fmaf(acc[f][reg],    arv0[f],   pr00);
                pl01 = fmaf(acc[4+f][reg],  alv0[4+f], pl01);
                pr01 = fmaf(acc[4+f][reg],  arv0[4+f], pr01);
                pl10 = fmaf(acc[8+f][reg],  alv1[f],   pl10);
                pr10 = fmaf(acc[8+f][reg],  arv1[f],   pr10);
                pl11 = fmaf(acc[12+f][reg], alv1[4+f], pl11);
                pr11 = fmaf(acc[12+f][reg], arv1[4+f], pr11);
            }
            pl00 = red16(pl00); pr00 = red16(pr00);
            pl01 = red16(pl01); pr01 = red16(pr01);
            pl10 = red16(pl10); pr10 = red16(pr10);
            pl11 = red16(pl11); pr11 = red16(pr11);
            if (c == 0 && ok){
                el0[orow*2] = pl00; el0[orow*2+1] = pl01;
                er0[orow*2] = pr00; er0[orow*2+1] = pr01;
                el1[orow*2] = pl10; el1[orow*2+1] = pl11;
                er1[orow*2] = pr10; er1[orow*2+1] = pr11;
            }
        } else {
            float pl0=0, pr0=0, pl1=0, pr1=0;
            #pragma unroll
            for (int f = 0; f < 8; f++){
                pl0 = fmaf(acc[f][reg],   alv0[f], pl0);
                pr0 = fmaf(acc[f][reg],   arv0[f], pr0);
                pl1 = fmaf(acc[8+f][reg], alv1[f], pl1);
                pr1 = fmaf(acc[8+f][reg], arv1[f], pr1);
            }
            pl0 = red16(pl0); pr0 = red16(pr0);
            pl1 = red16(pl1); pr1 = red16(pr1);
            if (c == 0 && ok){
                el0[orow] = pl0; er0[orow] = pr0;
                el1[orow] = pl1; er1[orow] = pr1;
            }
        }
    }
}

// ---------- fused aggregation: 2 nodes/wave, packed FMA, 4 gathers in flight ----------
template<int H>
__global__ __launch_bounds__(256) void k_agg2(
                       const int* __restrict__ rowptr,   // 2*NN+1, rel1 at +NN
                       const int* __restrict__ colsrc,   // 2*NE unified
                       const float* __restrict__ el0, const float* __restrict__ er0,
                       const float* __restrict__ el1, const float* __restrict__ er1,
                       const ushort_t* __restrict__ featb0, const ushort_t* __restrict__ featb1,
                       const float* __restrict__ bias0, const float* __restrict__ bias1,
                       ushort_t* __restrict__ outb, float* __restrict__ outf){
    int lane = threadIdx.x & 63;
    int half = lane >> 5;
    int hl   = lane & 31;
    int sub  = lane & 15;
    int g    = (lane >> 4) & 1;
    int node = ((blockIdx.x * blockDim.x + threadIdx.x) >> 6) * 2 + half;
    if (node >= NN) return;
    int base0 = rowptr[node],       end0 = rowptr[node+1];
    int base1 = rowptr[NN + node],  end1 = rowptr[NN + node + 1];
    bool has0 = end0 > base0, has1 = end1 > base1;
    float er00 = er0[node*H];
    float er01 = (H == 2) ? er0[node*H + 1] : 0.f;
    float er10 = er1[node*H];
    float er11 = (H == 2) ? er1[node*H + 1] : 0.f;
    float2 ap0[4], ap1[4];
    #pragma unroll
    for (int i = 0; i < 4; i++){ ap0[i] = make_float2(0.f,0.f); ap1[i] = make_float2(0.f,0.f); }
    float s00=0.f, s01=0.f, s10=0.f, s11=0.f;
    while (base0 < end0 || base1 < end1){
        int nrem0 = end0 - base0, nrem1 = end1 - base1;
        bool act0 = hl < nrem0, act1 = hl < nrem1;
        int sv0 = act0 ? colsrc[base0 + hl] : 0;
        int sv1 = act1 ? colsrc[base1 + hl] : 0;
        float a00=0.f, a01=0.f, a10=0.f, a11=0.f;
        if (act0){
            if (H == 2){
                float2 e2 = *(const float2*)&el0[sv0*2];
                float e0 = e2.x + er00, e1 = e2.y + er01;
                e0 = (e0 > 0.f) ? e0 : 0.2f*e0;
                e1 = (e1 > 0.f) ? e1 : 0.2f*e1;
                a00 = __expf(e0); a01 = __expf(e1);
            } else {
                float e0 = el0[sv0] + er00;
                e0 = (e0 > 0.f) ? e0 : 0.2f*e0;
                a00 = __expf(e0);
            }
        }
        if (act1){
            if (H == 2){
                float2 e2 = *(const float2*)&el1[sv1*2];
                float e0 = e2.x + er10, e1 = e2.y + er11;
                e0 = (e0 > 0.f) ? e0 : 0.2f*e0;
                e1 = (e1 > 0.f) ? e1 : 0.2f*e1;
                a10 = __expf(e0); a11 = __expf(e1);
            } else {
                float e0 = el1[sv1] + er10;
                e0 = (e0 > 0.f) ? e0 : 0.2f*e0;
                a10 = __expf(e0);
            }
        }
        s00 += a00; s01 += a01; s10 += a10; s11 += a11;
        int nn0 = (nrem0 > 0) ? min(32, nrem0) : 0;
        int nn1 = (nrem1 > 0) ? min(32, nrem1) : 0;
        int nnm = (nn0 > nn1) ? nn0 : nn1;
        // 2 slot-pairs per iteration -> 4 independent dwordx4 gathers in flight
        for (int j4 = 0; j4 < nnm; j4 += 4){
            int slA = (half << 5) + j4 + g;
            int slB = slA + 2;
            int sj0A = __shfl(sv0, slA), sj0B = __shfl(sv0, slB);
            int sj1A = __shfl(sv1, slA), sj1B = __shfl(sv1, slB);
            float2 w0A, w0B, w1A, w1B;
            w0A.x = __shfl(a00, slA); w0A.y = (H == 2) ? __shfl(a01, slA) : w0A.x;
            w0B.x = __shfl(a00, slB); w0B.y = (H == 2) ? __shfl(a01, slB) : w0B.x;
            w1A.x = __shfl(a10, slA); w1A.y = (H == 2) ? __shfl(a11, slA) : w1A.x;
            w1B.x = __shfl(a10, slB); w1B.y = (H == 2) ? __shfl(a11, slB) : w1B.x;
            uint4 p0A = *(const uint4*)&featb0[(unsigned)sj0A*FD + sub*8];
            uint4 p0B = *(const uint4*)&featb0[(unsigned)sj0B*FD + sub*8];
            uint4 p1A = *(const uint4*)&featb1[(unsigned)sj1A*FD + sub*8];
            uint4 p1B = *(const uint4*)&featb1[(unsigned)sj1B*FD + sub*8];
            pkfma(ap0[0], w0A, up2(p0A.x));
            pkfma(ap0[1], w0A, up2(p0A.y));
            pkfma(ap0[2], w0A, up2(p0A.z));
            pkfma(ap0[3], w0A, up2(p0A.w));
            pkfma(ap0[0], w0B, up2(p0B.x));
            pkfma(ap0[1], w0B, up2(p0B.y));
            pkfma(ap0[2], w0B, up2(p0B.z));
            pkfma(ap0[3], w0B, up2(p0B.w));
            pkfma(ap1[0], w1A, up2(p1A.x));
            pkfma(ap1[1], w1A, up2(p1A.y));
            pkfma(ap1[2], w1A, up2(p1A.z));
            pkfma(ap1[3], w1A, up2(p1A.w));
            pkfma(ap1[0], w1B, up2(p1B.x));
            pkfma(ap1[1], w1B, up2(p1B.y));
            pkfma(ap1[2], w1B, up2(p1B.z));
            pkfma(ap1[3], w1B, up2(p1B.w));
        }
        base0 += 32; base1 += 32;
    }
    // s-reduce within the 32-lane half (5 levels)
    #pragma unroll
    for (int off = 16; off > 0; off >>= 1){
        s00 += __shfl_xor(s00, off);
        s10 += __shfl_xor(s10, off);
        if (H == 2){ s01 += __shfl_xor(s01, off); s11 += __shfl_xor(s11, off); }
    }
    // group-reduce across the 2 groups of this half (1 level)
    #pragma unroll
    for (int i = 0; i < 4; i++){
        ap0[i].x += __shfl_xor(ap0[i].x, 16); ap0[i].y += __shfl_xor(ap0[i].y, 16);
        ap1[i].x += __shfl_xor(ap1[i].x, 16); ap1[i].y += __shfl_xor(ap1[i].y, 16);
    }
    if (hl < 16){
        float i00 = has0 ? 1.f/s00 : 0.f;
        float i01 = (H == 2) ? (has0 ? 1.f/s01 : 0.f) : i00;
        float i10 = has1 ? 1.f/s10 : 0.f;
        float i11 = (H == 2) ? (has1 ? 1.f/s11 : 0.f) : i10;
        float2 vp[4];
        #pragma unroll
        for (int t = 0; t < 4; t++){
            float bx = bias0[t*16 + sub]       + bias1[t*16 + sub];
            float by = bias0[(t+4)*16 + sub]   + bias1[(t+4)*16 + sub];
            vp[t].x = 0.5f*(ap0[t].x*i00 + ap1[t].x*i10 + bx);
            vp[t].y = 0.5f*(ap0[t].y*i01 + ap1[t].y*i11 + by);
        }
        if (H == 2){
            #pragma unroll
            for (int t = 0; t < 4; t++){
                vp[t].x = fmaxf(vp[t].x, 0.f);
                vp[t].y = fmaxf(vp[t].y, 0.f);
            }
            uint4 o;
            o.x = cvtpk(vp[0].x, vp[0].y); o.y = cvtpk(vp[1].x, vp[1].y);
            o.z = cvtpk(vp[2].x, vp[2].y); o.w = cvtpk(vp[3].x, vp[3].y);
            *(uint4*)&outb[(size_t)node*FD + sub*8] = o;
        } else {
            #pragma unroll
            for (int t = 0; t < 4; t++){
                outf[(size_t)node*FD + t*16 + sub]     = vp[t].x;
                outf[(size_t)node*FD + (t+4)*16 + sub] = vp[t].y;
            }
        }
    }
}

// ---------- launch ----------
extern "C" void kernel_launch(void* const* d_in, const int* in_sizes, int n_in,
                              void* d_out, int out_size, void* d_ws, size_t ws_size,
                              hipStream_t stream){
    const float* x   = (const float*)d_in[0];
    const float* W1  = (const float*)d_in[1];
    const float* al1 = (const float*)d_in[2];
    const float* ar1 = (const float*)d_in[3];
    const float* b1  = (const float*)d_in[4];
    const float* W2  = (const float*)d_in[5];
    const float* al2 = (const float*)d_in[6];
    const float* ar2 = (const float*)d_in[7];
    const float* b2  = (const float*)d_in[8];
    const int*   src = (const int*)d_in[9];
    const int*   dst = (const int*)d_in[10];
    float* out = (float*)d_out;

    size_t off = 0;
    auto carve = [&](size_t bytes) -> char* {
        char* p = (char*)d_ws + off;
        off += (bytes + 255) & ~(size_t)255;
        return p;
    };
    ushort_t* h1b    = (ushort_t*)carve((size_t)NN * FD * 2);
    ushort_t* featb0 = (ushort_t*)carve((size_t)NN * FD * 2);
    ushort_t* featb1 = (ushort_t*)carve((size_t)NN * FD * 2);
    ushort_t* Wt1    = (ushort_t*)carve(32768 * 2);
    ushort_t* Wt2    = (ushort_t*)carve(32768 * 2);
    float* el0      = (float*)carve((size_t)NN * 2 * 4);
    float* er0      = (float*)carve((size_t)NN * 2 * 4);
    float* el1      = (float*)carve((size_t)NN * 2 * 4);
    float* er1      = (float*)carve((size_t)NN * 2 * 4);
    int*   rowptrA  = (int*)  carve((size_t)(2*NN + 1) * 4);
    int*   colsrcA  = (int*)  carve((size_t)2*NE * 4);
    int*   counts   = (int*)  carve((size_t)2*NN * 4);
    int*   partials = (int*)  carve(1024);
    int*   bcur     = (int*)  carve((size_t)NBK * 4);
    if (off > ws_size) return;
    // ebuf (12.8 MB) aliases featb0 (25.6 MB): consumed before the GEMM fills it
    uint2* ebuf = (uint2*)featb0;

    const int EB2 = (2*NE + 255) / 256;                    // 6250
    const int NB2 = (2*NN + SCAN_TILE - 1) / SCAN_TILE;    // 196
    const int PB  = (2*NE + CHUNK - 1) / CHUNK;            // 196 partition blocks
    const int GB  = (NN + 63) / 64;                        // 1563
    const int WB  = (NN + 7) / 8;                          // agg: 8 nodes/block

    // prep: W repack (both layers, one launch)
    k_prepw2<<<256, 256, 0, stream>>>(W1, W2, Wt1, Wt2);

    // CSR build: hist -> scan -> bucket partition -> per-bucket LDS-cursor scatter
    hipMemsetAsync(counts, 0, (size_t)2*NN * 4, stream);
    k_hist2<<<EB2, 256, 0, stream>>>(dst, counts);
    k_scan_partial<<<NB2, 256, 0, stream>>>(counts, 2*NN, partials);
    k_scan_partials_excl<<<1, 256, 0, stream>>>(partials, NB2);
    k_scan_final<<<NB2, 256, 0, stream>>>(counts, 2*NN, 2*NE, partials, rowptrA);
    k_bcur<<<2, 256, 0, stream>>>(rowptrA, bcur);
    k_part<<<PB, 256, 0, stream>>>(dst, src, bcur, ebuf);
    k_bscatter<<<NBK, 256, 0, stream>>>(ebuf, rowptrA, colsrcA);

    // layer 1: H=2, fp32 A read (cast fused); agg writes bf16 relu(h1)
    k_gemm_mfma<2, true><<<GB, 256, 0, stream>>>(nullptr, x, Wt1,
                                           al1, ar1, al1 + FD, ar1 + FD,
                                           featb0, featb1, el0, er0, el1, er1);
    k_agg2<2><<<WB, 256, 0, stream>>>(rowptrA, colsrcA,
                                      el0, er0, el1, er1, featb0, featb1,
                                      b1, b1 + FD, h1b, nullptr);

    // layer 2: H=1 (W2 rows pre-permuted to absorb h1b's layout)
    k_gemm_mfma<1, false><<<GB, 256, 0, stream>>>(h1b, nullptr, Wt2,
                                           al2, ar2, al2 + FD, ar2 + FD,
                                           featb0, featb1, el0, er0, el1, er1);
    k_agg2<1><<<WB, 256, 0, stream>>>(rowptrA, colsrcA,
                                      el0, er0, el1, er1, featb0, featb1,
                                      b2, b2 + FD, nullptr, out);
}

// Round 13
// 288.395 us; speedup vs baseline: 2.0583x; 1.2356x over previous
//
#include <hip/hip_runtime.h>
#include <hip/hip_bf16.h>
#include <math.h>

#define NN 100000     // nodes
#define NE 800000     // edges per relation
#define FD 128        // feature dim

#define BKW 512       // bucket width in (unified) dst-node space
#define NBK 391       // ceil(2*NN / BKW)
#define CAP 4608      // fixed ebuf capacity per bucket (mean 4096, sigma 64 -> +8 sigma)
#define CHUNK 8192    // edges per partition block

typedef unsigned short ushort_t;
typedef __attribute__((ext_vector_type(8))) short bf16x8;
typedef __attribute__((ext_vector_type(4))) float f32x4;

union U8 { uint4 u; bf16x8 b; };

// ---------- bf16 pack helpers ----------
__device__ inline unsigned f2bf(float f){              // software RNE (prep kernels)
    unsigned u = __float_as_uint(f);
    return (u + 0x7fffu + ((u >> 16) & 1u)) >> 16;
}
__device__ inline unsigned cvtpk(float lo, float hi){  // HW packed cvt (1 inst, RNE)
    unsigned r;
    asm("v_cvt_pk_bf16_f32 %0, %1, %2" : "=v"(r) : "v"(lo), "v"(hi));
    return r;
}
__device__ inline float blo(unsigned p){ return __uint_as_float(p << 16); }
__device__ inline float bhi(unsigned p){ return __uint_as_float(p & 0xffff0000u); }
__device__ inline float2 up2(unsigned p){ float2 f; f.x = blo(p); f.y = bhi(p); return f; }
// packed dual-FMA: d.x += a.x*b.x; d.y += a.y*b.y  (one VALU inst)
__device__ inline void pkfma(float2& d, float2 a, float2 b){
    asm("v_pk_fma_f32 %0, %1, %2, %0" : "+v"(d) : "v"(a), "v"(b));
}

// ---------- bucket cursor init: bcur[b] = b*CAP ----------
__global__ void k_binit(int* __restrict__ bcur){
    int t = blockIdx.x * blockDim.x + threadIdx.x;
    if (t < NBK) bcur[t] = t * CAP;
}

// ---------- pass A: partition edges into fixed-capacity buckets ----------
__global__ __launch_bounds__(256) void k_part(const int* __restrict__ dst,
                                              const int* __restrict__ src,
                                              int* __restrict__ bcur,
                                              uint2* __restrict__ ebuf){
    __shared__ int lcount[NBK];
    __shared__ int lbase[NBK];
    int t = threadIdx.x;
    long base = (long)blockIdx.x * CHUNK;
    for (int j = t; j < NBK; j += 256) lcount[j] = 0;
    __syncthreads();
    #pragma unroll 4
    for (int k = 0; k < CHUNK/256; k++){
        long i = base + k*256 + t;
        if (i < 2*NE){
            int b = (dst[i] + ((i >= NE) ? NN : 0)) >> 9;
            atomicAdd(&lcount[b], 1);
        }
    }
    __syncthreads();
    for (int j = t; j < NBK; j += 256){
        int c = lcount[j];
        lbase[j] = c ? atomicAdd(&bcur[j], c) : 0;
    }
    __syncthreads();
    for (int j = t; j < NBK; j += 256) lcount[j] = 0;
    __syncthreads();
    #pragma unroll 4
    for (int k = 0; k < CHUNK/256; k++){
        long i = base + k*256 + t;
        if (i < 2*NE){
            int dstU = dst[i] + ((i >= NE) ? NN : 0);
            int b = dstU >> 9;
            int r = atomicAdd(&lcount[b], 1);
            int pos = lbase[b] + r;
            if (pos < (b + 1) * CAP)   // capacity guard (statistically never trips)
                ebuf[pos] = make_uint2((unsigned)src[i], (unsigned)dstU);
        }
    }
}

// ---------- pass B: tiny scan over bucket totals -> global edge offsets ----------
__global__ __launch_bounds__(512) void k_bktscan(const int* __restrict__ bcur,
                                                 int* __restrict__ gbase,
                                                 int* __restrict__ rowptr){
    __shared__ int sm[512];
    int t = threadIdx.x;
    int v = (t < NBK) ? min(bcur[t] - t*CAP, CAP) : 0;
    sm[t] = v; __syncthreads();
    for (int off = 1; off < 512; off <<= 1){
        int add = (t >= off) ? sm[t-off] : 0;
        __syncthreads();
        sm[t] += add;
        __syncthreads();
    }
    if (t <= NBK) gbase[t] = sm[t] - v;   // exclusive
    if (t == 0) rowptr[2*NN] = 2*NE;      // sentinel
}

// ---------- pass C: per-bucket local hist+scan -> rowptr + compacted colsrc ----------
// One block owns bucket b = unified nodes [b*BKW, b*BKW+BKW).
__global__ __launch_bounds__(256) void k_bscatter(const uint2* __restrict__ ebuf,
                                                  const int* __restrict__ bcur,
                                                  const int* __restrict__ gbase,
                                                  int* __restrict__ rowptr,
                                                  int* __restrict__ colsrc){
    __shared__ int lhist[BKW];
    __shared__ int lcur[BKW];
    __shared__ int sm[256];
    int b = blockIdx.x;
    int n0 = b * BKW;
    int nloc = min(2*NN, n0 + BKW) - n0;
    int ecnt = min(bcur[b] - b*CAP, CAP);
    const uint2* eb = ebuf + (size_t)b * CAP;
    int t = threadIdx.x;
    lhist[2*t] = 0; lhist[2*t+1] = 0;
    __syncthreads();
    for (int i = t; i < ecnt; i += 256)
        atomicAdd(&lhist[eb[i].y - n0], 1);
    __syncthreads();
    // exclusive scan over 512 counters: 2 per thread + block scan of partials
    int a0 = lhist[2*t], a1 = lhist[2*t+1];
    int ps = a0 + a1;
    sm[t] = ps; __syncthreads();
    for (int off = 1; off < 256; off <<= 1){
        int add = (t >= off) ? sm[t-off] : 0;
        __syncthreads();
        sm[t] += add;
        __syncthreads();
    }
    int excl = sm[t] - ps;
    int g = gbase[b];
    int p0 = g + excl, p1 = g + excl + a0;
    if (2*t     < nloc) rowptr[n0 + 2*t]     = p0;
    if (2*t + 1 < nloc) rowptr[n0 + 2*t + 1] = p1;
    lcur[2*t] = p0; lcur[2*t+1] = p1;
    __syncthreads();
    for (int i = t; i < ecnt; i += 256){
        uint2 e = eb[i];
        int p = atomicAdd(&lcur[e.y - n0], 1);
        colsrc[p] = (int)e.x;
    }
}

// ---------- prep: both W matrices -> B-fragment-linear bf16 (one launch) ----------
// m=1 (layer 2): A rows come from h1b's interleaved-stored layout:
// linear A pos q holds logical col (((q&7)>>1) + 4*(q&1))*16 + (q>>3).
__global__ void k_prepw2(const float* __restrict__ W1, const float* __restrict__ W2,
                         ushort_t* __restrict__ Wt1, ushort_t* __restrict__ Wt2){
    int idx = blockIdx.x * blockDim.x + threadIdx.x;   // 65536 total
    if (idx >= 65536) return;
    int m = idx >> 15;
    int i = idx & 32767;
    const float* W = m ? W2 : W1;
    ushort_t* Wt   = m ? Wt2 : Wt1;
    int j  = i & 7;
    int l  = (i >> 3) & 63;
    int ks = (i >> 9) & 3;
    int f  = i >> 11;
    int k  = ks*32 + (l >> 4)*8 + j;
    if (m) k = (((k & 7) >> 1) + 4*(k & 1))*16 + (k >> 3);
    int col = (f & 7)*16 + (l & 15);
    int rel = f >> 3;
    Wt[i] = (ushort_t)f2bf(W[rel*16384 + k*FD + col]);
}

// ---------- helpers ----------
__device__ inline float red16(float v){
    v += __shfl_xor(v, 1);
    v += __shfl_xor(v, 2);
    v += __shfl_xor(v, 4);
    v += __shfl_xor(v, 8);
    return v;
}

// ---------- MFMA dual-relation GEMM + fused el/er ----------
// AF32: read fp32 A directly, convert fragments in-register.
// featb stored head-interleaved: stored[c*8 + 2t]   = logical col  t   *16+c
//                                stored[c*8 + 2t+1] = logical col (t+4)*16+c
template<int H, bool AF32>
__global__ __launch_bounds__(256) void k_gemm_mfma(
        const ushort_t* __restrict__ Ab, const float* __restrict__ Af,
        const ushort_t* __restrict__ Wt,
        const float* __restrict__ al0, const float* __restrict__ ar0,
        const float* __restrict__ al1, const float* __restrict__ ar1,
        ushort_t* __restrict__ featb0, ushort_t* __restrict__ featb1,
        float* __restrict__ el0, float* __restrict__ er0,
        float* __restrict__ el1, float* __restrict__ er1){
    int t = threadIdx.x;
    int w = t >> 6, l = t & 63;
    int c = l & 15, kgrp = l >> 4;
    const bf16x8* WtV = (const bf16x8*)Wt;
    long arow = (long)blockIdx.x*64 + w*16 + c;
    bf16x8 zero8 = {0,0,0,0,0,0,0,0};
    bf16x8 af[4];
    bool rok = arow < NN;
    if (AF32){
        const float4* xv = (const float4*)Af;
        #pragma unroll
        for (int ks = 0; ks < 4; ks++){
            if (rok){
                float4 u = xv[arow*32 + (ks*4 + kgrp)*2];
                float4 v = xv[arow*32 + (ks*4 + kgrp)*2 + 1];
                U8 q;
                q.u = make_uint4(cvtpk(u.x,u.y), cvtpk(u.z,u.w),
                                 cvtpk(v.x,v.y), cvtpk(v.z,v.w));
                af[ks] = q.b;
            } else af[ks] = zero8;
        }
    } else {
        const bf16x8* AbV = (const bf16x8*)Ab;
        #pragma unroll
        for (int ks = 0; ks < 4; ks++)
            af[ks] = rok ? AbV[arow*16 + ks*4 + kgrp] : zero8;
    }
    f32x4 acc[16];
    #pragma unroll
    for (int f = 0; f < 16; f++) acc[f] = (f32x4){0.f,0.f,0.f,0.f};
    #pragma unroll
    for (int f = 0; f < 16; f++){
        #pragma unroll
        for (int ks = 0; ks < 4; ks++){
            acc[f] = __builtin_amdgcn_mfma_f32_16x16x32_bf16(
                         af[ks], WtV[(f*4 + ks)*64 + l], acc[f], 0, 0, 0);
        }
    }
    float alv0[8], arv0[8], alv1[8], arv1[8];
    #pragma unroll
    for (int f = 0; f < 8; f++){
        alv0[f] = al0[f*16 + c]; arv0[f] = ar0[f*16 + c];
        alv1[f] = al1[f*16 + c]; arv1[f] = ar1[f*16 + c];
    }
    #pragma unroll
    for (int reg = 0; reg < 4; reg++){
        long orow = (long)blockIdx.x*64 + w*16 + kgrp*4 + reg;
        bool ok = orow < NN;
        if (ok){
            uint4 p0, p1;
            p0.x = cvtpk(acc[0][reg],  acc[4][reg]);
            p0.y = cvtpk(acc[1][reg],  acc[5][reg]);
            p0.z = cvtpk(acc[2][reg],  acc[6][reg]);
            p0.w = cvtpk(acc[3][reg],  acc[7][reg]);
            p1.x = cvtpk(acc[8][reg],  acc[12][reg]);
            p1.y = cvtpk(acc[9][reg],  acc[13][reg]);
            p1.z = cvtpk(acc[10][reg], acc[14][reg]);
            p1.w = cvtpk(acc[11][reg], acc[15][reg]);
            *(uint4*)&featb0[orow*FD + c*8] = p0;
            *(uint4*)&featb1[orow*FD + c*8] = p1;
        }
        if (H == 2){
            float pl00=0, pr00=0, pl01=0, pr01=0;
            float pl10=0, pr10=0, pl11=0, pr11=0;
            #pragma unroll
            for (int f = 0; f < 4; f++){
                pl00 = fmaf(acc[f][reg],    alv0[f],   pl00);
                pr00 = fmaf(acc[f][reg],    arv0[f],   pr00);
                pl01 = fmaf(acc[4+f][reg],  alv0[4+f], pl01);
                pr01 = fmaf(acc[4+f][reg],  arv0[4+f], pr01);
                pl10 = fmaf(acc[8+f][reg],  alv1[f],   pl10);
                pr10 = fmaf(acc[8+f][reg],  arv1[f],   pr10);
                pl11 = fmaf(acc[12+f][reg], alv1[4+f], pl11);
                pr11 = fmaf(acc[12+f][reg], arv1[4+f], pr11);
            }
            pl00 = red16(pl00); pr00 = red16(pr00);
            pl01 = red16(pl01); pr01 = red16(pr01);
            pl10 = red16(pl10); pr10 = red16(pr10);
            pl11 = red16(pl11); pr11 = red16(pr11);
            if (c == 0 && ok){
                el0[orow*2] = pl00; el0[orow*2+1] = pl01;
                er0[orow*2] = pr00; er0[orow*2+1] = pr01;
                el1[orow*2] = pl10; el1[orow*2+1] = pl11;
                er1[orow*2] = pr10; er1[orow*2+1] = pr11;
            }
        } else {
            float pl0=0, pr0=0, pl1=0, pr1=0;
            #pragma unroll
            for (int f = 0; f < 8; f++){
                pl0 = fmaf(acc[f][reg],   alv0[f], pl0);
                pr0 = fmaf(acc[f][reg],   arv0[f], pr0);
                pl1 = fmaf(acc[8+f][reg], alv1[f], pl1);
                pr1 = fmaf(acc[8+f][reg], arv1[f], pr1);
            }
            pl0 = red16(pl0); pr0 = red16(pr0);
            pl1 = red16(pl1); pr1 = red16(pr1);
            if (c == 0 && ok){
                el0[orow] = pl0; er0[orow] = pr0;
                el1[orow] = pl1; er1[orow] = pr1;
            }
        }
    }
}

// ---------- fused aggregation: 2 nodes/wave, packed FMA, 4 gathers in flight ----------
template<int H>
__global__ __launch_bounds__(256) void k_agg2(
                       const int* __restrict__ rowptr,   // 2*NN+1, rel1 at +NN
                       const int* __restrict__ colsrc,   // 2*NE unified
                       const float* __restrict__ el0, const float* __restrict__ er0,
                       const float* __restrict__ el1, const float* __restrict__ er1,
                       const ushort_t* __restrict__ featb0, const ushort_t* __restrict__ featb1,
                       const float* __restrict__ bias0, const float* __restrict__ bias1,
                       ushort_t* __restrict__ outb, float* __restrict__ outf){
    int lane = threadIdx.x & 63;
    int half = lane >> 5;
    int hl   = lane & 31;
    int sub  = lane & 15;
    int g    = (lane >> 4) & 1;
    int node = ((blockIdx.x * blockDim.x + threadIdx.x) >> 6) * 2 + half;
    if (node >= NN) return;
    int base0 = rowptr[node],       end0 = rowptr[node+1];
    int base1 = rowptr[NN + node],  end1 = rowptr[NN + node + 1];
    bool has0 = end0 > base0, has1 = end1 > base1;
    float er00 = er0[node*H];
    float er01 = (H == 2) ? er0[node*H + 1] : 0.f;
    float er10 = er1[node*H];
    float er11 = (H == 2) ? er1[node*H + 1] : 0.f;
    float2 ap0[4], ap1[4];
    #pragma unroll
    for (int i = 0; i < 4; i++){ ap0[i] = make_float2(0.f,0.f); ap1[i] = make_float2(0.f,0.f); }
    float s00=0.f, s01=0.f, s10=0.f, s11=0.f;
    while (base0 < end0 || base1 < end1){
        int nrem0 = end0 - base0, nrem1 = end1 - base1;
        bool act0 = hl < nrem0, act1 = hl < nrem1;
        int sv0 = act0 ? colsrc[base0 + hl] : 0;
        int sv1 = act1 ? colsrc[base1 + hl] : 0;
        float a00=0.f, a01=0.f, a10=0.f, a11=0.f;
        if (act0){
            if (H == 2){
                float2 e2 = *(const float2*)&el0[sv0*2];
                float e0 = e2.x + er00, e1 = e2.y + er01;
                e0 = (e0 > 0.f) ? e0 : 0.2f*e0;
                e1 = (e1 > 0.f) ? e1 : 0.2f*e1;
                a00 = __expf(e0); a01 = __expf(e1);
            } else {
                float e0 = el0[sv0] + er00;
                e0 = (e0 > 0.f) ? e0 : 0.2f*e0;
                a00 = __expf(e0);
            }
        }
        if (act1){
            if (H == 2){
                float2 e2 = *(const float2*)&el1[sv1*2];
                float e0 = e2.x + er10, e1 = e2.y + er11;
                e0 = (e0 > 0.f) ? e0 : 0.2f*e0;
                e1 = (e1 > 0.f) ? e1 : 0.2f*e1;
                a10 = __expf(e0); a11 = __expf(e1);
            } else {
                float e0 = el1[sv1] + er10;
                e0 = (e0 > 0.f) ? e0 : 0.2f*e0;
                a10 = __expf(e0);
            }
        }
        s00 += a00; s01 += a01; s10 += a10; s11 += a11;
        int nn0 = (nrem0 > 0) ? min(32, nrem0) : 0;
        int nn1 = (nrem1 > 0) ? min(32, nrem1) : 0;
        int nnm = (nn0 > nn1) ? nn0 : nn1;
        // 2 slot-pairs per iteration -> 4 independent dwordx4 gathers in flight
        for (int j4 = 0; j4 < nnm; j4 += 4){
            int slA = (half << 5) + j4 + g;
            int slB = slA + 2;
            int sj0A = __shfl(sv0, slA), sj0B = __shfl(sv0, slB);
            int sj1A = __shfl(sv1, slA), sj1B = __shfl(sv1, slB);
            float2 w0A, w0B, w1A, w1B;
            w0A.x = __shfl(a00, slA); w0A.y = (H == 2) ? __shfl(a01, slA) : w0A.x;
            w0B.x = __shfl(a00, slB); w0B.y = (H == 2) ? __shfl(a01, slB) : w0B.x;
            w1A.x = __shfl(a10, slA); w1A.y = (H == 2) ? __shfl(a11, slA) : w1A.x;
            w1B.x = __shfl(a10, slB); w1B.y = (H == 2) ? __shfl(a11, slB) : w1B.x;
            uint4 p0A = *(const uint4*)&featb0[(unsigned)sj0A*FD + sub*8];
            uint4 p0B = *(const uint4*)&featb0[(unsigned)sj0B*FD + sub*8];
            uint4 p1A = *(const uint4*)&featb1[(unsigned)sj1A*FD + sub*8];
            uint4 p1B = *(const uint4*)&featb1[(unsigned)sj1B*FD + sub*8];
            pkfma(ap0[0], w0A, up2(p0A.x));
            pkfma(ap0[1], w0A, up2(p0A.y));
            pkfma(ap0[2], w0A, up2(p0A.z));
            pkfma(ap0[3], w0A, up2(p0A.w));
            pkfma(ap0[0], w0B, up2(p0B.x));
            pkfma(ap0[1], w0B, up2(p0B.y));
            pkfma(ap0[2], w0B, up2(p0B.z));
            pkfma(ap0[3], w0B, up2(p0B.w));
            pkfma(ap1[0], w1A, up2(p1A.x));
            pkfma(ap1[1], w1A, up2(p1A.y));
            pkfma(ap1[2], w1A, up2(p1A.z));
            pkfma(ap1[3], w1A, up2(p1A.w));
            pkfma(ap1[0], w1B, up2(p1B.x));
            pkfma(ap1[1], w1B, up2(p1B.y));
            pkfma(ap1[2], w1B, up2(p1B.z));
            pkfma(ap1[3], w1B, up2(p1B.w));
        }
        base0 += 32; base1 += 32;
    }
    // s-reduce within the 32-lane half (5 levels)
    #pragma unroll
    for (int off = 16; off > 0; off >>= 1){
        s00 += __shfl_xor(s00, off);
        s10 += __shfl_xor(s10, off);
        if (H == 2){ s01 += __shfl_xor(s01, off); s11 += __shfl_xor(s11, off); }
    }
    // group-reduce across the 2 groups of this half (1 level)
    #pragma unroll
    for (int i = 0; i < 4; i++){
        ap0[i].x += __shfl_xor(ap0[i].x, 16); ap0[i].y += __shfl_xor(ap0[i].y, 16);
        ap1[i].x += __shfl_xor(ap1[i].x, 16); ap1[i].y += __shfl_xor(ap1[i].y, 16);
    }
    if (hl < 16){
        float i00 = has0 ? 1.f/s00 : 0.f;
        float i01 = (H == 2) ? (has0 ? 1.f/s01 : 0.f) : i00;
        float i10 = has1 ? 1.f/s10 : 0.f;
        float i11 = (H == 2) ? (has1 ? 1.f/s11 : 0.f) : i10;
        float2 vp[4];
        #pragma unroll
        for (int t = 0; t < 4; t++){
            float bx = bias0[t*16 + sub]       + bias1[t*16 + sub];
            float by = bias0[(t+4)*16 + sub]   + bias1[(t+4)*16 + sub];
            vp[t].x = 0.5f*(ap0[t].x*i00 + ap1[t].x*i10 + bx);
            vp[t].y = 0.5f*(ap0[t].y*i01 + ap1[t].y*i11 + by);
        }
        if (H == 2){
            #pragma unroll
            for (int t = 0; t < 4; t++){
                vp[t].x = fmaxf(vp[t].x, 0.f);
                vp[t].y = fmaxf(vp[t].y, 0.f);
            }
            uint4 o;
            o.x = cvtpk(vp[0].x, vp[0].y); o.y = cvtpk(vp[1].x, vp[1].y);
            o.z = cvtpk(vp[2].x, vp[2].y); o.w = cvtpk(vp[3].x, vp[3].y);
            *(uint4*)&outb[(size_t)node*FD + sub*8] = o;
        } else {
            #pragma unroll
            for (int t = 0; t < 4; t++){
                outf[(size_t)node*FD + t*16 + sub]     = vp[t].x;
                outf[(size_t)node*FD + (t+4)*16 + sub] = vp[t].y;
            }
        }
    }
}

// ---------- launch ----------
extern "C" void kernel_launch(void* const* d_in, const int* in_sizes, int n_in,
                              void* d_out, int out_size, void* d_ws, size_t ws_size,
                              hipStream_t stream){
    const float* x   = (const float*)d_in[0];
    const float* W1  = (const float*)d_in[1];
    const float* al1 = (const float*)d_in[2];
    const float* ar1 = (const float*)d_in[3];
    const float* b1  = (const float*)d_in[4];
    const float* W2  = (const float*)d_in[5];
    const float* al2 = (const float*)d_in[6];
    const float* ar2 = (const float*)d_in[7];
    const float* b2  = (const float*)d_in[8];
    const int*   src = (const int*)d_in[9];
    const int*   dst = (const int*)d_in[10];
    float* out = (float*)d_out;

    size_t off = 0;
    auto carve = [&](size_t bytes) -> char* {
        char* p = (char*)d_ws + off;
        off += (bytes + 255) & ~(size_t)255;
        return p;
    };
    ushort_t* h1b    = (ushort_t*)carve((size_t)NN * FD * 2);
    ushort_t* featb0 = (ushort_t*)carve((size_t)NN * FD * 2);
    ushort_t* featb1 = (ushort_t*)carve((size_t)NN * FD * 2);
    ushort_t* Wt1    = (ushort_t*)carve(32768 * 2);
    ushort_t* Wt2    = (ushort_t*)carve(32768 * 2);
    float* el0      = (float*)carve((size_t)NN * 2 * 4);
    float* er0      = (float*)carve((size_t)NN * 2 * 4);
    float* el1      = (float*)carve((size_t)NN * 2 * 4);
    float* er1      = (float*)carve((size_t)NN * 2 * 4);
    int*   rowptrA  = (int*)  carve((size_t)(2*NN + 1) * 4);
    int*   colsrcA  = (int*)  carve((size_t)2*NE * 4);
    int*   bcur     = (int*)  carve((size_t)NBK * 4);
    int*   gbase    = (int*)  carve((size_t)(NBK + 1) * 4);
    if (off > ws_size) return;
    // ebuf (NBK*CAP*8B = 14.4 MB) aliases featb0+featb1 (51.2 MB): consumed pre-GEMM
    uint2* ebuf = (uint2*)featb0;

    const int PB = (2*NE + CHUNK - 1) / CHUNK;             // 196 partition blocks
    const int GB = (NN + 63) / 64;                         // 1563
    const int WB = (NN + 7) / 8;                           // agg: 8 nodes/block

    // prep: W repack (both layers, one launch)
    k_prepw2<<<256, 256, 0, stream>>>(W1, W2, Wt1, Wt2);

    // CSR build (scan-free): binit -> part -> bucket-total scan -> local hist+scatter
    k_binit<<<2, 256, 0, stream>>>(bcur);
    k_part<<<PB, 256, 0, stream>>>(dst, src, bcur, ebuf);
    k_bktscan<<<1, 512, 0, stream>>>(bcur, gbase, rowptrA);
    k_bscatter<<<NBK, 256, 0, stream>>>(ebuf, bcur, gbase, rowptrA, colsrcA);

    // layer 1: H=2, fp32 A read (cast fused); agg writes bf16 relu(h1)
    k_gemm_mfma<2, true><<<GB, 256, 0, stream>>>(nullptr, x, Wt1,
                                           al1, ar1, al1 + FD, ar1 + FD,
                                           featb0, featb1, el0, er0, el1, er1);
    k_agg2<2><<<WB, 256, 0, stream>>>(rowptrA, colsrcA,
                                      el0, er0, el1, er1, featb0, featb1,
                                      b1, b1 + FD, h1b, nullptr);

    // layer 2: H=1 (W2 rows pre-permuted to absorb h1b's layout)
    k_gemm_mfma<1, false><<<GB, 256, 0, stream>>>(h1b, nullptr, Wt2,
                                           al2, ar2, al2 + FD, ar2 + FD,
                                           featb0, featb1, el0, er0, el1, er1);
    k_agg2<1><<<WB, 256, 0, stream>>>(rowptrA, colsrcA,
                                      el0, er0, el1, er1, featb0, featb1,
                                      b2, b2 + FD, nullptr, out);
}

// Round 14
// 283.895 us; speedup vs baseline: 2.0909x; 1.0159x over previous
//
#include <hip/hip_runtime.h>
#include <hip/hip_bf16.h>
#include <math.h>

#define NN 100000     // nodes
#define NE 800000     // edges per relation
#define FD 128        // feature dim

#define BKW 512       // bucket width in (unified) dst-node space
#define NBK 391       // ceil(2*NN / BKW)
#define CAP 4608      // fixed ebuf capacity per bucket (mean 4096 + 8 sigma)
#define CHUNK 8192    // edges per partition block

typedef unsigned short ushort_t;
typedef __attribute__((ext_vector_type(8))) short bf16x8;
typedef __attribute__((ext_vector_type(4))) float f32x4;

union U8 { uint4 u; bf16x8 b; };

// ---------- bf16 pack helpers ----------
__device__ inline unsigned f2bf(float f){              // software RNE (prep kernels)
    unsigned u = __float_as_uint(f);
    return (u + 0x7fffu + ((u >> 16) & 1u)) >> 16;
}
__device__ inline unsigned cvtpk(float lo, float hi){  // HW packed cvt (1 inst, RNE)
    unsigned r;
    asm("v_cvt_pk_bf16_f32 %0, %1, %2" : "=v"(r) : "v"(lo), "v"(hi));
    return r;
}
__device__ inline float blo(unsigned p){ return __uint_as_float(p << 16); }
__device__ inline float bhi(unsigned p){ return __uint_as_float(p & 0xffff0000u); }
__device__ inline float2 up2(unsigned p){ float2 f; f.x = blo(p); f.y = bhi(p); return f; }
// packed dual-FMA: d.x += a.x*b.x; d.y += a.y*b.y  (one VALU inst)
__device__ inline void pkfma(float2& d, float2 a, float2 b){
    asm("v_pk_fma_f32 %0, %1, %2, %0" : "+v"(d) : "v"(a), "v"(b));
}

// ---------- pass A: partition edges into fixed-capacity buckets ----------
__global__ __launch_bounds__(256) void k_part(const int* __restrict__ dst,
                                              const int* __restrict__ src,
                                              int* __restrict__ bcur,
                                              uint2* __restrict__ ebuf){
    __shared__ int lcount[NBK];
    __shared__ int lbase[NBK];
    int t = threadIdx.x;
    long base = (long)blockIdx.x * CHUNK;
    for (int j = t; j < NBK; j += 256) lcount[j] = 0;
    __syncthreads();
    #pragma unroll 4
    for (int k = 0; k < CHUNK/256; k++){
        long i = base + k*256 + t;
        if (i < 2*NE){
            int b = (dst[i] + ((i >= NE) ? NN : 0)) >> 9;
            atomicAdd(&lcount[b], 1);
        }
    }
    __syncthreads();
    for (int j = t; j < NBK; j += 256){
        int c = lcount[j];
        lbase[j] = c ? atomicAdd(&bcur[j], c) : 0;
    }
    __syncthreads();
    for (int j = t; j < NBK; j += 256) lcount[j] = 0;
    __syncthreads();
    #pragma unroll 4
    for (int k = 0; k < CHUNK/256; k++){
        long i = base + k*256 + t;
        if (i < 2*NE){
            int dstU = dst[i] + ((i >= NE) ? NN : 0);
            int b = dstU >> 9;
            int r = atomicAdd(&lcount[b], 1);
            int pos = lbase[b] + r;
            if (pos < (b + 1) * CAP)   // capacity guard (statistically never trips)
                ebuf[pos] = make_uint2((unsigned)src[i], (unsigned)dstU);
        }
    }
}

// ---------- pass B: tiny scan over bucket totals -> global edge offsets ----------
__global__ __launch_bounds__(512) void k_bktscan(const int* __restrict__ bcur,
                                                 int* __restrict__ gbase,
                                                 int* __restrict__ rowptr){
    __shared__ int sm[512];
    int t = threadIdx.x;
    int v = (t < NBK) ? min(bcur[t] - t*CAP, CAP) : 0;
    sm[t] = v; __syncthreads();
    for (int off = 1; off < 512; off <<= 1){
        int add = (t >= off) ? sm[t-off] : 0;
        __syncthreads();
        sm[t] += add;
        __syncthreads();
    }
    if (t <= NBK) gbase[t] = sm[t] - v;   // exclusive
    if (t == 0) rowptr[2*NN] = 2*NE;      // sentinel
}

// ---------- pass C: per-bucket local hist+scan -> rowptr + compacted colsrc ----------
// One block owns bucket b; edges staged in LDS (single global read of ebuf).
__global__ __launch_bounds__(256) void k_bscatter(const uint2* __restrict__ ebuf,
                                                  const int* __restrict__ bcur,
                                                  const int* __restrict__ gbase,
                                                  int* __restrict__ rowptr,
                                                  int* __restrict__ colsrc){
    __shared__ uint2 se[CAP];      // 36 KB edge stage
    __shared__ int lhist[BKW];
    __shared__ int lcur[BKW];
    __shared__ int sm[256];
    int b = blockIdx.x;
    int n0 = b * BKW;
    int nloc = min(2*NN, n0 + BKW) - n0;
    int ecnt = min(bcur[b] - b*CAP, CAP);
    const uint2* eb = ebuf + (size_t)b * CAP;
    int t = threadIdx.x;
    lhist[2*t] = 0; lhist[2*t+1] = 0;
    __syncthreads();
    for (int i = t; i < ecnt; i += 256){
        uint2 e = eb[i];
        se[i] = e;
        atomicAdd(&lhist[e.y - n0], 1);
    }
    __syncthreads();
    int a0 = lhist[2*t], a1 = lhist[2*t+1];
    int ps = a0 + a1;
    sm[t] = ps; __syncthreads();
    for (int off = 1; off < 256; off <<= 1){
        int add = (t >= off) ? sm[t-off] : 0;
        __syncthreads();
        sm[t] += add;
        __syncthreads();
    }
    int excl = sm[t] - ps;
    int g = gbase[b];
    int p0 = g + excl, p1 = g + excl + a0;
    if (2*t     < nloc) rowptr[n0 + 2*t]     = p0;
    if (2*t + 1 < nloc) rowptr[n0 + 2*t + 1] = p1;
    lcur[2*t] = p0; lcur[2*t+1] = p1;
    __syncthreads();
    for (int i = t; i < ecnt; i += 256){
        uint2 e = se[i];
        int p = atomicAdd(&lcur[e.y - n0], 1);
        colsrc[p] = (int)e.x;
    }
}

// ---------- prep: both W matrices -> B-fragment bf16, + bucket cursor init ----------
// m=1 (layer 2): A rows come from h1b's interleaved-stored layout:
// linear A pos q holds logical col (((q&7)>>1) + 4*(q&1))*16 + (q>>3).
__global__ void k_prepw2(const float* __restrict__ W1, const float* __restrict__ W2,
                         ushort_t* __restrict__ Wt1, ushort_t* __restrict__ Wt2,
                         int* __restrict__ bcur){
    int idx = blockIdx.x * blockDim.x + threadIdx.x;
    if (idx >= 65536){
        int t = idx - 65536;
        if (t < NBK) bcur[t] = t * CAP;   // fused k_binit
        return;
    }
    int m = idx >> 15;
    int i = idx & 32767;
    const float* W = m ? W2 : W1;
    ushort_t* Wt   = m ? Wt2 : Wt1;
    int j  = i & 7;
    int l  = (i >> 3) & 63;
    int ks = (i >> 9) & 3;
    int f  = i >> 11;
    int k  = ks*32 + (l >> 4)*8 + j;
    if (m) k = (((k & 7) >> 1) + 4*(k & 1))*16 + (k >> 3);
    int col = (f & 7)*16 + (l & 15);
    int rel = f >> 3;
    Wt[i] = (ushort_t)f2bf(W[rel*16384 + k*FD + col]);
}

// ---------- helpers ----------
__device__ inline float red16(float v){
    v += __shfl_xor(v, 1);
    v += __shfl_xor(v, 2);
    v += __shfl_xor(v, 4);
    v += __shfl_xor(v, 8);
    return v;
}

// ---------- MFMA dual-relation GEMM + fused el/er ----------
// AF32: read fp32 A directly, convert fragments in-register.
// featb stored head-interleaved: stored[c*8 + 2t]   = logical col  t   *16+c
//                                stored[c*8 + 2t+1] = logical col (t+4)*16+c
template<int H, bool AF32>
__global__ __launch_bounds__(256) void k_gemm_mfma(
        const ushort_t* __restrict__ Ab, const float* __restrict__ Af,
        const ushort_t* __restrict__ Wt,
        const float* __restrict__ al0, const float* __restrict__ ar0,
        const float* __restrict__ al1, const float* __restrict__ ar1,
        ushort_t* __restrict__ featb0, ushort_t* __restrict__ featb1,
        float* __restrict__ el0, float* __restrict__ er0,
        float* __restrict__ el1, float* __restrict__ er1){
    int t = threadIdx.x;
    int w = t >> 6, l = t & 63;
    int c = l & 15, kgrp = l >> 4;
    const bf16x8* WtV = (const bf16x8*)Wt;
    long arow = (long)blockIdx.x*64 + w*16 + c;
    bf16x8 zero8 = {0,0,0,0,0,0,0,0};
    bf16x8 af[4];
    bool rok = arow < NN;
    if (AF32){
        const float4* xv = (const float4*)Af;
        #pragma unroll
        for (int ks = 0; ks < 4; ks++){
            if (rok){
                float4 u = xv[arow*32 + (ks*4 + kgrp)*2];
                float4 v = xv[arow*32 + (ks*4 + kgrp)*2 + 1];
                U8 q;
                q.u = make_uint4(cvtpk(u.x,u.y), cvtpk(u.z,u.w),
                                 cvtpk(v.x,v.y), cvtpk(v.z,v.w));
                af[ks] = q.b;
            } else af[ks] = zero8;
        }
    } else {
        const bf16x8* AbV = (const bf16x8*)Ab;
        #pragma unroll
        for (int ks = 0; ks < 4; ks++)
            af[ks] = rok ? AbV[arow*16 + ks*4 + kgrp] : zero8;
    }
    f32x4 acc[16];
    #pragma unroll
    for (int f = 0; f < 16; f++) acc[f] = (f32x4){0.f,0.f,0.f,0.f};
    #pragma unroll
    for (int f = 0; f < 16; f++){
        #pragma unroll
        for (int ks = 0; ks < 4; ks++){
            acc[f] = __builtin_amdgcn_mfma_f32_16x16x32_bf16(
                         af[ks], WtV[(f*4 + ks)*64 + l], acc[f], 0, 0, 0);
        }
    }
    float alv0[8], arv0[8], alv1[8], arv1[8];
    #pragma unroll
    for (int f = 0; f < 8; f++){
        alv0[f] = al0[f*16 + c]; arv0[f] = ar0[f*16 + c];
        alv1[f] = al1[f*16 + c]; arv1[f] = ar1[f*16 + c];
    }
    #pragma unroll
    for (int reg = 0; reg < 4; reg++){
        long orow = (long)blockIdx.x*64 + w*16 + kgrp*4 + reg;
        bool ok = orow < NN;
        if (ok){
            uint4 p0, p1;
            p0.x = cvtpk(acc[0][reg],  acc[4][reg]);
            p0.y = cvtpk(acc[1][reg],  acc[5][reg]);
            p0.z = cvtpk(acc[2][reg],  acc[6][reg]);
            p0.w = cvtpk(acc[3][reg],  acc[7][reg]);
            p1.x = cvtpk(acc[8][reg],  acc[12][reg]);
            p1.y = cvtpk(acc[9][reg],  acc[13][reg]);
            p1.z = cvtpk(acc[10][reg], acc[14][reg]);
            p1.w = cvtpk(acc[11][reg], acc[15][reg]);
            *(uint4*)&featb0[orow*FD + c*8] = p0;
            *(uint4*)&featb1[orow*FD + c*8] = p1;
        }
        if (H == 2){
            float pl00=0, pr00=0, pl01=0, pr01=0;
            float pl10=0, pr10=0, pl11=0, pr11=0;
            #pragma unroll
            for (int f = 0; f < 4; f++){
                pl00 = fmaf(acc[f][reg],    alv0[f],   pl00);
                pr00 = fmaf(acc[f][reg],    arv0[f],   pr00);
                pl01 = fmaf(acc[4+f][reg],  alv0[4+f], pl01);
                pr01 = fmaf(acc[4+f][reg],  arv0[4+f], pr01);
                pl10 = fmaf(acc[8+f][reg],  alv1[f],   pl10);
                pr10 = fmaf(acc[8+f][reg],  arv1[f],   pr10);
                pl11 = fmaf(acc[12+f][reg], alv1[4+f], pl11);
                pr11 = fmaf(acc[12+f][reg], arv1[4+f], pr11);
            }
            pl00 = red16(pl00); pr00 = red16(pr00);
            pl01 = red16(pl01); pr01 = red16(pr01);
            pl10 = red16(pl10); pr10 = red16(pr10);
            pl11 = red16(pl11); pr11 = red16(pr11);
            if (c == 0 && ok){
                el0[orow*2] = pl00; el0[orow*2+1] = pl01;
                er0[orow*2] = pr00; er0[orow*2+1] = pr01;
                el1[orow*2] = pl10; el1[orow*2+1] = pl11;
                er1[orow*2] = pr10; er1[orow*2+1] = pr11;
            }
        } else {
            float pl0=0, pr0=0, pl1=0, pr1=0;
            #pragma unroll
            for (int f = 0; f < 8; f++){
                pl0 = fmaf(acc[f][reg],   alv0[f], pl0);
                pr0 = fmaf(acc[f][reg],   arv0[f], pr0);
                pl1 = fmaf(acc[8+f][reg], alv1[f], pl1);
                pr1 = fmaf(acc[8+f][reg], arv1[f], pr1);
            }
            pl0 = red16(pl0); pr0 = red16(pr0);
            pl1 = red16(pl1); pr1 = red16(pr1);
            if (c == 0 && ok){
                el0[orow] = pl0; er0[orow] = pr0;
                el1[orow] = pl1; er1[orow] = pr1;
            }
        }
    }
}

// ---------- fused aggregation: 2 nodes/wave, LDS-staged edge records ----------
// Per 32-edge chunk each lane stages {src, w_h0, w_h1} as float4 (2 ds_write_b128);
// inner loop fetches each slot's record with 1 broadcast ds_read_b128 (4 DS ops/iter
// instead of 12 ds_bpermute). Same-wave DS ordering makes this barrier-free.
template<int H>
__global__ __launch_bounds__(256) void k_agg2(
                       const int* __restrict__ rowptr,   // 2*NN+1, rel1 at +NN
                       const int* __restrict__ colsrc,   // 2*NE unified
                       const float* __restrict__ el0, const float* __restrict__ er0,
                       const float* __restrict__ el1, const float* __restrict__ er1,
                       const ushort_t* __restrict__ featb0, const ushort_t* __restrict__ featb1,
                       const float* __restrict__ bias0, const float* __restrict__ bias1,
                       ushort_t* __restrict__ outb, float* __restrict__ outf){
    __shared__ float4 stg[4][2][2][32];   // [wave][half][rel][slot] = 8 KB
    int wid  = threadIdx.x >> 6;
    int lane = threadIdx.x & 63;
    int half = lane >> 5;
    int hl   = lane & 31;
    int sub  = lane & 15;
    int g    = (lane >> 4) & 1;
    int node = ((blockIdx.x * blockDim.x + threadIdx.x) >> 6) * 2 + half;
    if (node >= NN) return;
    int base0 = rowptr[node],       end0 = rowptr[node+1];
    int base1 = rowptr[NN + node],  end1 = rowptr[NN + node + 1];
    bool has0 = end0 > base0, has1 = end1 > base1;
    float er00 = er0[node*H];
    float er01 = (H == 2) ? er0[node*H + 1] : 0.f;
    float er10 = er1[node*H];
    float er11 = (H == 2) ? er1[node*H + 1] : 0.f;
    float2 ap0[4], ap1[4];
    #pragma unroll
    for (int i = 0; i < 4; i++){ ap0[i] = make_float2(0.f,0.f); ap1[i] = make_float2(0.f,0.f); }
    float s00=0.f, s01=0.f, s10=0.f, s11=0.f;
    while (base0 < end0 || base1 < end1){
        int nrem0 = end0 - base0, nrem1 = end1 - base1;
        bool act0 = hl < nrem0, act1 = hl < nrem1;
        int sv0 = act0 ? colsrc[base0 + hl] : 0;
        int sv1 = act1 ? colsrc[base1 + hl] : 0;
        float a00=0.f, a01=0.f, a10=0.f, a11=0.f;
        if (act0){
            if (H == 2){
                float2 e2 = *(const float2*)&el0[sv0*2];
                float e0 = e2.x + er00, e1 = e2.y + er01;
                e0 = (e0 > 0.f) ? e0 : 0.2f*e0;
                e1 = (e1 > 0.f) ? e1 : 0.2f*e1;
                a00 = __expf(e0); a01 = __expf(e1);
            } else {
                float e0 = el0[sv0] + er00;
                e0 = (e0 > 0.f) ? e0 : 0.2f*e0;
                a00 = __expf(e0);
            }
        }
        if (act1){
            if (H == 2){
                float2 e2 = *(const float2*)&el1[sv1*2];
                float e0 = e2.x + er10, e1 = e2.y + er11;
                e0 = (e0 > 0.f) ? e0 : 0.2f*e0;
                e1 = (e1 > 0.f) ? e1 : 0.2f*e1;
                a10 = __expf(e0); a11 = __expf(e1);
            } else {
                float e0 = el1[sv1] + er10;
                e0 = (e0 > 0.f) ? e0 : 0.2f*e0;
                a10 = __expf(e0);
            }
        }
        s00 += a00; s01 += a01; s10 += a10; s11 += a11;
        stg[wid][half][0][hl] = make_float4(__int_as_float(sv0), a00,
                                            (H == 2) ? a01 : a00, 0.f);
        stg[wid][half][1][hl] = make_float4(__int_as_float(sv1), a10,
                                            (H == 2) ? a11 : a10, 0.f);
        __builtin_amdgcn_sched_barrier(0);   // keep reads after the stage
        int nn0 = (nrem0 > 0) ? min(32, nrem0) : 0;
        int nn1 = (nrem1 > 0) ? min(32, nrem1) : 0;
        int nnm = (nn0 > nn1) ? nn0 : nn1;
        for (int j4 = 0; j4 < nnm; j4 += 4){
            int sA = j4 + g, sB = sA + 2;
            float4 e0A = stg[wid][half][0][sA];
            float4 e0B = stg[wid][half][0][sB];
            float4 e1A = stg[wid][half][1][sA];
            float4 e1B = stg[wid][half][1][sB];
            uint4 p0A = *(const uint4*)&featb0[__float_as_uint(e0A.x)*FD + sub*8];
            uint4 p0B = *(const uint4*)&featb0[__float_as_uint(e0B.x)*FD + sub*8];
            uint4 p1A = *(const uint4*)&featb1[__float_as_uint(e1A.x)*FD + sub*8];
            uint4 p1B = *(const uint4*)&featb1[__float_as_uint(e1B.x)*FD + sub*8];
            float2 w0A = make_float2(e0A.y, e0A.z);
            float2 w0B = make_float2(e0B.y, e0B.z);
            float2 w1A = make_float2(e1A.y, e1A.z);
            float2 w1B = make_float2(e1B.y, e1B.z);
            pkfma(ap0[0], w0A, up2(p0A.x));
            pkfma(ap0[1], w0A, up2(p0A.y));
            pkfma(ap0[2], w0A, up2(p0A.z));
            pkfma(ap0[3], w0A, up2(p0A.w));
            pkfma(ap0[0], w0B, up2(p0B.x));
            pkfma(ap0[1], w0B, up2(p0B.y));
            pkfma(ap0[2], w0B, up2(p0B.z));
            pkfma(ap0[3], w0B, up2(p0B.w));
            pkfma(ap1[0], w1A, up2(p1A.x));
            pkfma(ap1[1], w1A, up2(p1A.y));
            pkfma(ap1[2], w1A, up2(p1A.z));
            pkfma(ap1[3], w1A, up2(p1A.w));
            pkfma(ap1[0], w1B, up2(p1B.x));
            pkfma(ap1[1], w1B, up2(p1B.y));
            pkfma(ap1[2], w1B, up2(p1B.z));
            pkfma(ap1[3], w1B, up2(p1B.w));
        }
        base0 += 32; base1 += 32;
    }
    // s-reduce within the 32-lane half (5 levels)
    #pragma unroll
    for (int off = 16; off > 0; off >>= 1){
        s00 += __shfl_xor(s00, off);
        s10 += __shfl_xor(s10, off);
        if (H == 2){ s01 += __shfl_xor(s01, off); s11 += __shfl_xor(s11, off); }
    }
    // group-reduce across the 2 groups of this half (1 level)
    #pragma unroll
    for (int i = 0; i < 4; i++){
        ap0[i].x += __shfl_xor(ap0[i].x, 16); ap0[i].y += __shfl_xor(ap0[i].y, 16);
        ap1[i].x += __shfl_xor(ap1[i].x, 16); ap1[i].y += __shfl_xor(ap1[i].y, 16);
    }
    if (hl < 16){
        float i00 = has0 ? 1.f/s00 : 0.f;
        float i01 = (H == 2) ? (has0 ? 1.f/s01 : 0.f) : i00;
        float i10 = has1 ? 1.f/s10 : 0.f;
        float i11 = (H == 2) ? (has1 ? 1.f/s11 : 0.f) : i10;
        float2 vp[4];
        #pragma unroll
        for (int t = 0; t < 4; t++){
            float bx = bias0[t*16 + sub]       + bias1[t*16 + sub];
            float by = bias0[(t+4)*16 + sub]   + bias1[(t+4)*16 + sub];
            vp[t].x = 0.5f*(ap0[t].x*i00 + ap1[t].x*i10 + bx);
            vp[t].y = 0.5f*(ap0[t].y*i01 + ap1[t].y*i11 + by);
        }
        if (H == 2){
            #pragma unroll
            for (int t = 0; t < 4; t++){
                vp[t].x = fmaxf(vp[t].x, 0.f);
                vp[t].y = fmaxf(vp[t].y, 0.f);
            }
            uint4 o;
            o.x = cvtpk(vp[0].x, vp[0].y); o.y = cvtpk(vp[1].x, vp[1].y);
            o.z = cvtpk(vp[2].x, vp[2].y); o.w = cvtpk(vp[3].x, vp[3].y);
            *(uint4*)&outb[(size_t)node*FD + sub*8] = o;
        } else {
            #pragma unroll
            for (int t = 0; t < 4; t++){
                outf[(size_t)node*FD + t*16 + sub]     = vp[t].x;
                outf[(size_t)node*FD + (t+4)*16 + sub] = vp[t].y;
            }
        }
    }
}

// ---------- launch ----------
extern "C" void kernel_launch(void* const* d_in, const int* in_sizes, int n_in,
                              void* d_out, int out_size, void* d_ws, size_t ws_size,
                              hipStream_t stream){
    const float* x   = (const float*)d_in[0];
    const float* W1  = (const float*)d_in[1];
    const float* al1 = (const float*)d_in[2];
    const float* ar1 = (const float*)d_in[3];
    const float* b1  = (const float*)d_in[4];
    const float* W2  = (const float*)d_in[5];
    const float* al2 = (const float*)d_in[6];
    const float* ar2 = (const float*)d_in[7];
    const float* b2  = (const float*)d_in[8];
    const int*   src = (const int*)d_in[9];
    const int*   dst = (const int*)d_in[10];
    float* out = (float*)d_out;

    size_t off = 0;
    auto carve = [&](size_t bytes) -> char* {
        char* p = (char*)d_ws + off;
        off += (bytes + 255) & ~(size_t)255;
        return p;
    };
    ushort_t* h1b    = (ushort_t*)carve((size_t)NN * FD * 2);
    ushort_t* featb0 = (ushort_t*)carve((size_t)NN * FD * 2);
    ushort_t* featb1 = (ushort_t*)carve((size_t)NN * FD * 2);
    ushort_t* Wt1    = (ushort_t*)carve(32768 * 2);
    ushort_t* Wt2    = (ushort_t*)carve(32768 * 2);
    float* el0      = (float*)carve((size_t)NN * 2 * 4);
    float* er0      = (float*)carve((size_t)NN * 2 * 4);
    float* el1      = (float*)carve((size_t)NN * 2 * 4);
    float* er1      = (float*)carve((size_t)NN * 2 * 4);
    int*   rowptrA  = (int*)  carve((size_t)(2*NN + 1) * 4);
    int*   colsrcA  = (int*)  carve((size_t)2*NE * 4);
    int*   bcur     = (int*)  carve((size_t)NBK * 4);
    int*   gbase    = (int*)  carve((size_t)(NBK + 1) * 4);
    if (off > ws_size) return;
    // ebuf (NBK*CAP*8B = 14.4 MB) aliases featb0+featb1 (51.2 MB): consumed pre-GEMM
    uint2* ebuf = (uint2*)featb0;

    const int PB = (2*NE + CHUNK - 1) / CHUNK;             // 196 partition blocks
    const int GB = (NN + 63) / 64;                         // 1563
    const int WB = (NN + 7) / 8;                           // agg: 8 nodes/block
    const int PWB = (65536 + NBK + 255) / 256;             // prepw + binit

    // prep: W repack + bucket-cursor init (one launch)
    k_prepw2<<<PWB, 256, 0, stream>>>(W1, W2, Wt1, Wt2, bcur);

    // CSR build (scan-free): part -> bucket-total scan -> local hist+scatter
    k_part<<<PB, 256, 0, stream>>>(dst, src, bcur, ebuf);
    k_bktscan<<<1, 512, 0, stream>>>(bcur, gbase, rowptrA);
    k_bscatter<<<NBK, 256, 0, stream>>>(ebuf, bcur, gbase, rowptrA, colsrcA);

    // layer 1: H=2, fp32 A read (cast fused); agg writes bf16 relu(h1)
    k_gemm_mfma<2, true><<<GB, 256, 0, stream>>>(nullptr, x, Wt1,
                                           al1, ar1, al1 + FD, ar1 + FD,
                                           featb0, featb1, el0, er0, el1, er1);
    k_agg2<2><<<WB, 256, 0, stream>>>(rowptrA, colsrcA,
                                      el0, er0, el1, er1, featb0, featb1,
                                      b1, b1 + FD, h1b, nullptr);

    // layer 2: H=1 (W2 rows pre-permuted to absorb h1b's layout)
    k_gemm_mfma<1, false><<<GB, 256, 0, stream>>>(h1b, nullptr, Wt2,
                                           al2, ar2, al2 + FD, ar2 + FD,
                                           featb0, featb1, el0, er0, el1, er1);
    k_agg2<1><<<WB, 256, 0, stream>>>(rowptrA, colsrcA,
                                      el0, er0, el1, er1, featb0, featb1,
                                      b2, b2 + FD, nullptr, out);
}

// Round 15
// 260.805 us; speedup vs baseline: 2.2760x; 1.0885x over previous
//
#include <hip/hip_runtime.h>
#include <hip/hip_bf16.h>
#include <math.h>

#define NN 100000     // nodes
#define NE 800000     // edges per relation
#define FD 128        // feature dim

#define BKW 512       // bucket width in (unified) dst-node space
#define NBK 391       // ceil(2*NN / BKW)
#define CAP 4608      // fixed ebuf capacity per bucket (mean 4096 + 8 sigma)
#define CHUNK 8192    // edges per partition block
#define PB   196      // partition blocks = ceil(2*NE/CHUNK)
#define GB   1563     // gemm blocks = ceil(NN/64)

typedef unsigned short ushort_t;
typedef __attribute__((ext_vector_type(8))) short bf16x8;
typedef __attribute__((ext_vector_type(4))) float f32x4;

union U8 { uint4 u; bf16x8 b; };

// ---------- bf16 pack helpers ----------
__device__ inline unsigned f2bf(float f){              // software RNE (prep kernels)
    unsigned u = __float_as_uint(f);
    return (u + 0x7fffu + ((u >> 16) & 1u)) >> 16;
}
__device__ inline unsigned cvtpk(float lo, float hi){  // HW packed cvt (1 inst, RNE)
    unsigned r;
    asm("v_cvt_pk_bf16_f32 %0, %1, %2" : "=v"(r) : "v"(lo), "v"(hi));
    return r;
}
__device__ inline float blo(unsigned p){ return __uint_as_float(p << 16); }
__device__ inline float bhi(unsigned p){ return __uint_as_float(p & 0xffff0000u); }
__device__ inline float2 up2(unsigned p){ float2 f; f.x = blo(p); f.y = bhi(p); return f; }
// packed dual-FMA: d.x += a.x*b.x; d.y += a.y*b.y  (one VALU inst)
__device__ inline void pkfma(float2& d, float2 a, float2 b){
    asm("v_pk_fma_f32 %0, %1, %2, %0" : "+v"(d) : "v"(a), "v"(b));
}

// ---------- bodies ----------

// partition edges into fixed-capacity buckets (relative cursors, memset-zeroed)
__device__ void part_body(const int* __restrict__ dst, const int* __restrict__ src,
                          int* __restrict__ bcur, uint2* __restrict__ ebuf){
    __shared__ int lcount[NBK];
    __shared__ int lbase[NBK];
    int t = threadIdx.x;
    long base = (long)blockIdx.x * CHUNK;
    for (int j = t; j < NBK; j += 256) lcount[j] = 0;
    __syncthreads();
    #pragma unroll 4
    for (int k = 0; k < CHUNK/256; k++){
        long i = base + k*256 + t;
        if (i < 2*NE){
            int b = (dst[i] + ((i >= NE) ? NN : 0)) >> 9;
            atomicAdd(&lcount[b], 1);
        }
    }
    __syncthreads();
    for (int j = t; j < NBK; j += 256){
        int c = lcount[j];
        lbase[j] = c ? atomicAdd(&bcur[j], c) : 0;
    }
    __syncthreads();
    for (int j = t; j < NBK; j += 256) lcount[j] = 0;
    __syncthreads();
    #pragma unroll 4
    for (int k = 0; k < CHUNK/256; k++){
        long i = base + k*256 + t;
        if (i < 2*NE){
            int dstU = dst[i] + ((i >= NE) ? NN : 0);
            int b = dstU >> 9;
            int r = atomicAdd(&lcount[b], 1);
            int pos = lbase[b] + r;
            if (pos < CAP)   // capacity guard (statistically never trips)
                ebuf[(size_t)b*CAP + pos] = make_uint2((unsigned)src[i], (unsigned)dstU);
        }
    }
}

// W repack: both matrices -> B-fragment-linear bf16.
// m=1 (layer 2): A rows come from h1b's interleaved-stored layout:
// linear A pos q holds logical col (((q&7)>>1) + 4*(q&1))*16 + (q>>3).
__device__ void prepw_body(int idx, const float* __restrict__ W1,
                           const float* __restrict__ W2,
                           ushort_t* __restrict__ Wt1, ushort_t* __restrict__ Wt2){
    int m = idx >> 15;
    int i = idx & 32767;
    const float* W = m ? W2 : W1;
    ushort_t* Wt   = m ? Wt2 : Wt1;
    int j  = i & 7;
    int l  = (i >> 3) & 63;
    int ks = (i >> 9) & 3;
    int f  = i >> 11;
    int k  = ks*32 + (l >> 4)*8 + j;
    if (m) k = (((k & 7) >> 1) + 4*(k & 1))*16 + (k >> 3);
    int col = (f & 7)*16 + (l & 15);
    int rel = f >> 3;
    Wt[i] = (ushort_t)f2bf(W[rel*16384 + k*FD + col]);
}

// per-bucket hist + local scan + atomic global region allocator -> rowbeg/rowend/colsrc
__device__ void bscatter_body(int b, const uint2* __restrict__ ebuf,
                              const int* __restrict__ bcur, int* __restrict__ gcounter,
                              int* __restrict__ rowbeg, int* __restrict__ rowend,
                              int* __restrict__ colsrc){
    __shared__ int lhist[BKW];
    __shared__ int lcur[BKW];
    __shared__ int sm[256];
    __shared__ int gb;
    int n0 = b * BKW;
    int nloc = min(2*NN, n0 + BKW) - n0;
    int ecnt = min(bcur[b], CAP);
    const uint2* eb = ebuf + (size_t)b * CAP;
    int t = threadIdx.x;
    lhist[2*t] = 0; lhist[2*t+1] = 0;
    __syncthreads();
    for (int i = t; i < ecnt; i += 256)
        atomicAdd(&lhist[eb[i].y - n0], 1);
    __syncthreads();
    int a0 = lhist[2*t], a1 = lhist[2*t+1];
    int ps = a0 + a1;
    sm[t] = ps; __syncthreads();
    for (int off = 1; off < 256; off <<= 1){
        int add = (t >= off) ? sm[t-off] : 0;
        __syncthreads();
        sm[t] += add;
        __syncthreads();
    }
    if (t == 255) gb = atomicAdd(gcounter, sm[255]);
    __syncthreads();
    int excl = sm[t] - ps;
    int p0 = gb + excl, p1 = gb + excl + a0;
    if (2*t < nloc){ rowbeg[n0 + 2*t] = p0; rowend[n0 + 2*t] = p0 + a0; }
    if (2*t + 1 < nloc){ rowbeg[n0 + 2*t + 1] = p1; rowend[n0 + 2*t + 1] = p1 + a1; }
    lcur[2*t] = p0; lcur[2*t+1] = p1;
    __syncthreads();
    for (int i = t; i < ecnt; i += 256){
        uint2 e = eb[i];
        int p = atomicAdd(&lcur[e.y - n0], 1);
        colsrc[p] = (int)e.x;
    }
}

// ---------- helpers ----------
__device__ inline float red16(float v){
    v += __shfl_xor(v, 1);
    v += __shfl_xor(v, 2);
    v += __shfl_xor(v, 4);
    v += __shfl_xor(v, 8);
    return v;
}

// ---------- MFMA dual-relation GEMM + fused el/er (body, takes block id) ----------
// AF32: read fp32 A directly, convert fragments in-register.
// featb stored head-interleaved: stored[c*8 + 2t]   = logical col  t   *16+c
//                                stored[c*8 + 2t+1] = logical col (t+4)*16+c
template<int H, bool AF32>
__device__ void gemm_body(int bid,
        const ushort_t* __restrict__ Ab, const float* __restrict__ Af,
        const ushort_t* __restrict__ Wt,
        const float* __restrict__ al0, const float* __restrict__ ar0,
        const float* __restrict__ al1, const float* __restrict__ ar1,
        ushort_t* __restrict__ featb0, ushort_t* __restrict__ featb1,
        float* __restrict__ el0, float* __restrict__ er0,
        float* __restrict__ el1, float* __restrict__ er1){
    int t = threadIdx.x;
    int w = t >> 6, l = t & 63;
    int c = l & 15, kgrp = l >> 4;
    const bf16x8* WtV = (const bf16x8*)Wt;
    long arow = (long)bid*64 + w*16 + c;
    bf16x8 zero8 = {0,0,0,0,0,0,0,0};
    bf16x8 af[4];
    bool rok = arow < NN;
    if (AF32){
        const float4* xv = (const float4*)Af;
        #pragma unroll
        for (int ks = 0; ks < 4; ks++){
            if (rok){
                float4 u = xv[arow*32 + (ks*4 + kgrp)*2];
                float4 v = xv[arow*32 + (ks*4 + kgrp)*2 + 1];
                U8 q;
                q.u = make_uint4(cvtpk(u.x,u.y), cvtpk(u.z,u.w),
                                 cvtpk(v.x,v.y), cvtpk(v.z,v.w));
                af[ks] = q.b;
            } else af[ks] = zero8;
        }
    } else {
        const bf16x8* AbV = (const bf16x8*)Ab;
        #pragma unroll
        for (int ks = 0; ks < 4; ks++)
            af[ks] = rok ? AbV[arow*16 + ks*4 + kgrp] : zero8;
    }
    f32x4 acc[16];
    #pragma unroll
    for (int f = 0; f < 16; f++) acc[f] = (f32x4){0.f,0.f,0.f,0.f};
    #pragma unroll
    for (int f = 0; f < 16; f++){
        #pragma unroll
        for (int ks = 0; ks < 4; ks++){
            acc[f] = __builtin_amdgcn_mfma_f32_16x16x32_bf16(
                         af[ks], WtV[(f*4 + ks)*64 + l], acc[f], 0, 0, 0);
        }
    }
    float alv0[8], arv0[8], alv1[8], arv1[8];
    #pragma unroll
    for (int f = 0; f < 8; f++){
        alv0[f] = al0[f*16 + c]; arv0[f] = ar0[f*16 + c];
        alv1[f] = al1[f*16 + c]; arv1[f] = ar1[f*16 + c];
    }
    #pragma unroll
    for (int reg = 0; reg < 4; reg++){
        long orow = (long)bid*64 + w*16 + kgrp*4 + reg;
        bool ok = orow < NN;
        if (ok){
            uint4 p0, p1;
            p0.x = cvtpk(acc[0][reg],  acc[4][reg]);
            p0.y = cvtpk(acc[1][reg],  acc[5][reg]);
            p0.z = cvtpk(acc[2][reg],  acc[6][reg]);
            p0.w = cvtpk(acc[3][reg],  acc[7][reg]);
            p1.x = cvtpk(acc[8][reg],  acc[12][reg]);
            p1.y = cvtpk(acc[9][reg],  acc[13][reg]);
            p1.z = cvtpk(acc[10][reg], acc[14][reg]);
            p1.w = cvtpk(acc[11][reg], acc[15][reg]);
            *(uint4*)&featb0[orow*FD + c*8] = p0;
            *(uint4*)&featb1[orow*FD + c*8] = p1;
        }
        if (H == 2){
            float pl00=0, pr00=0, pl01=0, pr01=0;
            float pl10=0, pr10=0, pl11=0, pr11=0;
            #pragma unroll
            for (int f = 0; f < 4; f++){
                pl00 = fmaf(acc[f][reg],    alv0[f],   pl00);
                pr00 = fmaf(acc[f][reg],    arv0[f],   pr00);
                pl01 = fmaf(acc[4+f][reg],  alv0[4+f], pl01);
                pr01 = fmaf(acc[4+f][reg],  arv0[4+f], pr01);
                pl10 = fmaf(acc[8+f][reg],  alv1[f],   pl10);
                pr10 = fmaf(acc[8+f][reg],  arv1[f],   pr10);
                pl11 = fmaf(acc[12+f][reg], alv1[4+f], pl11);
                pr11 = fmaf(acc[12+f][reg], arv1[4+f], pr11);
            }
            pl00 = red16(pl00); pr00 = red16(pr00);
            pl01 = red16(pl01); pr01 = red16(pr01);
            pl10 = red16(pl10); pr10 = red16(pr10);
            pl11 = red16(pl11); pr11 = red16(pr11);
            if (c == 0 && ok){
                el0[orow*2] = pl00; el0[orow*2+1] = pl01;
                er0[orow*2] = pr00; er0[orow*2+1] = pr01;
                el1[orow*2] = pl10; el1[orow*2+1] = pl11;
                er1[orow*2] = pr10; er1[orow*2+1] = pr11;
            }
        } else {
            float pl0=0, pr0=0, pl1=0, pr1=0;
            #pragma unroll
            for (int f = 0; f < 8; f++){
                pl0 = fmaf(acc[f][reg],   alv0[f], pl0);
                pr0 = fmaf(acc[f][reg],   arv0[f], pr0);
                pl1 = fmaf(acc[8+f][reg], alv1[f], pl1);
                pr1 = fmaf(acc[8+f][reg], arv1[f], pr1);
            }
            pl0 = red16(pl0); pr0 = red16(pr0);
            pl1 = red16(pl1); pr1 = red16(pr1);
            if (c == 0 && ok){
                el0[orow] = pl0; er0[orow] = pr0;
                el1[orow] = pl1; er1[orow] = pr1;
            }
        }
    }
}

// ---------- fused launch A: edge partition (blocks 0..PB) || W repack ----------
__global__ __launch_bounds__(256) void kA(const int* __restrict__ dst,
                                          const int* __restrict__ src,
                                          int* __restrict__ bcur,
                                          uint2* __restrict__ ebuf,
                                          const float* __restrict__ W1,
                                          const float* __restrict__ W2,
                                          ushort_t* __restrict__ Wt1,
                                          ushort_t* __restrict__ Wt2){
    if (blockIdx.x < PB){
        part_body(dst, src, bcur, ebuf);
        return;
    }
    int idx = (blockIdx.x - PB) * 256 + threadIdx.x;   // 0..65535
    prepw_body(idx, W1, W2, Wt1, Wt2);
}

// ---------- fused launch B: bucket scatter (blocks 0..NBK) || layer-1 GEMM ----------
__global__ __launch_bounds__(256) void kB(
        const uint2* __restrict__ ebuf, const int* __restrict__ bcur,
        int* __restrict__ gcounter, int* __restrict__ rowbeg,
        int* __restrict__ rowend, int* __restrict__ colsrc,
        const float* __restrict__ Af, const ushort_t* __restrict__ Wt,
        const float* __restrict__ al0, const float* __restrict__ ar0,
        const float* __restrict__ al1, const float* __restrict__ ar1,
        ushort_t* __restrict__ featb0, ushort_t* __restrict__ featb1,
        float* __restrict__ el0, float* __restrict__ er0,
        float* __restrict__ el1, float* __restrict__ er1){
    if (blockIdx.x < NBK){
        bscatter_body(blockIdx.x, ebuf, bcur, gcounter, rowbeg, rowend, colsrc);
        return;
    }
    gemm_body<2, true>(blockIdx.x - NBK, nullptr, Af, Wt, al0, ar0, al1, ar1,
                       featb0, featb1, el0, er0, el1, er1);
}

// ---------- standalone layer-2 GEMM ----------
__global__ __launch_bounds__(256) void k_gemm2(
        const ushort_t* __restrict__ Ab, const ushort_t* __restrict__ Wt,
        const float* __restrict__ al0, const float* __restrict__ ar0,
        const float* __restrict__ al1, const float* __restrict__ ar1,
        ushort_t* __restrict__ featb0, ushort_t* __restrict__ featb1,
        float* __restrict__ el0, float* __restrict__ er0,
        float* __restrict__ el1, float* __restrict__ er1){
    gemm_body<1, false>(blockIdx.x, Ab, nullptr, Wt, al0, ar0, al1, ar1,
                        featb0, featb1, el0, er0, el1, er1);
}

// ---------- fused aggregation: 2 nodes/wave, LDS-staged edge records ----------
template<int H>
__global__ __launch_bounds__(256) void k_agg2(
                       const int* __restrict__ rowbeg,   // 2*NN, rel1 at +NN
                       const int* __restrict__ rowend,
                       const int* __restrict__ colsrc,   // 2*NE unified
                       const float* __restrict__ el0, const float* __restrict__ er0,
                       const float* __restrict__ el1, const float* __restrict__ er1,
                       const ushort_t* __restrict__ featb0, const ushort_t* __restrict__ featb1,
                       const float* __restrict__ bias0, const float* __restrict__ bias1,
                       ushort_t* __restrict__ outb, float* __restrict__ outf){
    __shared__ float4 stg[4][2][2][32];   // [wave][half][rel][slot] = 8 KB
    int wid  = threadIdx.x >> 6;
    int lane = threadIdx.x & 63;
    int half = lane >> 5;
    int hl   = lane & 31;
    int sub  = lane & 15;
    int g    = (lane >> 4) & 1;
    int node = ((blockIdx.x * blockDim.x + threadIdx.x) >> 6) * 2 + half;
    if (node >= NN) return;
    int base0 = rowbeg[node],       end0 = rowend[node];
    int base1 = rowbeg[NN + node],  end1 = rowend[NN + node];
    bool has0 = end0 > base0, has1 = end1 > base1;
    float er00 = er0[node*H];
    float er01 = (H == 2) ? er0[node*H + 1] : 0.f;
    float er10 = er1[node*H];
    float er11 = (H == 2) ? er1[node*H + 1] : 0.f;
    float2 ap0[4], ap1[4];
    #pragma unroll
    for (int i = 0; i < 4; i++){ ap0[i] = make_float2(0.f,0.f); ap1[i] = make_float2(0.f,0.f); }
    float s00=0.f, s01=0.f, s10=0.f, s11=0.f;
    while (base0 < end0 || base1 < end1){
        int nrem0 = end0 - base0, nrem1 = end1 - base1;
        bool act0 = hl < nrem0, act1 = hl < nrem1;
        int sv0 = act0 ? colsrc[base0 + hl] : 0;
        int sv1 = act1 ? colsrc[base1 + hl] : 0;
        float a00=0.f, a01=0.f, a10=0.f, a11=0.f;
        if (act0){
            if (H == 2){
                float2 e2 = *(const float2*)&el0[sv0*2];
                float e0 = e2.x + er00, e1 = e2.y + er01;
                e0 = (e0 > 0.f) ? e0 : 0.2f*e0;
                e1 = (e1 > 0.f) ? e1 : 0.2f*e1;
                a00 = __expf(e0); a01 = __expf(e1);
            } else {
                float e0 = el0[sv0] + er00;
                e0 = (e0 > 0.f) ? e0 : 0.2f*e0;
                a00 = __expf(e0);
            }
        }
        if (act1){
            if (H == 2){
                float2 e2 = *(const float2*)&el1[sv1*2];
                float e0 = e2.x + er10, e1 = e2.y + er11;
                e0 = (e0 > 0.f) ? e0 : 0.2f*e0;
                e1 = (e1 > 0.f) ? e1 : 0.2f*e1;
                a10 = __expf(e0); a11 = __expf(e1);
            } else {
                float e0 = el1[sv1] + er10;
                e0 = (e0 > 0.f) ? e0 : 0.2f*e0;
                a10 = __expf(e0);
            }
        }
        s00 += a00; s01 += a01; s10 += a10; s11 += a11;
        stg[wid][half][0][hl] = make_float4(__int_as_float(sv0), a00,
                                            (H == 2) ? a01 : a00, 0.f);
        stg[wid][half][1][hl] = make_float4(__int_as_float(sv1), a10,
                                            (H == 2) ? a11 : a10, 0.f);
        __builtin_amdgcn_sched_barrier(0);   // keep reads after the stage
        int nn0 = (nrem0 > 0) ? min(32, nrem0) : 0;
        int nn1 = (nrem1 > 0) ? min(32, nrem1) : 0;
        int nnm = (nn0 > nn1) ? nn0 : nn1;
        for (int j4 = 0; j4 < nnm; j4 += 4){
            int sA = j4 + g, sB = sA + 2;
            float4 e0A = stg[wid][half][0][sA];
            float4 e0B = stg[wid][half][0][sB];
            float4 e1A = stg[wid][half][1][sA];
            float4 e1B = stg[wid][half][1][sB];
            uint4 p0A = *(const uint4*)&featb0[__float_as_uint(e0A.x)*FD + sub*8];
            uint4 p0B = *(const uint4*)&featb0[__float_as_uint(e0B.x)*FD + sub*8];
            uint4 p1A = *(const uint4*)&featb1[__float_as_uint(e1A.x)*FD + sub*8];
            uint4 p1B = *(const uint4*)&featb1[__float_as_uint(e1B.x)*FD + sub*8];
            float2 w0A = make_float2(e0A.y, e0A.z);
            float2 w0B = make_float2(e0B.y, e0B.z);
            float2 w1A = make_float2(e1A.y, e1A.z);
            float2 w1B = make_float2(e1B.y, e1B.z);
            pkfma(ap0[0], w0A, up2(p0A.x));
            pkfma(ap0[1], w0A, up2(p0A.y));
            pkfma(ap0[2], w0A, up2(p0A.z));
            pkfma(ap0[3], w0A, up2(p0A.w));
            pkfma(ap0[0], w0B, up2(p0B.x));
            pkfma(ap0[1], w0B, up2(p0B.y));
            pkfma(ap0[2], w0B, up2(p0B.z));
            pkfma(ap0[3], w0B, up2(p0B.w));
            pkfma(ap1[0], w1A, up2(p1A.x));
            pkfma(ap1[1], w1A, up2(p1A.y));
            pkfma(ap1[2], w1A, up2(p1A.z));
            pkfma(ap1[3], w1A, up2(p1A.w));
            pkfma(ap1[0], w1B, up2(p1B.x));
            pkfma(ap1[1], w1B, up2(p1B.y));
            pkfma(ap1[2], w1B, up2(p1B.z));
            pkfma(ap1[3], w1B, up2(p1B.w));
        }
        base0 += 32; base1 += 32;
    }
    // s-reduce within the 32-lane half (5 levels)
    #pragma unroll
    for (int off = 16; off > 0; off >>= 1){
        s00 += __shfl_xor(s00, off);
        s10 += __shfl_xor(s10, off);
        if (H == 2){ s01 += __shfl_xor(s01, off); s11 += __shfl_xor(s11, off); }
    }
    // group-reduce across the 2 groups of this half (1 level)
    #pragma unroll
    for (int i = 0; i < 4; i++){
        ap0[i].x += __shfl_xor(ap0[i].x, 16); ap0[i].y += __shfl_xor(ap0[i].y, 16);
        ap1[i].x += __shfl_xor(ap1[i].x, 16); ap1[i].y += __shfl_xor(ap1[i].y, 16);
    }
    if (hl < 16){
        float i00 = has0 ? 1.f/s00 : 0.f;
        float i01 = (H == 2) ? (has0 ? 1.f/s01 : 0.f) : i00;
        float i10 = has1 ? 1.f/s10 : 0.f;
        float i11 = (H == 2) ? (has1 ? 1.f/s11 : 0.f) : i10;
        float2 vp[4];
        #pragma unroll
        for (int t = 0; t < 4; t++){
            float bx = bias0[t*16 + sub]       + bias1[t*16 + sub];
            float by = bias0[(t+4)*16 + sub]   + bias1[(t+4)*16 + sub];
            vp[t].x = 0.5f*(ap0[t].x*i00 + ap1[t].x*i10 + bx);
            vp[t].y = 0.5f*(ap0[t].y*i01 + ap1[t].y*i11 + by);
        }
        if (H == 2){
            #pragma unroll
            for (int t = 0; t < 4; t++){
                vp[t].x = fmaxf(vp[t].x, 0.f);
                vp[t].y = fmaxf(vp[t].y, 0.f);
            }
            uint4 o;
            o.x = cvtpk(vp[0].x, vp[0].y); o.y = cvtpk(vp[1].x, vp[1].y);
            o.z = cvtpk(vp[2].x, vp[2].y); o.w = cvtpk(vp[3].x, vp[3].y);
            *(uint4*)&outb[(size_t)node*FD + sub*8] = o;
        } else {
            #pragma unroll
            for (int t = 0; t < 4; t++){
                outf[(size_t)node*FD + t*16 + sub]     = vp[t].x;
                outf[(size_t)node*FD + (t+4)*16 + sub] = vp[t].y;
            }
        }
    }
}

// ---------- launch ----------
extern "C" void kernel_launch(void* const* d_in, const int* in_sizes, int n_in,
                              void* d_out, int out_size, void* d_ws, size_t ws_size,
                              hipStream_t stream){
    const float* x   = (const float*)d_in[0];
    const float* W1  = (const float*)d_in[1];
    const float* al1 = (const float*)d_in[2];
    const float* ar1 = (const float*)d_in[3];
    const float* b1  = (const float*)d_in[4];
    const float* W2  = (const float*)d_in[5];
    const float* al2 = (const float*)d_in[6];
    const float* ar2 = (const float*)d_in[7];
    const float* b2  = (const float*)d_in[8];
    const int*   src = (const int*)d_in[9];
    const int*   dst = (const int*)d_in[10];
    float* out = (float*)d_out;

    size_t off = 0;
    auto carve = [&](size_t bytes) -> char* {
        char* p = (char*)d_ws + off;
        off += (bytes + 255) & ~(size_t)255;
        return p;
    };
    ushort_t* h1b    = (ushort_t*)carve((size_t)NN * FD * 2);
    ushort_t* featb0 = (ushort_t*)carve((size_t)NN * FD * 2);
    ushort_t* featb1 = (ushort_t*)carve((size_t)NN * FD * 2);
    uint2*    ebuf   = (uint2*)   carve((size_t)NBK * CAP * 8);   // own carve: kB races otherwise
    ushort_t* Wt1    = (ushort_t*)carve(32768 * 2);
    ushort_t* Wt2    = (ushort_t*)carve(32768 * 2);
    float* el0      = (float*)carve((size_t)NN * 2 * 4);
    float* er0      = (float*)carve((size_t)NN * 2 * 4);
    float* el1      = (float*)carve((size_t)NN * 2 * 4);
    float* er1      = (float*)carve((size_t)NN * 2 * 4);
    int*   rowbeg   = (int*)  carve((size_t)2*NN * 4);
    int*   rowend   = (int*)  carve((size_t)2*NN * 4);
    int*   colsrcA  = (int*)  carve((size_t)2*NE * 4);
    int*   bcur     = (int*)  carve((size_t)(NBK + 1) * 4);   // +1: gcounter tail
    if (off > ws_size) return;
    int* gcounter = bcur + NBK;

    const int WB = (NN + 7) / 8;                           // agg: 8 nodes/block

    // zero relative bucket cursors + global edge allocator (one memset)
    hipMemsetAsync(bcur, 0, (size_t)(NBK + 1) * 4, stream);

    // A: edge partition || W repack
    kA<<<PB + 256, 256, 0, stream>>>(dst, src, bcur, ebuf, W1, W2, Wt1, Wt2);

    // B: per-bucket scatter (first NBK blocks) || layer-1 GEMM
    kB<<<NBK + GB, 256, 0, stream>>>(ebuf, bcur, gcounter, rowbeg, rowend, colsrcA,
                                     x, Wt1, al1, ar1, al1 + FD, ar1 + FD,
                                     featb0, featb1, el0, er0, el1, er1);

    // layer-1 aggregation (writes bf16 relu(h1))
    k_agg2<2><<<WB, 256, 0, stream>>>(rowbeg, rowend, colsrcA,
                                      el0, er0, el1, er1, featb0, featb1,
                                      b1, b1 + FD, h1b, nullptr);

    // layer 2: GEMM (W2 rows pre-permuted to absorb h1b's layout) + aggregation
    k_gemm2<<<GB, 256, 0, stream>>>(h1b, Wt2, al2, ar2, al2 + FD, ar2 + FD,
                                    featb0, featb1, el0, er0, el1, er1);
    k_agg2<1><<<WB, 256, 0, stream>>>(rowbeg, rowend, colsrcA,
                                      el0, er0, el1, er1, featb0, featb1,
                                      b2, b2 + FD, nullptr, out);
}

// Round 17
// 257.213 us; speedup vs baseline: 2.3078x; 1.0140x over previous
//
#include <hip/hip_runtime.h>
#include <hip/hip_bf16.h>
#include <math.h>

#define NN 100000     // nodes
#define NE 800000     // edges per relation
#define FD 128        // feature dim

#define BKW 512       // bucket width in (unified) dst-node space
#define NBK 391       // ceil(2*NN / BKW)
#define CAP 4608      // fixed ebuf capacity per bucket (mean 4096 + 8 sigma)
#define CHUNK 2048    // edges per partition block (small -> ~3 blocks/CU occupancy)
#define PB   782      // partition blocks = ceil(2*NE/CHUNK)
#define GB   1563     // gemm blocks = ceil(NN/64)

typedef unsigned short ushort_t;
typedef __attribute__((ext_vector_type(8))) short bf16x8;
typedef __attribute__((ext_vector_type(4))) float f32x4;

union U8 { uint4 u; bf16x8 b; };

// ---------- bf16 pack helpers ----------
__device__ inline unsigned f2bf(float f){              // software RNE (prep kernels)
    unsigned u = __float_as_uint(f);
    return (u + 0x7fffu + ((u >> 16) & 1u)) >> 16;
}
__device__ inline unsigned cvtpk(float lo, float hi){  // HW packed cvt (1 inst, RNE)
    unsigned r;
    asm("v_cvt_pk_bf16_f32 %0, %1, %2" : "=v"(r) : "v"(lo), "v"(hi));
    return r;
}
__device__ inline float blo(unsigned p){ return __uint_as_float(p << 16); }
__device__ inline float bhi(unsigned p){ return __uint_as_float(p & 0xffff0000u); }
__device__ inline float2 up2(unsigned p){ float2 f; f.x = blo(p); f.y = bhi(p); return f; }
// packed dual-FMA: d.x += a.x*b.x; d.y += a.y*b.y  (one VALU inst)
__device__ inline void pkfma(float2& d, float2 a, float2 b){
    asm("v_pk_fma_f32 %0, %1, %2, %0" : "+v"(d) : "v"(a), "v"(b));
}

// ---------- bodies ----------

// partition edges into fixed-capacity buckets (relative cursors, memset-zeroed)
__device__ void part_body(const int* __restrict__ dst, const int* __restrict__ src,
                          int* __restrict__ bcur, uint2* __restrict__ ebuf){
    __shared__ int lcount[NBK];
    __shared__ int lbase[NBK];
    int t = threadIdx.x;
    long base = (long)blockIdx.x * CHUNK;
    for (int j = t; j < NBK; j += 256) lcount[j] = 0;
    __syncthreads();
    #pragma unroll 4
    for (int k = 0; k < CHUNK/256; k++){
        long i = base + k*256 + t;
        if (i < 2*NE){
            int b = (dst[i] + ((i >= NE) ? NN : 0)) >> 9;
            atomicAdd(&lcount[b], 1);
        }
    }
    __syncthreads();
    for (int j = t; j < NBK; j += 256){
        int c = lcount[j];
        lbase[j] = c ? atomicAdd(&bcur[j], c) : 0;
    }
    __syncthreads();
    for (int j = t; j < NBK; j += 256) lcount[j] = 0;
    __syncthreads();
    #pragma unroll 4
    for (int k = 0; k < CHUNK/256; k++){
        long i = base + k*256 + t;
        if (i < 2*NE){
            int dstU = dst[i] + ((i >= NE) ? NN : 0);
            int b = dstU >> 9;
            int r = atomicAdd(&lcount[b], 1);
            int pos = lbase[b] + r;
            if (pos < CAP)   // capacity guard (statistically never trips)
                ebuf[(size_t)b*CAP + pos] = make_uint2((unsigned)src[i], (unsigned)dstU);
        }
    }
}

// W repack: both matrices -> B-fragment-linear bf16.
// m=1 (layer 2): A rows come from h1b's interleaved-stored layout:
// linear A pos q holds logical col (((q&7)>>1) + 4*(q&1))*16 + (q>>3).
__device__ void prepw_body(int idx, const float* __restrict__ W1,
                           const float* __restrict__ W2,
                           ushort_t* __restrict__ Wt1, ushort_t* __restrict__ Wt2){
    int m = idx >> 15;
    int i = idx & 32767;
    const float* W = m ? W2 : W1;
    ushort_t* Wt   = m ? Wt2 : Wt1;
    int j  = i & 7;
    int l  = (i >> 3) & 63;
    int ks = (i >> 9) & 3;
    int f  = i >> 11;
    int k  = ks*32 + (l >> 4)*8 + j;
    if (m) k = (((k & 7) >> 1) + 4*(k & 1))*16 + (k >> 3);
    int col = (f & 7)*16 + (l & 15);
    int rel = f >> 3;
    Wt[i] = (ushort_t)f2bf(W[rel*16384 + k*FD + col]);
}

// per-bucket hist + local scan + atomic global region allocator -> rowbeg/rowend/colsrc
__device__ void bscatter_body(int b, const uint2* __restrict__ ebuf,
                              const int* __restrict__ bcur, int* __restrict__ gcounter,
                              int* __restrict__ rowbeg, int* __restrict__ rowend,
                              int* __restrict__ colsrc){
    __shared__ int lhist[BKW];
    __shared__ int lcur[BKW];
    __shared__ int sm[256];
    __shared__ int gb;
    int n0 = b * BKW;
    int nloc = min(2*NN, n0 + BKW) - n0;
    int ecnt = min(bcur[b], CAP);
    const uint2* eb = ebuf + (size_t)b * CAP;
    int t = threadIdx.x;
    lhist[2*t] = 0; lhist[2*t+1] = 0;
    __syncthreads();
    for (int i = t; i < ecnt; i += 256)
        atomicAdd(&lhist[eb[i].y - n0], 1);
    __syncthreads();
    int a0 = lhist[2*t], a1 = lhist[2*t+1];
    int ps = a0 + a1;
    sm[t] = ps; __syncthreads();
    for (int off = 1; off < 256; off <<= 1){
        int add = (t >= off) ? sm[t-off] : 0;
        __syncthreads();
        sm[t] += add;
        __syncthreads();
    }
    if (t == 255) gb = atomicAdd(gcounter, sm[255]);
    __syncthreads();
    int excl = sm[t] - ps;
    int p0 = gb + excl, p1 = gb + excl + a0;
    if (2*t < nloc){ rowbeg[n0 + 2*t] = p0; rowend[n0 + 2*t] = p0 + a0; }
    if (2*t + 1 < nloc){ rowbeg[n0 + 2*t + 1] = p1; rowend[n0 + 2*t + 1] = p1 + a1; }
    lcur[2*t] = p0; lcur[2*t+1] = p1;
    __syncthreads();
    for (int i = t; i < ecnt; i += 256){
        uint2 e = eb[i];   // second pass is L2-warm (same XCD just wrote/read it)
        int p = atomicAdd(&lcur[e.y - n0], 1);
        colsrc[p] = (int)e.x;
    }
}

// ---------- helpers ----------
__device__ inline float red16(float v){
    v += __shfl_xor(v, 1);
    v += __shfl_xor(v, 2);
    v += __shfl_xor(v, 4);
    v += __shfl_xor(v, 8);
    return v;
}

// ---------- MFMA dual-relation GEMM + fused el/er (body, takes block id) ----------
// AF32: read fp32 A directly, convert fragments in-register.
// featb stored head-interleaved: stored[c*8 + 2t]   = logical col  t   *16+c
//                                stored[c*8 + 2t+1] = logical col (t+4)*16+c
template<int H, bool AF32>
__device__ void gemm_body(int bid,
        const ushort_t* __restrict__ Ab, const float* __restrict__ Af,
        const ushort_t* __restrict__ Wt,
        const float* __restrict__ al0, const float* __restrict__ ar0,
        const float* __restrict__ al1, const float* __restrict__ ar1,
        ushort_t* __restrict__ featb0, ushort_t* __restrict__ featb1,
        float* __restrict__ el0, float* __restrict__ er0,
        float* __restrict__ el1, float* __restrict__ er1){
    int t = threadIdx.x;
    int w = t >> 6, l = t & 63;
    int c = l & 15, kgrp = l >> 4;
    const bf16x8* WtV = (const bf16x8*)Wt;
    long arow = (long)bid*64 + w*16 + c;
    bf16x8 zero8 = {0,0,0,0,0,0,0,0};
    bf16x8 af[4];
    bool rok = arow < NN;
    if (AF32){
        const float4* xv = (const float4*)Af;
        #pragma unroll
        for (int ks = 0; ks < 4; ks++){
            if (rok){
                float4 u = xv[arow*32 + (ks*4 + kgrp)*2];
                float4 v = xv[arow*32 + (ks*4 + kgrp)*2 + 1];
                U8 q;
                q.u = make_uint4(cvtpk(u.x,u.y), cvtpk(u.z,u.w),
                                 cvtpk(v.x,v.y), cvtpk(v.z,v.w));
                af[ks] = q.b;
            } else af[ks] = zero8;
        }
    } else {
        const bf16x8* AbV = (const bf16x8*)Ab;
        #pragma unroll
        for (int ks = 0; ks < 4; ks++)
            af[ks] = rok ? AbV[arow*16 + ks*4 + kgrp] : zero8;
    }
    f32x4 acc[16];
    #pragma unroll
    for (int f = 0; f < 16; f++) acc[f] = (f32x4){0.f,0.f,0.f,0.f};
    #pragma unroll
    for (int f = 0; f < 16; f++){
        #pragma unroll
        for (int ks = 0; ks < 4; ks++){
            acc[f] = __builtin_amdgcn_mfma_f32_16x16x32_bf16(
                         af[ks], WtV[(f*4 + ks)*64 + l], acc[f], 0, 0, 0);
        }
    }
    float alv0[8], arv0[8], alv1[8], arv1[8];
    #pragma unroll
    for (int f = 0; f < 8; f++){
        alv0[f] = al0[f*16 + c]; arv0[f] = ar0[f*16 + c];
        alv1[f] = al1[f*16 + c]; arv1[f] = ar1[f*16 + c];
    }
    #pragma unroll
    for (int reg = 0; reg < 4; reg++){
        long orow = (long)bid*64 + w*16 + kgrp*4 + reg;
        bool ok = orow < NN;
        if (ok){
            uint4 p0, p1;
            p0.x = cvtpk(acc[0][reg],  acc[4][reg]);
            p0.y = cvtpk(acc[1][reg],  acc[5][reg]);
            p0.z = cvtpk(acc[2][reg],  acc[6][reg]);
            p0.w = cvtpk(acc[3][reg],  acc[7][reg]);
            p1.x = cvtpk(acc[8][reg],  acc[12][reg]);
            p1.y = cvtpk(acc[9][reg],  acc[13][reg]);
            p1.z = cvtpk(acc[10][reg], acc[14][reg]);
            p1.w = cvtpk(acc[11][reg], acc[15][reg]);
            *(uint4*)&featb0[orow*FD + c*8] = p0;
            *(uint4*)&featb1[orow*FD + c*8] = p1;
        }
        if (H == 2){
            float pl00=0, pr00=0, pl01=0, pr01=0;
            float pl10=0, pr10=0, pl11=0, pr11=0;
            #pragma unroll
            for (int f = 0; f < 4; f++){
                pl00 = fmaf(acc[f][reg],    alv0[f],   pl00);
                pr00 = fmaf(acc[f][reg],    arv0[f],   pr00);
                pl01 = fmaf(acc[4+f][reg],  alv0[4+f], pl01);
                pr01 = fmaf(acc[4+f][reg],  arv0[4+f], pr01);
                pl10 = fmaf(acc[8+f][reg],  alv1[f],   pl10);
                pr10 = fmaf(acc[8+f][reg],  arv1[f],   pr10);
                pl11 = fmaf(acc[12+f][reg], alv1[4+f], pl11);
                pr11 = fmaf(acc[12+f][reg], arv1[4+f], pr11);
            }
            pl00 = red16(pl00); pr00 = red16(pr00);
            pl01 = red16(pl01); pr01 = red16(pr01);
            pl10 = red16(pl10); pr10 = red16(pr10);
            pl11 = red16(pl11); pr11 = red16(pr11);
            if (c == 0 && ok){
                el0[orow*2] = pl00; el0[orow*2+1] = pl01;
                er0[orow*2] = pr00; er0[orow*2+1] = pr01;
                el1[orow*2] = pl10; el1[orow*2+1] = pl11;
                er1[orow*2] = pr10; er1[orow*2+1] = pr11;
            }
        } else {
            float pl0=0, pr0=0, pl1=0, pr1=0;
            #pragma unroll
            for (int f = 0; f < 8; f++){
                pl0 = fmaf(acc[f][reg],   alv0[f], pl0);
                pr0 = fmaf(acc[f][reg],   arv0[f], pr0);
                pl1 = fmaf(acc[8+f][reg], alv1[f], pl1);
                pr1 = fmaf(acc[8+f][reg], arv1[f], pr1);
            }
            pl0 = red16(pl0); pr0 = red16(pr0);
            pl1 = red16(pl1); pr1 = red16(pr1);
            if (c == 0 && ok){
                el0[orow] = pl0; er0[orow] = pr0;
                el1[orow] = pl1; er1[orow] = pr1;
            }
        }
    }
}

// ---------- fused launch A: edge partition (blocks 0..PB) || W repack ----------
__global__ __launch_bounds__(256) void kA(const int* __restrict__ dst,
                                          const int* __restrict__ src,
                                          int* __restrict__ bcur,
                                          uint2* __restrict__ ebuf,
                                          const float* __restrict__ W1,
                                          const float* __restrict__ W2,
                                          ushort_t* __restrict__ Wt1,
                                          ushort_t* __restrict__ Wt2){
    if (blockIdx.x < PB){
        part_body(dst, src, bcur, ebuf);
        return;
    }
    int idx = (blockIdx.x - PB) * 256 + threadIdx.x;   // 0..65535
    prepw_body(idx, W1, W2, Wt1, Wt2);
}

// ---------- fused launch B: bucket scatter (blocks 0..NBK) || layer-1 GEMM ----------
__global__ __launch_bounds__(256) void kB(
        const uint2* __restrict__ ebuf, const int* __restrict__ bcur,
        int* __restrict__ gcounter, int* __restrict__ rowbeg,
        int* __restrict__ rowend, int* __restrict__ colsrc,
        const float* __restrict__ Af, const ushort_t* __restrict__ Wt,
        const float* __restrict__ al0, const float* __restrict__ ar0,
        const float* __restrict__ al1, const float* __restrict__ ar1,
        ushort_t* __restrict__ featb0, ushort_t* __restrict__ featb1,
        float* __restrict__ el0, float* __restrict__ er0,
        float* __restrict__ el1, float* __restrict__ er1){
    if (blockIdx.x < NBK){
        bscatter_body(blockIdx.x, ebuf, bcur, gcounter, rowbeg, rowend, colsrc);
        return;
    }
    gemm_body<2, true>(blockIdx.x - NBK, nullptr, Af, Wt, al0, ar0, al1, ar1,
                       featb0, featb1, el0, er0, el1, er1);
}

// ---------- standalone layer-2 GEMM ----------
__global__ __launch_bounds__(256) void k_gemm2(
        const ushort_t* __restrict__ Ab, const ushort_t* __restrict__ Wt,
        const float* __restrict__ al0, const float* __restrict__ ar0,
        const float* __restrict__ al1, const float* __restrict__ ar1,
        ushort_t* __restrict__ featb0, ushort_t* __restrict__ featb1,
        float* __restrict__ el0, float* __restrict__ er0,
        float* __restrict__ el1, float* __restrict__ er1){
    gemm_body<1, false>(blockIdx.x, Ab, nullptr, Wt, al0, ar0, al1, ar1,
                        featb0, featb1, el0, er0, el1, er1);
}

// ---------- fused aggregation: 2 nodes/wave, LDS-staged edge records ----------
template<int H>
__global__ __launch_bounds__(256) void k_agg2(
                       const int* __restrict__ rowbeg,   // 2*NN, rel1 at +NN
                       const int* __restrict__ rowend,
                       const int* __restrict__ colsrc,   // 2*NE unified
                       const float* __restrict__ el0, const float* __restrict__ er0,
                       const float* __restrict__ el1, const float* __restrict__ er1,
                       const ushort_t* __restrict__ featb0, const ushort_t* __restrict__ featb1,
                       const float* __restrict__ bias0, const float* __restrict__ bias1,
                       ushort_t* __restrict__ outb, float* __restrict__ outf){
    __shared__ float4 stg[4][2][2][32];   // [wave][half][rel][slot] = 8 KB
    int wid  = threadIdx.x >> 6;
    int lane = threadIdx.x & 63;
    int half = lane >> 5;
    int hl   = lane & 31;
    int sub  = lane & 15;
    int g    = (lane >> 4) & 1;
    int node = ((blockIdx.x * blockDim.x + threadIdx.x) >> 6) * 2 + half;
    if (node >= NN) return;
    int base0 = rowbeg[node],       end0 = rowend[node];
    int base1 = rowbeg[NN + node],  end1 = rowend[NN + node];
    bool has0 = end0 > base0, has1 = end1 > base1;
    float er00 = er0[node*H];
    float er01 = (H == 2) ? er0[node*H + 1] : 0.f;
    float er10 = er1[node*H];
    float er11 = (H == 2) ? er1[node*H + 1] : 0.f;
    float2 ap0[4], ap1[4];
    #pragma unroll
    for (int i = 0; i < 4; i++){ ap0[i] = make_float2(0.f,0.f); ap1[i] = make_float2(0.f,0.f); }
    float s00=0.f, s01=0.f, s10=0.f, s11=0.f;
    while (base0 < end0 || base1 < end1){
        int nrem0 = end0 - base0, nrem1 = end1 - base1;
        bool act0 = hl < nrem0, act1 = hl < nrem1;
        int sv0 = act0 ? colsrc[base0 + hl] : 0;
        int sv1 = act1 ? colsrc[base1 + hl] : 0;
        float a00=0.f, a01=0.f, a10=0.f, a11=0.f;
        if (act0){
            if (H == 2){
                float2 e2 = *(const float2*)&el0[sv0*2];
                float e0 = e2.x + er00, e1 = e2.y + er01;
                e0 = (e0 > 0.f) ? e0 : 0.2f*e0;
                e1 = (e1 > 0.f) ? e1 : 0.2f*e1;
                a00 = __expf(e0); a01 = __expf(e1);
            } else {
                float e0 = el0[sv0] + er00;
                e0 = (e0 > 0.f) ? e0 : 0.2f*e0;
                a00 = __expf(e0);
            }
        }
        if (act1){
            if (H == 2){
                float2 e2 = *(const float2*)&el1[sv1*2];
                float e0 = e2.x + er10, e1 = e2.y + er11;
                e0 = (e0 > 0.f) ? e0 : 0.2f*e0;
                e1 = (e1 > 0.f) ? e1 : 0.2f*e1;
                a10 = __expf(e0); a11 = __expf(e1);
            } else {
                float e0 = el1[sv1] + er10;
                e0 = (e0 > 0.f) ? e0 : 0.2f*e0;
                a10 = __expf(e0);
            }
        }
        s00 += a00; s01 += a01; s10 += a10; s11 += a11;
        stg[wid][half][0][hl] = make_float4(__int_as_float(sv0), a00,
                                            (H == 2) ? a01 : a00, 0.f);
        stg[wid][half][1][hl] = make_float4(__int_as_float(sv1), a10,
                                            (H == 2) ? a11 : a10, 0.f);
        __builtin_amdgcn_sched_barrier(0);   // keep reads after the stage
        int nn0 = (nrem0 > 0) ? min(32, nrem0) : 0;
        int nn1 = (nrem1 > 0) ? min(32, nrem1) : 0;
        int nnm = (nn0 > nn1) ? nn0 : nn1;
        for (int j4 = 0; j4 < nnm; j4 += 4){
            int sA = j4 + g, sB = sA + 2;
            float4 e0A = stg[wid][half][0][sA];
            float4 e0B = stg[wid][half][0][sB];
            float4 e1A = stg[wid][half][1][sA];
            float4 e1B = stg[wid][half][1][sB];
            uint4 p0A = *(const uint4*)&featb0[__float_as_uint(e0A.x)*FD + sub*8];
            uint4 p0B = *(const uint4*)&featb0[__float_as_uint(e0B.x)*FD + sub*8];
            uint4 p1A = *(const uint4*)&featb1[__float_as_uint(e1A.x)*FD + sub*8];
            uint4 p1B = *(const uint4*)&featb1[__float_as_uint(e1B.x)*FD + sub*8];
            float2 w0A = make_float2(e0A.y, e0A.z);
            float2 w0B = make_float2(e0B.y, e0B.z);
            float2 w1A = make_float2(e1A.y, e1A.z);
            float2 w1B = make_float2(e1B.y, e1B.z);
            pkfma(ap0[0], w0A, up2(p0A.x));
            pkfma(ap0[1], w0A, up2(p0A.y));
            pkfma(ap0[2], w0A, up2(p0A.z));
            pkfma(ap0[3], w0A, up2(p0A.w));
            pkfma(ap0[0], w0B, up2(p0B.x));
            pkfma(ap0[1], w0B, up2(p0B.y));
            pkfma(ap0[2], w0B, up2(p0B.z));
            pkfma(ap0[3], w0B, up2(p0B.w));
            pkfma(ap1[0], w1A, up2(p1A.x));
            pkfma(ap1[1], w1A, up2(p1A.y));
            pkfma(ap1[2], w1A, up2(p1A.z));
            pkfma(ap1[3], w1A, up2(p1A.w));
            pkfma(ap1[0], w1B, up2(p1B.x));
            pkfma(ap1[1], w1B, up2(p1B.y));
            pkfma(ap1[2], w1B, up2(p1B.z));
            pkfma(ap1[3], w1B, up2(p1B.w));
        }
        base0 += 32; base1 += 32;
    }
    // s-reduce within the 32-lane half (5 levels)
    #pragma unroll
    for (int off = 16; off > 0; off >>= 1){
        s00 += __shfl_xor(s00, off);
        s10 += __shfl_xor(s10, off);
        if (H == 2){ s01 += __shfl_xor(s01, off); s11 += __shfl_xor(s11, off); }
    }
    // group-reduce across the 2 groups of this half (1 level)
    #pragma unroll
    for (int i = 0; i < 4; i++){
        ap0[i].x += __shfl_xor(ap0[i].x, 16); ap0[i].y += __shfl_xor(ap0[i].y, 16);
        ap1[i].x += __shfl_xor(ap1[i].x, 16); ap1[i].y += __shfl_xor(ap1[i].y, 16);
    }
    if (hl < 16){
        float i00 = has0 ? 1.f/s00 : 0.f;
        float i01 = (H == 2) ? (has0 ? 1.f/s01 : 0.f) : i00;
        float i10 = has1 ? 1.f/s10 : 0.f;
        float i11 = (H == 2) ? (has1 ? 1.f/s11 : 0.f) : i10;
        float2 vp[4];
        #pragma unroll
        for (int t = 0; t < 4; t++){
            float bx = bias0[t*16 + sub]       + bias1[t*16 + sub];
            float by = bias0[(t+4)*16 + sub]   + bias1[(t+4)*16 + sub];
            vp[t].x = 0.5f*(ap0[t].x*i00 + ap1[t].x*i10 + bx);
            vp[t].y = 0.5f*(ap0[t].y*i01 + ap1[t].y*i11 + by);
        }
        if (H == 2){
            #pragma unroll
            for (int t = 0; t < 4; t++){
                vp[t].x = fmaxf(vp[t].x, 0.f);
                vp[t].y = fmaxf(vp[t].y, 0.f);
            }
            uint4 o;
            o.x = cvtpk(vp[0].x, vp[0].y); o.y = cvtpk(vp[1].x, vp[1].y);
            o.z = cvtpk(vp[2].x, vp[2].y); o.w = cvtpk(vp[3].x, vp[3].y);
            *(uint4*)&outb[(size_t)node*FD + sub*8] = o;
        } else {
            #pragma unroll
            for (int t = 0; t < 4; t++){
                outf[(size_t)node*FD + t*16 + sub]     = vp[t].x;
                outf[(size_t)node*FD + (t+4)*16 + sub] = vp[t].y;
            }
        }
    }
}

// ---------- launch ----------
extern "C" void kernel_launch(void* const* d_in, const int* in_sizes, int n_in,
                              void* d_out, int out_size, void* d_ws, size_t ws_size,
                              hipStream_t stream){
    const float* x   = (const float*)d_in[0];
    const float* W1  = (const float*)d_in[1];
    const float* al1 = (const float*)d_in[2];
    const float* ar1 = (const float*)d_in[3];
    const float* b1  = (const float*)d_in[4];
    const float* W2  = (const float*)d_in[5];
    const float* al2 = (const float*)d_in[6];
    const float* ar2 = (const float*)d_in[7];
    const float* b2  = (const float*)d_in[8];
    const int*   src = (const int*)d_in[9];
    const int*   dst = (const int*)d_in[10];
    float* out = (float*)d_out;

    size_t off = 0;
    auto carve = [&](size_t bytes) -> char* {
        char* p = (char*)d_ws + off;
        off += (bytes + 255) & ~(size_t)255;
        return p;
    };
    ushort_t* h1b    = (ushort_t*)carve((size_t)NN * FD * 2);
    ushort_t* featb0 = (ushort_t*)carve((size_t)NN * FD * 2);
    ushort_t* featb1 = (ushort_t*)carve((size_t)NN * FD * 2);
    uint2*    ebuf   = (uint2*)   carve((size_t)NBK * CAP * 8);   // own carve: kB races otherwise
    ushort_t* Wt1    = (ushort_t*)carve(32768 * 2);
    ushort_t* Wt2    = (ushort_t*)carve(32768 * 2);
    float* el0      = (float*)carve((size_t)NN * 2 * 4);
    float* er0      = (float*)carve((size_t)NN * 2 * 4);
    float* el1      = (float*)carve((size_t)NN * 2 * 4);
    float* er1      = (float*)carve((size_t)NN * 2 * 4);
    int*   rowbeg   = (int*)  carve((size_t)2*NN * 4);
    int*   rowend   = (int*)  carve((size_t)2*NN * 4);
    int*   colsrcA  = (int*)  carve((size_t)2*NE * 4);
    int*   bcur     = (int*)  carve((size_t)(NBK + 1) * 4);   // +1: gcounter tail
    if (off > ws_size) return;
    int* gcounter = bcur + NBK;

    const int WB = (NN + 7) / 8;                           // agg: 8 nodes/block

    // zero relative bucket cursors + global edge allocator (one memset)
    hipMemsetAsync(bcur, 0, (size_t)(NBK + 1) * 4, stream);

    // A: edge partition || W repack
    kA<<<PB + 256, 256, 0, stream>>>(dst, src, bcur, ebuf, W1, W2, Wt1, Wt2);

    // B: per-bucket scatter (first NBK blocks) || layer-1 GEMM
    kB<<<NBK + GB, 256, 0, stream>>>(ebuf, bcur, gcounter, rowbeg, rowend, colsrcA,
                                     x, Wt1, al1, ar1, al1 + FD, ar1 + FD,
                                     featb0, featb1, el0, er0, el1, er1);

    // layer-1 aggregation (writes bf16 relu(h1))
    k_agg2<2><<<WB, 256, 0, stream>>>(rowbeg, rowend, colsrcA,
                                      el0, er0, el1, er1, featb0, featb1,
                                      b1, b1 + FD, h1b, nullptr);

    // layer 2: GEMM (W2 rows pre-permuted to absorb h1b's layout) + aggregation
    k_gemm2<<<GB, 256, 0, stream>>>(h1b, Wt2, al2, ar2, al2 + FD, ar2 + FD,
                                    featb0, featb1, el0, er0, el1, er1);
    k_agg2<1><<<WB, 256, 0, stream>>>(rowbeg, rowend, colsrcA,
                                      el0, er0, el1, er1, featb0, featb1,
                                      b2, b2 + FD, nullptr, out);
}